// Round 10
// baseline (1782.131 us; speedup 1.0000x reference)
//
#include <hip/hip_runtime.h>
#include <math.h>

#ifndef M_PI
#define M_PI 3.14159265358979323846
#endif

#define BBc 4
#define CCc 32
#define NRk 16
#define HHc 192
#define WWc 192
#define HWc 36864
#define DDi 1179648
#define M1c 12
#define EPSc 1e-5f

static const size_t DDs = (size_t)DDi;

// ---------------- workspace layout (floats) ----------------
#define SZ_T   ((size_t)4718592)       // B*C*HW  (= B*D)
#define SZ_ZC  ((size_t)589824)        // 12ky*4b*32c*192h*2  (ky-major)
#define SZ_ZF  ((size_t)73728)         // 4b*12ky*24j*32c*2 (specA->specB)
#define SZ_WT  ((size_t)589824)        // ky-major
#define SZ_TAB ((size_t)4992)          // 13*192*2

#define OFF_XC   ((size_t)0)
#define OFF_XI   (OFF_XC + SZ_T)
#define OFF_F    (OFF_XI + SZ_T)
#define OFF_G    (OFF_F + 5 * SZ_T)
#define OFF_ZC   (OFF_G + 5 * SZ_T)
#define OFF_ZF   (OFF_ZC + SZ_ZC)
#define OFF_MO   (OFF_ZF + SZ_ZF)             // setup alias only
#define OFF_TM   (OFF_MO + SZ_ZF)
#define OFF_WT   (OFF_TM + SZ_ZC)
#define OFF_TAB  (OFF_WT + SZ_WT)
#define OFF_STAT (OFF_TAB + SZ_TAB)
#define A_XI0  OFF_G                   // setup alias (dead before first G write)

// ---- stats sublayout: sliced accumulators (round 4, confirmed -34%) ----
// NOTE (rounds 7-8): cooperative-kernel fusion of f6+f7g FAILS in this
// harness — hipLaunchCooperativeKernel is incompatible with hipGraph capture
// (silently never executes). Do NOT retry cooperative launches here.
#define NSLICE  32
#define NGSLICE 16
#define ST_EV   1024
#define ST_INJ   (16 * ST_EV)
#define ST_BN    (ST_INJ + 16)
#define ST_GRAM  (ST_BN + 64)
#define ST_ALPHA (ST_GRAM + NGSLICE * 60)
#define ST_TOTAL (ST_ALPHA + 20)

// bf16 helpers (RNE)
__device__ __forceinline__ float bf2f(unsigned short u) {
    return __uint_as_float(((unsigned int)u) << 16);
}
__device__ __forceinline__ unsigned short f2bf(float f) {
    unsigned int u = __float_as_uint(f);
    unsigned int r = (u + 0x7FFFu + ((u >> 16) & 1u)) >> 16;
    return (unsigned short)r;
}

// ---------------- small utility kernels ----------------
__global__ void k_zero(float* p, int n) {
    int i = blockIdx.x * blockDim.x + threadIdx.x;
    if (i < n) p[i] = 0.f;
}

__global__ void k_tables(float* tab) {
    int i = blockIdx.x * blockDim.x + threadIdx.x;  // 13*192
    if (i < 13 * 192) {
        int k = i / 192, x = i % 192;
        double th = 2.0 * M_PI * (double)(k * x) / 192.0;
        tab[i] = (float)cos(th);
        tab[13 * 192 + i] = (float)sin(th);
    }
}

// transpose spectral weights to wt[ky][j][i][o][2]
__global__ void k_wt(const float* __restrict__ w1r, const float* __restrict__ w1i,
                     const float* __restrict__ w2r, const float* __restrict__ w2i,
                     float* __restrict__ wt) {
    int idx = blockIdx.x * 256 + threadIdx.x;  // 24*12*32*32
    if (idx >= 24 * 12 * 1024) return;
    int o = idx & 31;
    int i = (idx >> 5) & 31;
    int ky = (idx >> 10) % 12;
    int j = idx / (12 * 1024);
    const float* wr;
    const float* wi;
    int x;
    if (j < 12) { wr = w1r; wi = w1i; x = j; }
    else        { wr = w2r; wi = w2i; x = j - 12; }
    int src = ((i * 32 + o) * 12 + x) * 12 + ky;
    size_t dst = (((size_t)ky * 24 + j) * 1024 + i * 32 + o) * 2;
    wt[dst] = wr[src];
    wt[dst + 1] = wi[src];
}

// effective single-channel conv weights
__global__ void k_ew(const float* __restrict__ cw, const float* __restrict__ fc0w,
                     const float* __restrict__ fc0b, float* __restrict__ ewb) {
    int i = threadIdx.x;  // 144 = 16 n x 9 taps
    if (i >= 144) return;
    int n = i / 9, t = i % 9;
    float ew = 0.f, eb = 0.f;
    for (int c = 0; c < 32; ++c) {
        float k = cw[(size_t)(n * CCc + c) * 9 + t];
        ew += k * fc0w[c];
        eb += k * fc0b[c];
    }
    ewb[i] = ew;
    ewb[144 + i] = eb;
}

// conv3x3 SAME on rank-1 input via effective kernels
__global__ __launch_bounds__(192) void k_conv2(const float* __restrict__ x,
                                               const float* __restrict__ ewb,
                                               float* __restrict__ xi0) {
    int b = blockIdx.x / HHc, h = blockIdx.x % HHc;
    __shared__ float sm[3 * 194];
    __shared__ float ews[144], ebs[144];
    int w = threadIdx.x;
    for (int i = threadIdx.x; i < 3 * 194; i += 192) {
        int r = i / 194, col = (i % 194) - 1;
        int hr = h + r - 1;
        float v = 0.f;
        if (hr >= 0 && hr < HHc && col >= 0 && col < WWc)
            v = x[(size_t)b * HWc + (size_t)hr * WWc + col];
        sm[i] = v;
    }
    if (threadIdx.x < 144) {
        ews[threadIdx.x] = ewb[threadIdx.x];
        ebs[threadIdx.x] = ewb[144 + threadIdx.x];
    }
    __syncthreads();
    float xv[9], mk[9];
#pragma unroll
    for (int r = 0; r < 3; ++r) {
        int hr = h + r - 1;
        bool rok = (hr >= 0 && hr < HHc);
#pragma unroll
        for (int dx = 0; dx < 3; ++dx) {
            int wx = w + dx - 1;
            bool ok = rok && (wx >= 0) && (wx < WWc);
            xv[r * 3 + dx] = sm[r * 194 + (w + dx)];
            mk[r * 3 + dx] = ok ? 1.f : 0.f;
        }
    }
#pragma unroll
    for (int n = 0; n < 16; ++n) {
        float acc = 0.f;
#pragma unroll
        for (int t = 0; t < 9; ++t)
            acc += ews[n * 9 + t] * xv[t] + mk[t] * ebs[n * 9 + t];
        xi0[((size_t)b * NRk + n) * HWc + (size_t)h * WWc + w] = acc;
    }
}

// generic contiguous-bin sum/sumsq with atomics (setup only)
__global__ void k_binstats(const float* __restrict__ src, float* __restrict__ stats,
                           int binsize, int blocksPerBin) {
    int bin = blockIdx.x / blocksPerBin, sub = blockIdx.x % blocksPerBin;
    const float* p = src + (size_t)bin * binsize;
    float s = 0.f, q = 0.f;
    for (int i = sub * blockDim.x + threadIdx.x; i < binsize; i += blocksPerBin * blockDim.x) {
        float v = p[i];
        s += v;
        q += v * v;
    }
    for (int o = 32; o; o >>= 1) { s += __shfl_down(s, o); q += __shfl_down(q, o); }
    __shared__ float rs[4], rq[4];
    int wid = threadIdx.x >> 6, lane = threadIdx.x & 63;
    if (lane == 0) { rs[wid] = s; rq[wid] = q; }
    __syncthreads();
    if (threadIdx.x == 0) {
        int nw = blockDim.x >> 6;
        float ts = 0.f, tq = 0.f;
        for (int i = 0; i < nw; ++i) { ts += rs[i]; tq += rq[i]; }
        atomicAdd(&stats[bin * 2], ts);
        atomicAdd(&stats[bin * 2 + 1], tq);
    }
}

// xi = sigmoid(q_w * GN(xi0) + q_b)
__global__ __launch_bounds__(192) void k_xi(const float* __restrict__ xi0,
                                            const float* __restrict__ stats,
                                            const float* __restrict__ gnw, const float* __restrict__ gnb,
                                            const float* __restrict__ qw, const float* __restrict__ qb,
                                            float* __restrict__ xi) {
    int b = blockIdx.x / HHc, h = blockIdx.x % HHc;
    int w = threadIdx.x;
    const float Ninv = 1.f / (8.f * HWc);
    float tn[16];
#pragma unroll
    for (int n = 0; n < 16; ++n) {
        int g = n >> 3;
        float su = stats[(b * 2 + g) * 2], sq = stats[(b * 2 + g) * 2 + 1];
        float mu = su * Ninv;
        float var = sq * Ninv - mu * mu;
        float inv = rsqrtf(var + EPSc);
        float v = xi0[((size_t)b * NRk + n) * HWc + (size_t)h * WWc + w];
        tn[n] = (v - mu) * inv * gnw[n] + gnb[n];
    }
#pragma unroll
    for (int d = 0; d < 32; ++d) {
        float acc = qb[d];
        const float* row = qw + d * 16;
#pragma unroll
        for (int n = 0; n < 16; ++n) acc += tn[n] * row[n];
        xi[((size_t)b * CCc + d) * HWc + (size_t)h * WWc + w] = 1.f / (1.f + expf(-acc));
    }
}

// ---------------- DFT chain ----------------
// ZC layout: [ky][b][c][h][2]; write: ZC[((ky*128 + bc)*192 + h)*2 + isim]

// plain forward DFT along W (eval 1, z = F0)
__global__ __launch_bounds__(192) void k_dftw(const float* __restrict__ z0,
                                              const float* __restrict__ tab,
                                              float* __restrict__ Zc) {
    int bc = blockIdx.x / 24;
    int hg = blockIdx.x % 24;
    int b = bc >> 5, c = bc & 31;
    const float* zp = z0 + (size_t)b * DDs + (size_t)c * HWc + (size_t)hg * 8 * WWc;
    __shared__ float rows[8 * 196];
    __shared__ float tb[24 * 196];
    const float4* zq = (const float4*)zp;
    for (int i4 = threadIdx.x; i4 < 384; i4 += 192) {
        float4 v = zq[i4];
        int r = i4 / 48, col = (i4 % 48) * 4;
        *(float4*)&rows[r * 196 + col] = v;
    }
    for (int i4 = threadIdx.x; i4 < 1152; i4 += 192) {
        int rr = i4 / 48, col = (i4 % 48) * 4;
        const float* src = (rr < 12) ? &tab[rr * 192 + col] : &tab[2496 + (rr - 12) * 192 + col];
        *(float4*)&tb[rr * 196 + col] = *(const float4*)src;
    }
    __syncthreads();
    int t = threadIdx.x;
    int r = t / 24, q = t % 24, ky = q >> 1, isim = q & 1;
    const float* tbp = tb + (isim ? (12 + ky) * 196 : ky * 196);
    const float* rowp = rows + r * 196;
    float a0 = 0.f, a1 = 0.f, a2 = 0.f, a3 = 0.f;
#pragma unroll
    for (int w2 = 0; w2 < WWc; w2 += 4) {
        a0 += rowp[w2] * tbp[w2];
        a1 += rowp[w2 + 1] * tbp[w2 + 1];
        a2 += rowp[w2 + 2] * tbp[w2 + 2];
        a3 += rowp[w2 + 3] * tbp[w2 + 3];
    }
    float acc = (a0 + a1) + (a2 + a3);
    if (isim) acc = -acc;
    int h = hg * 8 + r;
    Zc[(((size_t)ky * 128 + bc) * HHc + h) * 2 + isim] = acc;
}

// FUSED alpha-solve + xnew + forward W-DFT; skips F slots with alpha==0.
__global__ __launch_bounds__(192) void k_dftwx(const float* __restrict__ F,
                                               const float* __restrict__ gram,
                                               const float* __restrict__ tab,
                                               float* __restrict__ xc,
                                               float* __restrict__ Zc,
                                               int n) {
    int bc = blockIdx.x / 24;
    int hg = blockIdx.x % 24;
    int b = bc >> 5, c = bc & 31;
    __shared__ float rows[8 * 196];
    __shared__ float tb[24 * 196];
    __shared__ float gs[15];
    __shared__ float alf[5];
    for (int i4 = threadIdx.x; i4 < 1152; i4 += 192) {
        int rr = i4 / 48, col = (i4 % 48) * 4;
        const float* src = (rr < 12) ? &tab[rr * 192 + col] : &tab[2496 + (rr - 12) * 192 + col];
        *(float4*)&tb[rr * 196 + col] = *(const float4*)src;
    }
    if (threadIdx.x < 15) {
        float v = 0.f;
        for (int s2 = 0; s2 < NGSLICE; ++s2) v += gram[s2 * 60 + b * 15 + threadIdx.x];
        gs[threadIdx.x] = v;
    }
    __syncthreads();
    if (threadIdx.x == 0) {
        float H[5][5];
#pragma unroll
        for (int i = 0; i < 5; ++i)
#pragma unroll
            for (int j = 0; j <= i; ++j) {
                float v;
                if (i < n && j < n) v = gs[i * (i + 1) / 2 + j] + ((i == j) ? 1e-4f : 0.f);
                else                v = (i == j) ? 1.f : 0.f;
                H[i][j] = v;
                H[j][i] = v;
            }
        float L[5][5], D[5], w[5], y[5];
#pragma unroll
        for (int j = 0; j < 5; ++j) {
            float d = H[j][j];
#pragma unroll
            for (int k2 = 0; k2 < j; ++k2) d -= L[j][k2] * L[j][k2] * D[k2];
            D[j] = d;
#pragma unroll
            for (int i = j + 1; i < 5; ++i) {
                float v = H[i][j];
#pragma unroll
                for (int k2 = 0; k2 < j; ++k2) v -= L[i][k2] * L[j][k2] * D[k2];
                L[i][j] = v / d;
            }
        }
#pragma unroll
        for (int i = 0; i < 5; ++i) {
            float v = (i < n) ? 1.f : 0.f;
#pragma unroll
            for (int k2 = 0; k2 < i; ++k2) v -= L[i][k2] * w[k2];
            w[i] = v;
        }
#pragma unroll
        for (int i = 4; i >= 0; --i) {
            float v = w[i] / D[i];
#pragma unroll
            for (int k2 = i + 1; k2 < 5; ++k2) v -= L[k2][i] * y[k2];
            y[i] = v;
        }
        float sum = y[0] + y[1] + y[2] + y[3] + y[4];
        float inv = 1.f / sum;
#pragma unroll
        for (int j = 0; j < 5; ++j) alf[j] = (j < n) ? y[j] * inv : 0.f;
    }
    __syncthreads();
    float a0 = alf[0], a1 = alf[1], a2 = alf[2], a3 = alf[3], a4 = alf[4];

    size_t elem = (size_t)b * DDs + (size_t)c * HWc + (size_t)hg * 8 * WWc;
    int off4 = (int)(elem >> 2);
    const int sq4 = 1179648;  // SZ_T/4
    const float4* F4 = (const float4*)F;
    float4* xc4 = (float4*)xc;
    if (n == 5) {
        for (int i4 = threadIdx.x; i4 < 384; i4 += 192) {
            float4 f0 = F4[off4 + i4];
            float4 f1 = F4[sq4 + off4 + i4];
            float4 f2 = F4[2 * sq4 + off4 + i4];
            float4 f3 = F4[3 * sq4 + off4 + i4];
            float4 f4v = F4[4 * sq4 + off4 + i4];
            float4 v;
            v.x = a0 * f0.x + a1 * f1.x + a2 * f2.x + a3 * f3.x + a4 * f4v.x;
            v.y = a0 * f0.y + a1 * f1.y + a2 * f2.y + a3 * f3.y + a4 * f4v.y;
            v.z = a0 * f0.z + a1 * f1.z + a2 * f2.z + a3 * f3.z + a4 * f4v.z;
            v.w = a0 * f0.w + a1 * f1.w + a2 * f2.w + a3 * f3.w + a4 * f4v.w;
            xc4[off4 + i4] = v;
            int r = i4 / 48, col = (i4 % 48) * 4;
            *(float4*)&rows[r * 196 + col] = v;
        }
    } else {
        for (int i4 = threadIdx.x; i4 < 384; i4 += 192) {
            float4 f0 = F4[off4 + i4];
            float4 f1 = F4[sq4 + off4 + i4];
            float4 v;
            v.x = a0 * f0.x + a1 * f1.x;
            v.y = a0 * f0.y + a1 * f1.y;
            v.z = a0 * f0.z + a1 * f1.z;
            v.w = a0 * f0.w + a1 * f1.w;
            if (n >= 3) {
                float4 f2 = F4[2 * sq4 + off4 + i4];
                v.x += a2 * f2.x; v.y += a2 * f2.y; v.z += a2 * f2.z; v.w += a2 * f2.w;
            }
            if (n >= 4) {
                float4 f3 = F4[3 * sq4 + off4 + i4];
                v.x += a3 * f3.x; v.y += a3 * f3.y; v.z += a3 * f3.z; v.w += a3 * f3.w;
            }
            xc4[off4 + i4] = v;
            int r = i4 / 48, col = (i4 % 48) * 4;
            *(float4*)&rows[r * 196 + col] = v;
        }
    }
    __syncthreads();
    int t = threadIdx.x;
    int r = t / 24, q = t % 24, ky = q >> 1, isim = q & 1;
    const float* tbp = tb + (isim ? (12 + ky) * 196 : ky * 196);
    const float* rowp = rows + r * 196;
    float a0s = 0.f, a1s = 0.f, a2s = 0.f, a3s = 0.f;
#pragma unroll
    for (int w2 = 0; w2 < WWc; w2 += 4) {
        a0s += rowp[w2] * tbp[w2];
        a1s += rowp[w2 + 1] * tbp[w2 + 1];
        a2s += rowp[w2 + 2] * tbp[w2 + 2];
        a3s += rowp[w2 + 3] * tbp[w2 + 3];
    }
    float acc = (a0s + a1s) + (a2s + a3s);
    if (isim) acc = -acc;
    int h = hg * 8 + r;
    Zc[(((size_t)ky * 128 + bc) * HHc + h) * 2 + isim] = acc;
}

// k_specA: H-DFT. grid 256 blocks, 192 threads, ~30KB LDS.
__global__ __launch_bounds__(192) void k_specA(const float* __restrict__ ZC,
                                               const float* __restrict__ tab,
                                               float* __restrict__ ZF) {
    int kyh = blockIdx.x & 1;
    int c = (blockIdx.x >> 1) & 31;
    int b = blockIdx.x >> 6;
    int bc = b * 32 + c;
    int ky0 = kyh * 6;
    __shared__ float zc[6 * 388];
    __shared__ float tcs[13 * 196];
    __shared__ float tsn[13 * 196];
    int t = threadIdx.x;
    for (int i4 = t; i4 < 576; i4 += 192) {
        int kyl = i4 / 96, r4 = (i4 % 96) * 4;
        *(float4*)&zc[kyl * 388 + r4] =
            *(const float4*)(ZC + (size_t)((ky0 + kyl) * 128 + bc) * 384 + r4);
    }
    for (int i4 = t; i4 < 1248; i4 += 192) {
        int half = i4 / 624, k = (i4 % 624) / 48, col = (i4 % 48) * 4;
        const float* src = tab + half * 2496 + k * 192 + col;
        float* dst = (half ? tsn : tcs) + k * 196 + col;
        *(float4*)dst = *(const float4*)src;
    }
    __syncthreads();
    if (t < 144) {
        int kyl = t / 24, j = t % 24;
        int k = (j < 12) ? j : 24 - j;
        float sgn = (j < 12) ? 1.f : -1.f;
        const float* zp = zc + kyl * 388;
        const float* cp = tcs + k * 196;
        const float* sp = tsn + k * 196;
        float re0 = 0.f, im0 = 0.f, re1 = 0.f, im1 = 0.f;
        for (int h = 0; h < 192; h += 2) {
            float zr = zp[h * 2], zi = zp[h * 2 + 1];
            float cv = cp[h], sv = sgn * sp[h];
            re0 += zr * cv + zi * sv;
            im0 += zi * cv - zr * sv;
            float zr1 = zp[h * 2 + 2], zi1 = zp[h * 2 + 3];
            float cv1 = cp[h + 1], sv1 = sgn * sp[h + 1];
            re1 += zr1 * cv1 + zi1 * sv1;
            im1 += zi1 * cv1 - zr1 * sv1;
        }
        size_t o = (((size_t)(b * 12 + ky0 + kyl) * 24 + j) * 32 + c) * 2;
        ZF[o] = re0 + re1;
        ZF[o + 1] = im0 + im1;
    }
}

// k_specB: mode-mix + iDFT-H. grid 192 blocks, 256 threads, ~17.5KB LDS.
__global__ __launch_bounds__(256) void k_specB(const float* __restrict__ ZF,
                                               const float* __restrict__ wt,
                                               const float* __restrict__ tab,
                                               float* __restrict__ Tm) {
    int hq = blockIdx.x & 3;
    int ky = (blockIdx.x >> 2) % 12;
    int b = blockIdx.x / 48;
    __shared__ float zf[24 * 64];
    __shared__ float mo[32 * 50];
    __shared__ float tcs[13 * 48];
    __shared__ float tsn[13 * 48];
    int t = threadIdx.x;
    const float4* zsrc = (const float4*)(ZF + (size_t)(b * 12 + ky) * 1536);
    for (int i4 = t; i4 < 384; i4 += 256)
        *(float4*)&zf[i4 * 4] = zsrc[i4];
    for (int i4 = t; i4 < 312; i4 += 256) {
        int half = i4 / 156, idx = i4 % 156;
        int k = idx / 12, col = (idx % 12) * 4;
        const float* src = tab + half * 2496 + k * 192 + hq * 48 + col;
        float* dst = (half ? tsn : tcs) + k * 48 + col;
        *(float4*)dst = *(const float4*)src;
    }
    __syncthreads();
    const float* wky = wt + (size_t)ky * 24 * 2048;
    for (int p = t; p < 768; p += 256) {
        int j = p / 32, o = p % 32;
        const float* wp = wky + (size_t)j * 2048 + o * 2;
        const float* zj = zf + j * 64;
        float re = 0.f, im = 0.f;
#pragma unroll 8
        for (int i = 0; i < 32; ++i) {
            float ar = zj[i * 2], ai = zj[i * 2 + 1];
            float wr = wp[i * 64], wi = wp[i * 64 + 1];
            re += ar * wr - ai * wi;
            im += ar * wi + ai * wr;
        }
        mo[o * 50 + j * 2] = re;
        mo[o * 50 + j * 2 + 1] = im;
    }
    __syncthreads();
    const float scale = 1.f / 192.f;
    for (int p = t; p < 1536; p += 256) {
        int o = p / 48, hl = p % 48;
        int h = hq * 48 + hl;
        const float* mp = mo + o * 50;
        float re = 0.f, im = 0.f;
#pragma unroll
        for (int j = 0; j < 24; ++j) {
            int k = (j < 12) ? j : 24 - j;
            float sgn = (j < 12) ? 1.f : -1.f;
            float mr = mp[j * 2], mi = mp[j * 2 + 1];
            float cv = tcs[k * 48 + hl], sv = sgn * tsn[k * 48 + hl];
            re += mr * cv - mi * sv;
            im += mr * sv + mi * cv;
        }
        float* dst = Tm + ((size_t)(b * 32 + o) * HHc + h) * 24 + ky * 2;
        dst[0] = re * scale;
        dst[1] = im * scale;
    }
}

// iDFT-W + y2(1x1 conv) + exact gelu + xi add -> sbuf; gn1 stats (sliced).
__global__ __launch_bounds__(384) void k_f5(const float* __restrict__ z0,
                                            const float* __restrict__ Tm,
                                            const float* __restrict__ xi,
                                            const float* __restrict__ w0w,
                                            const float* __restrict__ w0b,
                                            const float* __restrict__ tab,
                                            float* __restrict__ sbuf,
                                            float* __restrict__ stats_e,
                                            int use_y1) {
    int h = blockIdx.x % HHc;
    int b = blockIdx.x / HHc;
    __shared__ float zl[32 * 192];
    __shared__ float w0s[32 * 36];
    __shared__ float tms[32 * 28];
    __shared__ float redc[6][2];
    int tid = threadIdx.x;
    int oq = tid & 3;
    int wq = (tid >> 2) % 48;
    int oh = tid / 192;
    int w4 = wq * 4;
    int ob = oh * 16 + oq;

    if (z0) {
        const float* zp = z0 + (size_t)b * DDs + (size_t)h * WWc;
        for (int i4 = tid; i4 < 32 * 48; i4 += 384) {
            int c = i4 / 48, q = (i4 % 48) * 4;
            float4 v = *(const float4*)(zp + (size_t)c * HWc + q);
            *(float4*)&zl[c * 192 + q] = v;
        }
        if (tid < 256) {
            int oo = tid >> 3, q = (tid & 7) * 4;
            *(float4*)&w0s[oo * 36 + q] = *(const float4*)(w0w + oo * 32 + q);
        }
    }
    if (use_y1) {
        if (tid < 192) {
            int oo = tid / 6, q = (tid % 6) * 4;
            *(float4*)&tms[oo * 28 + q] =
                *(const float4*)(Tm + (((size_t)b * 32 + oo) * HHc + h) * 24 + q);
        }
    }
    float4 c1r = *(const float4*)(tab + 192 + w4);
    float4 s1r = *(const float4*)(tab + 2496 + 192 + w4);
    __syncthreads();

    const float Winv = 1.f / 192.f;
    float acc[4][4];
#pragma unroll
    for (int oo = 0; oo < 4; ++oo) {
        float bbv = w0b[ob + oo * 4];
#pragma unroll
        for (int k = 0; k < 4; ++k) acc[oo][k] = bbv;
    }
    if (use_y1) {
#pragma unroll
        for (int oo = 0; oo < 4; ++oo) {
            float t0 = tms[(ob + oo * 4) * 28];
#pragma unroll
            for (int k = 0; k < 4; ++k) acc[oo][k] += t0 * Winv;
        }
        float4 ck = c1r, sk = s1r;
        const float sc = 2.f * Winv;
#pragma unroll
        for (int ky = 1; ky <= 11; ++ky) {
#pragma unroll
            for (int oo = 0; oo < 4; ++oo) {
                int o = ob + oo * 4;
                float tre = tms[o * 28 + 2 * ky] * sc;
                float tim = tms[o * 28 + 2 * ky + 1] * sc;
                acc[oo][0] += tre * ck.x - tim * sk.x;
                acc[oo][1] += tre * ck.y - tim * sk.y;
                acc[oo][2] += tre * ck.z - tim * sk.z;
                acc[oo][3] += tre * ck.w - tim * sk.w;
            }
            if (ky < 11) {
                float4 cn, sn;
                cn.x = ck.x * c1r.x - sk.x * s1r.x;
                sn.x = sk.x * c1r.x + ck.x * s1r.x;
                cn.y = ck.y * c1r.y - sk.y * s1r.y;
                sn.y = sk.y * c1r.y + ck.y * s1r.y;
                cn.z = ck.z * c1r.z - sk.z * s1r.z;
                sn.z = sk.z * c1r.z + ck.z * s1r.z;
                cn.w = ck.w * c1r.w - sk.w * s1r.w;
                sn.w = sk.w * c1r.w + ck.w * s1r.w;
                ck = cn; sk = sn;
            }
        }
    }
    if (z0) {
#pragma unroll 2
        for (int c = 0; c < 32; c += 4) {
            float4 wv[4];
#pragma unroll
            for (int oo = 0; oo < 4; ++oo)
                wv[oo] = *(const float4*)&w0s[(ob + oo * 4) * 36 + c];
#pragma unroll
            for (int k = 0; k < 4; ++k) {
                float4 z4 = *(const float4*)&zl[(c + k) * 192 + w4];
#pragma unroll
                for (int oo = 0; oo < 4; ++oo) {
                    float wvk = ((const float*)&wv[oo])[k];
                    acc[oo][0] += z4.x * wvk;
                    acc[oo][1] += z4.y * wvk;
                    acc[oo][2] += z4.z * wvk;
                    acc[oo][3] += z4.w * wvk;
                }
            }
        }
    }
    float4 xv[4];
#pragma unroll
    for (int oo = 0; oo < 4; ++oo) {
        int o = ob + oo * 4;
        xv[oo] = *(const float4*)(xi + (size_t)b * DDs + (size_t)o * HWc +
                                  (size_t)h * WWc + w4);
    }
    float s = 0.f, q = 0.f;
#pragma unroll
    for (int oo = 0; oo < 4; ++oo) {
        int o = ob + oo * 4;
        size_t gi = (size_t)b * DDs + (size_t)o * HWc + (size_t)h * WWc + w4;
        float4 out4;
        float* op = (float*)&out4;
        const float* xp = (const float*)&xv[oo];
#pragma unroll
        for (int k = 0; k < 4; ++k) {
            float v = acc[oo][k];
            float u = 0.5f * v * (1.f + erff(v * 0.70710678118654752f));
            float sv = xp[k] + u;
            op[k] = sv;
            s += sv;
            q += sv * sv;
        }
        *(float4*)(sbuf + gi) = out4;
    }
    for (int o2 = 32; o2; o2 >>= 1) {
        s += __shfl_down(s, o2);
        q += __shfl_down(q, o2);
    }
    int wid = tid >> 6, lane = tid & 63;
    if (lane == 0) { redc[wid][0] = s; redc[wid][1] = q; }
    __syncthreads();
    if (tid == 0) {
        float s0 = redc[0][0] + redc[1][0] + redc[2][0];
        float q0 = redc[0][1] + redc[1][1] + redc[2][1];
        float s1 = redc[3][0] + redc[4][0] + redc[5][0];
        float q1 = redc[3][1] + redc[4][1] + redc[5][1];
        int slice = blockIdx.x & (NSLICE - 1);
        float* st = stats_e + slice * 32;
        atomicAdd(&st[b * 4 + 0], s0);
        atomicAdd(&st[b * 4 + 1], q0);
        atomicAdd(&st[b * 4 + 2], s1);
        atomicAdd(&st[b * 4 + 3], q1);
    }
}

// Round 10: k_f6 is STATS-ONLY (no buf write). Computes gn2 stats from
// relu(z + GN1(buf)) without materializing it; k_f7g recomputes the identical
// values (same deterministic stats) — saves the 18.9MB intermediate write.
__global__ __launch_bounds__(256) void k_f6(const float* __restrict__ z0,
                                            const float* __restrict__ buf,
                                            float* __restrict__ stats_e,
                                            const float* __restrict__ n1w,
                                            const float* __restrict__ n1b,
                                            float* __restrict__ gram,
                                            int slot) {
    {
        int gid = blockIdx.x * 256 + threadIdx.x;
        if (gid < NGSLICE * 20) {
            int s2 = gid / 20, r = gid % 20;
            int j = r % 5, b2 = r / 5;
            int ii = slot > j ? slot : j, jj = slot > j ? j : slot;
            gram[s2 * 60 + b2 * 15 + ii * (ii + 1) / 2 + jj] = 0.f;
        }
    }
    const int binq = 147456;
    const int BPB = 144;
    int bin = blockIdx.x / BPB, sub = blockIdx.x % BPB;
    float Nv = 16.f * HWc;
    float su = 0.f, sq = 0.f;
    for (int s2 = 0; s2 < NSLICE; ++s2) {
        su += stats_e[s2 * 32 + bin * 2];
        sq += stats_e[s2 * 32 + bin * 2 + 1];
    }
    float mu = su / Nv;
    float var = sq / Nv - mu * mu;
    float inv = rsqrtf(var + EPSc);
    const float4* z4 = (const float4*)z0;
    const float4* b4 = (const float4*)buf;
    float s = 0.f, q = 0.f;
    for (int i4 = sub * 256 + threadIdx.x; i4 < binq; i4 += BPB * 256) {
        int e4 = bin * binq + i4;
        int c = (bin & 1) * 16 + i4 / 9216;
        float w1 = inv * n1w[c];
        float b1 = n1b[c] - mu * w1;
        float4 sv = b4[e4];
        float4 zv = make_float4(0.f, 0.f, 0.f, 0.f);
        if (z0) zv = z4[e4];
        float4 r;
        r.x = zv.x + sv.x * w1 + b1; r.x = r.x > 0.f ? r.x : 0.f;
        r.y = zv.y + sv.y * w1 + b1; r.y = r.y > 0.f ? r.y : 0.f;
        r.z = zv.z + sv.z * w1 + b1; r.z = r.z > 0.f ? r.z : 0.f;
        r.w = zv.w + sv.w * w1 + b1; r.w = r.w > 0.f ? r.w : 0.f;
        s += r.x + r.y + r.z + r.w;
        q += r.x * r.x + r.y * r.y + r.z * r.z + r.w * r.w;
    }
    for (int o = 32; o; o >>= 1) { s += __shfl_down(s, o); q += __shfl_down(q, o); }
    __shared__ float rs[4], rq[4];
    int wid = threadIdx.x >> 6, lane = threadIdx.x & 63;
    if (lane == 0) { rs[wid] = s; rq[wid] = q; }
    __syncthreads();
    if (threadIdx.x == 0) {
        int slice = blockIdx.x & (NSLICE - 1);
        atomicAdd(&stats_e[slice * 32 + 16 + bin * 2], rs[0] + rs[1] + rs[2] + rs[3]);
        atomicAdd(&stats_e[slice * 32 + 16 + bin * 2 + 1], rq[0] + rq[1] + rq[2] + rq[3]);
    }
}

// Round 10: k_f7g recomputes relu(z + GN1(buf)) (bit-identical to k_f6's),
// applies GN2, writes F slot; G/gram guarded by nvalid (skip uninitialized
// bf16 history slots in early evals). nvalid==0 => no gram work.
__global__ __launch_bounds__(256) void k_f7g(float* buf,
                                             const float* __restrict__ z,
                                             const float* __restrict__ stats_e,
                                             const float* __restrict__ n1w,
                                             const float* __restrict__ n1b,
                                             const float* __restrict__ n2w,
                                             const float* __restrict__ n2b,
                                             unsigned short* __restrict__ G,
                                             float* __restrict__ gram,
                                             int slot, int nvalid) {
    int b = blockIdx.x / 288, sub = blockIdx.x % 288;
    const float Ninv = 1.f / (16.f * HWc);
    // gn1 slice sums (both groups of this b)
    float s10 = 0.f, q10 = 0.f, s11 = 0.f, q11 = 0.f;
    // gn2 slice sums
    float su0 = 0.f, sq0 = 0.f, su1 = 0.f, sq1 = 0.f;
    for (int s2 = 0; s2 < NSLICE; ++s2) {
        const float* st1 = stats_e + s2 * 32 + b * 4;
        s10 += st1[0]; q10 += st1[1]; s11 += st1[2]; q11 += st1[3];
        const float* st2 = stats_e + s2 * 32 + 16 + b * 4;
        su0 += st2[0]; sq0 += st2[1]; su1 += st2[2]; sq1 += st2[3];
    }
    float mu10 = s10 * Ninv, i10 = rsqrtf(q10 * Ninv - mu10 * mu10 + EPSc);
    float mu11 = s11 * Ninv, i11 = rsqrtf(q11 * Ninv - mu11 * mu11 + EPSc);
    float mu0 = su0 * Ninv, inv0 = rsqrtf(sq0 * Ninv - mu0 * mu0 + EPSc);
    float mu1 = su1 * Ninv, inv1 = rsqrtf(sq1 * Ninv - mu1 * mu1 + EPSc);
    const int bq = 294912;
    const int sq4 = 1179648;
    float4* b4 = (float4*)buf;
    const float4* z4 = (const float4*)z;
    ushort4* GU = (ushort4*)G;
    float p0 = 0, p1 = 0, p2 = 0, p3 = 0, p4 = 0;
    for (int loc4 = sub * 256 + threadIdx.x; loc4 < bq; loc4 += 73728) {
        int e4 = b * bq + loc4;
        int c = loc4 / 9216;
        float mu1g, i1g, mu, inv;
        if (c < 16) { mu1g = mu10; i1g = i10; mu = mu0; inv = inv0; }
        else        { mu1g = mu11; i1g = i11; mu = mu1; inv = inv1; }
        float w1 = i1g * n1w[c];
        float b1 = n1b[c] - mu1g * w1;
        float wv = inv * n2w[c];
        float bv = n2b[c] - mu * wv;
        float4 sv = b4[e4];
        float4 zv = make_float4(0.f, 0.f, 0.f, 0.f);
        if (z) zv = z4[e4];
        float4 r;
        r.x = zv.x + sv.x * w1 + b1; r.x = r.x > 0.f ? r.x : 0.f;
        r.y = zv.y + sv.y * w1 + b1; r.y = r.y > 0.f ? r.y : 0.f;
        r.z = zv.z + sv.z * w1 + b1; r.z = r.z > 0.f ? r.z : 0.f;
        r.w = zv.w + sv.w * w1 + b1; r.w = r.w > 0.f ? r.w : 0.f;
        float4 fn;
        fn.x = r.x * wv + bv;
        fn.y = r.y * wv + bv;
        fn.z = r.z * wv + bv;
        fn.w = r.w * wv + bv;
        b4[e4] = fn;
        if (nvalid) {
            float4 g;
            g.x = fn.x - zv.x; g.y = fn.y - zv.y; g.z = fn.z - zv.z; g.w = fn.w - zv.w;
            ushort4 gw;
            gw.x = f2bf(g.x); gw.y = f2bf(g.y); gw.z = f2bf(g.z); gw.w = f2bf(g.w);
            GU[(size_t)slot * sq4 + e4] = gw;
            float4 gj[5];
#pragma unroll
            for (int j = 0; j < 5; ++j) {
                if (j >= nvalid) { gj[j] = make_float4(0.f, 0.f, 0.f, 0.f); }
                else if (j == slot) { gj[j] = g; }
                else {
                    ushort4 u = GU[(size_t)j * sq4 + e4];
                    gj[j].x = bf2f(u.x); gj[j].y = bf2f(u.y);
                    gj[j].z = bf2f(u.z); gj[j].w = bf2f(u.w);
                }
            }
            p0 += g.x * gj[0].x + g.y * gj[0].y + g.z * gj[0].z + g.w * gj[0].w;
            p1 += g.x * gj[1].x + g.y * gj[1].y + g.z * gj[1].z + g.w * gj[1].w;
            p2 += g.x * gj[2].x + g.y * gj[2].y + g.z * gj[2].z + g.w * gj[2].w;
            p3 += g.x * gj[3].x + g.y * gj[3].y + g.z * gj[3].z + g.w * gj[3].w;
            p4 += g.x * gj[4].x + g.y * gj[4].y + g.z * gj[4].z + g.w * gj[4].w;
        }
    }
    if (!nvalid) return;
    float p[5] = {p0, p1, p2, p3, p4};
    __shared__ float red[4][5];
    int wid = threadIdx.x >> 6, lane = threadIdx.x & 63;
#pragma unroll
    for (int j = 0; j < 5; ++j) {
        float v = p[j];
        for (int o = 32; o; o >>= 1) v += __shfl_down(v, o);
        if (lane == 0) red[wid][j] = v;
    }
    __syncthreads();
    if (threadIdx.x == 0) {
        int gsl = (blockIdx.x & (NGSLICE - 1)) * 60;
#pragma unroll
        for (int j = 0; j < 5; ++j) {
            if (j >= nvalid) continue;
            int ii = slot > j ? slot : j, jj = slot > j ? j : slot;
            atomicAdd(&gram[gsl + b * 15 + ii * (ii + 1) / 2 + jj],
                      red[0][j] + red[1][j] + red[2][j] + red[3][j]);
        }
    }
}

// ---------------- final: BN stats + BN + fc1(gelu) + fc2 ----------------
__global__ __launch_bounds__(256) void k_bnstats(const float* __restrict__ z,
                                                 float* __restrict__ bstats) {
    const int BPB = 18;
    int c = blockIdx.x / BPB, sub = blockIdx.x % BPB;
    float s = 0.f, q = 0.f;
    for (int i = sub * 256 + threadIdx.x; i < BBc * HWc; i += BPB * 256) {
        int b = i / HWc, hw = i % HWc;
        float v = z[(size_t)b * DDs + (size_t)c * HWc + hw];
        s += v;
        q += v * v;
    }
    for (int o = 32; o; o >>= 1) { s += __shfl_down(s, o); q += __shfl_down(q, o); }
    __shared__ float rs[4], rq[4];
    int wid = threadIdx.x >> 6, lane = threadIdx.x & 63;
    if (lane == 0) { rs[wid] = s; rq[wid] = q; }
    __syncthreads();
    if (threadIdx.x == 0) {
        atomicAdd(&bstats[c * 2], rs[0] + rs[1] + rs[2] + rs[3]);
        atomicAdd(&bstats[c * 2 + 1], rq[0] + rq[1] + rq[2] + rq[3]);
    }
}

__global__ __launch_bounds__(192) void k_final(const float* __restrict__ z,
                                               const float* __restrict__ bstats,
                                               const float* __restrict__ bnw,
                                               const float* __restrict__ bnb,
                                               const float* __restrict__ fc1w,
                                               const float* __restrict__ fc1b,
                                               const float* __restrict__ fc2w,
                                               const float* __restrict__ fc2b,
                                               float* __restrict__ out) {
    int b = blockIdx.x / HHc, h = blockIdx.x % HHc;
    int w = threadIdx.x;
    const float Ninv = 1.f / ((float)BBc * HWc);
    float zv[32];
#pragma unroll
    for (int c = 0; c < 32; ++c) {
        float su = bstats[c * 2], sq = bstats[c * 2 + 1];
        float mu = su * Ninv;
        float var = sq * Ninv - mu * mu;
        float inv = rsqrtf(var + EPSc);
        float v = z[(size_t)b * DDs + (size_t)c * HWc + (size_t)h * WWc + w];
        zv[c] = (v - mu) * inv * bnw[c] + bnb[c];
    }
    float acc2 = fc2b[0];
#pragma unroll
    for (int o = 0; o < 32; ++o) {
        float a = fc1b[o];
        const float* row = fc1w + o * 32;
#pragma unroll
        for (int c = 0; c < 32; ++c) a += zv[c] * row[c];
        float g = 0.5f * a * (1.f + erff(a * 0.70710678118654752f));
        acc2 += fc2w[o] * g;
    }
    out[(size_t)b * HWc + (size_t)h * WWc + w] = acc2;
}

// ---------------- host ----------------
extern "C" void kernel_launch(void* const* d_in, const int* in_sizes, int n_in,
                              void* d_out, int out_size, void* d_ws, size_t ws_size,
                              hipStream_t stream) {
    (void)in_sizes; (void)n_in; (void)out_size; (void)ws_size;
    const float* x    = (const float*)d_in[0];
    const float* fc0w = (const float*)d_in[1];
    const float* fc0b = (const float*)d_in[2];
    const float* convw = (const float*)d_in[3];
    const float* gnw  = (const float*)d_in[4];
    const float* gnb  = (const float*)d_in[5];
    const float* qw   = (const float*)d_in[6];
    const float* qb   = (const float*)d_in[7];
    const float* sw1r = (const float*)d_in[8];
    const float* sw1i = (const float*)d_in[9];
    const float* sw2r = (const float*)d_in[10];
    const float* sw2i = (const float*)d_in[11];
    const float* w0w  = (const float*)d_in[12];
    const float* w0b  = (const float*)d_in[13];
    const float* n1w  = (const float*)d_in[14];
    const float* n1b  = (const float*)d_in[15];
    const float* n2w  = (const float*)d_in[16];
    const float* n2b  = (const float*)d_in[17];
    const float* bnw  = (const float*)d_in[18];
    const float* bnb  = (const float*)d_in[19];
    const float* fc1w = (const float*)d_in[20];
    const float* fc1b = (const float*)d_in[21];
    const float* fc2w = (const float*)d_in[22];
    const float* fc2b = (const float*)d_in[23];
    float* out = (float*)d_out;

    float* ws = (float*)d_ws;
    float* XC  = ws + OFF_XC;
    float* XIp = ws + OFF_XI;
    float* Fb  = ws + OFF_F;
    unsigned short* Gb16 = (unsigned short*)(ws + OFF_G);
    float* ZC  = ws + OFF_ZC;
    float* ZFp = ws + OFF_ZF;
    float* MOp = ws + OFF_MO;
    float* TM  = ws + OFF_TM;
    float* WT  = ws + OFF_WT;
    float* TAB = ws + OFF_TAB;
    float* ST  = ws + OFF_STAT;
    float* XI0 = ws + A_XI0;   // setup alias (inside G region)
    float* EWB = MOp;          // setup alias

    auto runtail = [&](const float* zin, int outslot, int use_y1, int evalIdx,
                       int nvalid) {
        float* dst = Fb + (size_t)outslot * SZ_T;
        if (use_y1) {
            k_specA<<<256, 192, 0, stream>>>(ZC, TAB, ZFp);
            k_specB<<<BBc * 12 * 4, 256, 0, stream>>>(ZFp, WT, TAB, TM);
        }
        float* stats_e = ST + (size_t)evalIdx * ST_EV;
        k_f5<<<BBc * HHc, 384, 0, stream>>>(zin, TM, XIp, w0w, w0b, TAB, dst,
                                            stats_e, use_y1);
        k_f6<<<8 * 144, 256, 0, stream>>>(zin, dst, stats_e, n1w, n1b,
                                          ST + ST_GRAM, outslot);
        k_f7g<<<4 * 288, 256, 0, stream>>>(dst, zin, stats_e, n1w, n1b, n2w, n2b,
                                           Gb16, ST + ST_GRAM, outslot, nvalid);
    };

    // setup
    k_tables<<<10, 256, 0, stream>>>(TAB);
    k_wt<<<(24 * 12 * 1024 + 255) / 256, 256, 0, stream>>>(sw1r, sw1i, sw2r, sw2i, WT);
    k_zero<<<(ST_TOTAL + 255) / 256, 256, 0, stream>>>(ST, ST_TOTAL);
    k_ew<<<1, 192, 0, stream>>>(convw, fc0w, fc0b, EWB);
    k_conv2<<<BBc * HHc, 192, 0, stream>>>(x, EWB, XI0);
    k_binstats<<<8 * 36, 256, 0, stream>>>(XI0, ST + ST_INJ, 8 * HWc, 36);
    k_xi<<<BBc * HHc, 192, 0, stream>>>(XI0, ST + ST_INJ, gnw, gnb, qw, qb, XIp);

    // f0 = f(0) -> F0, G0, Gram(0,0): only slot 0 valid
    runtail(nullptr, 0, 0, 0, 1);
    // f1 = f(F0): plain dftw on F0; slots 0,1 valid
    k_dftw<<<BBc * CCc * 24, 192, 0, stream>>>(Fb, TAB, ZC);
    runtail(Fb, 1, 1, 1, 2);

    // Anderson iterations k = 2..15: fused solve+xnew+dftw -> rest
    for (int k = 2; k < 16; ++k) {
        int n = k < 5 ? k : 5;
        int slot = k % 5;
        int nv = (k < 15) ? ((k + 1 < 5) ? (k + 1) : 5) : 0;
        k_dftwx<<<BBc * CCc * 24, 192, 0, stream>>>(Fb, ST + ST_GRAM, TAB, XC, ZC, n);
        runtail(XC, slot, 1, k, nv);
    }

    // final z = F slot 0; BatchNorm + fc1(gelu) + fc2
    k_bnstats<<<32 * 18, 256, 0, stream>>>(Fb, ST + ST_BN);
    k_final<<<BBc * HHc, 192, 0, stream>>>(Fb, ST + ST_BN, bnw, bnb, fc1w, fc1b,
                                           fc2w, fc2b, out);
}

// Round 11
// 1754.756 us; speedup vs baseline: 1.0156x; 1.0156x over previous
//
#include <hip/hip_runtime.h>
#include <math.h>

#ifndef M_PI
#define M_PI 3.14159265358979323846
#endif

#define BBc 4
#define CCc 32
#define NRk 16
#define HHc 192
#define WWc 192
#define HWc 36864
#define DDi 1179648
#define M1c 12
#define EPSc 1e-5f

static const size_t DDs = (size_t)DDi;

// ---------------- workspace layout (floats) ----------------
#define SZ_T   ((size_t)4718592)       // B*C*HW  (= B*D)
#define SZ_ZC  ((size_t)589824)        // 12ky*4b*32c*192h*2  (ky-major)
#define SZ_ZF  ((size_t)73728)         // 4b*12ky*24j*32c*2 (specA->specB)
#define SZ_WT  ((size_t)589824)        // ky-major
#define SZ_TAB ((size_t)4992)          // 13*192*2

#define OFF_XC   ((size_t)0)
#define OFF_XI   (OFF_XC + SZ_T)
#define OFF_F    (OFF_XI + SZ_T)
#define OFF_G    (OFF_F + 5 * SZ_T)
#define OFF_ZC   (OFF_G + 5 * SZ_T)
#define OFF_ZF   (OFF_ZC + SZ_ZC)
#define OFF_MO   (OFF_ZF + SZ_ZF)             // setup alias only
#define OFF_TM   (OFF_MO + SZ_ZF)
#define OFF_WT   (OFF_TM + SZ_ZC)
#define OFF_TAB  (OFF_WT + SZ_WT)
#define OFF_STAT (OFF_TAB + SZ_TAB)
#define A_XI0  OFF_G                   // setup alias (dead before first G write)

// ---- stats sublayout: sliced accumulators (round 4, confirmed -34%) ----
// NOTE (rounds 7-8): cooperative-kernel fusion FAILS in this harness
// (hipLaunchCooperativeKernel incompatible with hipGraph capture; silently
// never executes). Do NOT retry cooperative launches.
// NOTE (round 10): stats-only f6 + GN1-recompute in f7g was NET-WORSE
// (+18us): the removed 19MB write was L3-absorbed; recompute wasn't free.
#define NSLICE  32
#define NGSLICE 16
#define ST_EV   1024
#define ST_INJ   (16 * ST_EV)
#define ST_BN    (ST_INJ + 16)
#define ST_GRAM  (ST_BN + 64)
#define ST_ALPHA (ST_GRAM + NGSLICE * 60)
#define ST_TOTAL (ST_ALPHA + 20)

// bf16 helpers (RNE)
__device__ __forceinline__ float bf2f(unsigned short u) {
    return __uint_as_float(((unsigned int)u) << 16);
}
__device__ __forceinline__ unsigned short f2bf(float f) {
    unsigned int u = __float_as_uint(f);
    unsigned int r = (u + 0x7FFFu + ((u >> 16) & 1u)) >> 16;
    return (unsigned short)r;
}

// ---------------- small utility kernels ----------------
__global__ void k_zero(float* p, int n) {
    int i = blockIdx.x * blockDim.x + threadIdx.x;
    if (i < n) p[i] = 0.f;
}

__global__ void k_tables(float* tab) {
    int i = blockIdx.x * blockDim.x + threadIdx.x;  // 13*192
    if (i < 13 * 192) {
        int k = i / 192, x = i % 192;
        double th = 2.0 * M_PI * (double)(k * x) / 192.0;
        tab[i] = (float)cos(th);
        tab[13 * 192 + i] = (float)sin(th);
    }
}

// transpose spectral weights to wt[ky][j][i][o][2]
__global__ void k_wt(const float* __restrict__ w1r, const float* __restrict__ w1i,
                     const float* __restrict__ w2r, const float* __restrict__ w2i,
                     float* __restrict__ wt) {
    int idx = blockIdx.x * 256 + threadIdx.x;  // 24*12*32*32
    if (idx >= 24 * 12 * 1024) return;
    int o = idx & 31;
    int i = (idx >> 5) & 31;
    int ky = (idx >> 10) % 12;
    int j = idx / (12 * 1024);
    const float* wr;
    const float* wi;
    int x;
    if (j < 12) { wr = w1r; wi = w1i; x = j; }
    else        { wr = w2r; wi = w2i; x = j - 12; }
    int src = ((i * 32 + o) * 12 + x) * 12 + ky;
    size_t dst = (((size_t)ky * 24 + j) * 1024 + i * 32 + o) * 2;
    wt[dst] = wr[src];
    wt[dst + 1] = wi[src];
}

// effective single-channel conv weights
__global__ void k_ew(const float* __restrict__ cw, const float* __restrict__ fc0w,
                     const float* __restrict__ fc0b, float* __restrict__ ewb) {
    int i = threadIdx.x;  // 144 = 16 n x 9 taps
    if (i >= 144) return;
    int n = i / 9, t = i % 9;
    float ew = 0.f, eb = 0.f;
    for (int c = 0; c < 32; ++c) {
        float k = cw[(size_t)(n * CCc + c) * 9 + t];
        ew += k * fc0w[c];
        eb += k * fc0b[c];
    }
    ewb[i] = ew;
    ewb[144 + i] = eb;
}

// conv3x3 SAME on rank-1 input via effective kernels
__global__ __launch_bounds__(192) void k_conv2(const float* __restrict__ x,
                                               const float* __restrict__ ewb,
                                               float* __restrict__ xi0) {
    int b = blockIdx.x / HHc, h = blockIdx.x % HHc;
    __shared__ float sm[3 * 194];
    __shared__ float ews[144], ebs[144];
    int w = threadIdx.x;
    for (int i = threadIdx.x; i < 3 * 194; i += 192) {
        int r = i / 194, col = (i % 194) - 1;
        int hr = h + r - 1;
        float v = 0.f;
        if (hr >= 0 && hr < HHc && col >= 0 && col < WWc)
            v = x[(size_t)b * HWc + (size_t)hr * WWc + col];
        sm[i] = v;
    }
    if (threadIdx.x < 144) {
        ews[threadIdx.x] = ewb[threadIdx.x];
        ebs[threadIdx.x] = ewb[144 + threadIdx.x];
    }
    __syncthreads();
    float xv[9], mk[9];
#pragma unroll
    for (int r = 0; r < 3; ++r) {
        int hr = h + r - 1;
        bool rok = (hr >= 0 && hr < HHc);
#pragma unroll
        for (int dx = 0; dx < 3; ++dx) {
            int wx = w + dx - 1;
            bool ok = rok && (wx >= 0) && (wx < WWc);
            xv[r * 3 + dx] = sm[r * 194 + (w + dx)];
            mk[r * 3 + dx] = ok ? 1.f : 0.f;
        }
    }
#pragma unroll
    for (int n = 0; n < 16; ++n) {
        float acc = 0.f;
#pragma unroll
        for (int t = 0; t < 9; ++t)
            acc += ews[n * 9 + t] * xv[t] + mk[t] * ebs[n * 9 + t];
        xi0[((size_t)b * NRk + n) * HWc + (size_t)h * WWc + w] = acc;
    }
}

// generic contiguous-bin sum/sumsq with atomics (setup only)
__global__ void k_binstats(const float* __restrict__ src, float* __restrict__ stats,
                           int binsize, int blocksPerBin) {
    int bin = blockIdx.x / blocksPerBin, sub = blockIdx.x % blocksPerBin;
    const float* p = src + (size_t)bin * binsize;
    float s = 0.f, q = 0.f;
    for (int i = sub * blockDim.x + threadIdx.x; i < binsize; i += blocksPerBin * blockDim.x) {
        float v = p[i];
        s += v;
        q += v * v;
    }
    for (int o = 32; o; o >>= 1) { s += __shfl_down(s, o); q += __shfl_down(q, o); }
    __shared__ float rs[4], rq[4];
    int wid = threadIdx.x >> 6, lane = threadIdx.x & 63;
    if (lane == 0) { rs[wid] = s; rq[wid] = q; }
    __syncthreads();
    if (threadIdx.x == 0) {
        int nw = blockDim.x >> 6;
        float ts = 0.f, tq = 0.f;
        for (int i = 0; i < nw; ++i) { ts += rs[i]; tq += rq[i]; }
        atomicAdd(&stats[bin * 2], ts);
        atomicAdd(&stats[bin * 2 + 1], tq);
    }
}

// xi = sigmoid(q_w * GN(xi0) + q_b)
__global__ __launch_bounds__(192) void k_xi(const float* __restrict__ xi0,
                                            const float* __restrict__ stats,
                                            const float* __restrict__ gnw, const float* __restrict__ gnb,
                                            const float* __restrict__ qw, const float* __restrict__ qb,
                                            float* __restrict__ xi) {
    int b = blockIdx.x / HHc, h = blockIdx.x % HHc;
    int w = threadIdx.x;
    const float Ninv = 1.f / (8.f * HWc);
    float tn[16];
#pragma unroll
    for (int n = 0; n < 16; ++n) {
        int g = n >> 3;
        float su = stats[(b * 2 + g) * 2], sq = stats[(b * 2 + g) * 2 + 1];
        float mu = su * Ninv;
        float var = sq * Ninv - mu * mu;
        float inv = rsqrtf(var + EPSc);
        float v = xi0[((size_t)b * NRk + n) * HWc + (size_t)h * WWc + w];
        tn[n] = (v - mu) * inv * gnw[n] + gnb[n];
    }
#pragma unroll
    for (int d = 0; d < 32; ++d) {
        float acc = qb[d];
        const float* row = qw + d * 16;
#pragma unroll
        for (int n = 0; n < 16; ++n) acc += tn[n] * row[n];
        xi[((size_t)b * CCc + d) * HWc + (size_t)h * WWc + w] = 1.f / (1.f + expf(-acc));
    }
}

// ---------------- DFT chain ----------------
// ZC layout: [ky][b][c][h][2]; write: ZC[((ky*128 + bc)*192 + h)*2 + isim]

// plain forward DFT along W (eval 1, z = F0)
__global__ __launch_bounds__(192) void k_dftw(const float* __restrict__ z0,
                                              const float* __restrict__ tab,
                                              float* __restrict__ Zc) {
    int bc = blockIdx.x / 24;
    int hg = blockIdx.x % 24;
    int b = bc >> 5, c = bc & 31;
    const float* zp = z0 + (size_t)b * DDs + (size_t)c * HWc + (size_t)hg * 8 * WWc;
    __shared__ float rows[8 * 196];
    __shared__ float tb[24 * 196];
    const float4* zq = (const float4*)zp;
    for (int i4 = threadIdx.x; i4 < 384; i4 += 192) {
        float4 v = zq[i4];
        int r = i4 / 48, col = (i4 % 48) * 4;
        *(float4*)&rows[r * 196 + col] = v;
    }
    for (int i4 = threadIdx.x; i4 < 1152; i4 += 192) {
        int rr = i4 / 48, col = (i4 % 48) * 4;
        const float* src = (rr < 12) ? &tab[rr * 192 + col] : &tab[2496 + (rr - 12) * 192 + col];
        *(float4*)&tb[rr * 196 + col] = *(const float4*)src;
    }
    __syncthreads();
    int t = threadIdx.x;
    int r = t / 24, q = t % 24, ky = q >> 1, isim = q & 1;
    const float* tbp = tb + (isim ? (12 + ky) * 196 : ky * 196);
    const float* rowp = rows + r * 196;
    float a0 = 0.f, a1 = 0.f, a2 = 0.f, a3 = 0.f;
#pragma unroll
    for (int w2 = 0; w2 < WWc; w2 += 4) {
        a0 += rowp[w2] * tbp[w2];
        a1 += rowp[w2 + 1] * tbp[w2 + 1];
        a2 += rowp[w2 + 2] * tbp[w2 + 2];
        a3 += rowp[w2 + 3] * tbp[w2 + 3];
    }
    float acc = (a0 + a1) + (a2 + a3);
    if (isim) acc = -acc;
    int h = hg * 8 + r;
    Zc[(((size_t)ky * 128 + bc) * HHc + h) * 2 + isim] = acc;
}

// FUSED alpha-solve + xnew + forward W-DFT; skips F slots with alpha==0.
__global__ __launch_bounds__(192) void k_dftwx(const float* __restrict__ F,
                                               const float* __restrict__ gram,
                                               const float* __restrict__ tab,
                                               float* __restrict__ xc,
                                               float* __restrict__ Zc,
                                               int n) {
    int bc = blockIdx.x / 24;
    int hg = blockIdx.x % 24;
    int b = bc >> 5, c = bc & 31;
    __shared__ float rows[8 * 196];
    __shared__ float tb[24 * 196];
    __shared__ float gs[15];
    __shared__ float alf[5];
    for (int i4 = threadIdx.x; i4 < 1152; i4 += 192) {
        int rr = i4 / 48, col = (i4 % 48) * 4;
        const float* src = (rr < 12) ? &tab[rr * 192 + col] : &tab[2496 + (rr - 12) * 192 + col];
        *(float4*)&tb[rr * 196 + col] = *(const float4*)src;
    }
    if (threadIdx.x < 15) {
        float v = 0.f;
        for (int s2 = 0; s2 < NGSLICE; ++s2) v += gram[s2 * 60 + b * 15 + threadIdx.x];
        gs[threadIdx.x] = v;
    }
    __syncthreads();
    if (threadIdx.x == 0) {
        float H[5][5];
#pragma unroll
        for (int i = 0; i < 5; ++i)
#pragma unroll
            for (int j = 0; j <= i; ++j) {
                float v;
                if (i < n && j < n) v = gs[i * (i + 1) / 2 + j] + ((i == j) ? 1e-4f : 0.f);
                else                v = (i == j) ? 1.f : 0.f;
                H[i][j] = v;
                H[j][i] = v;
            }
        float L[5][5], D[5], w[5], y[5];
#pragma unroll
        for (int j = 0; j < 5; ++j) {
            float d = H[j][j];
#pragma unroll
            for (int k2 = 0; k2 < j; ++k2) d -= L[j][k2] * L[j][k2] * D[k2];
            D[j] = d;
#pragma unroll
            for (int i = j + 1; i < 5; ++i) {
                float v = H[i][j];
#pragma unroll
                for (int k2 = 0; k2 < j; ++k2) v -= L[i][k2] * L[j][k2] * D[k2];
                L[i][j] = v / d;
            }
        }
#pragma unroll
        for (int i = 0; i < 5; ++i) {
            float v = (i < n) ? 1.f : 0.f;
#pragma unroll
            for (int k2 = 0; k2 < i; ++k2) v -= L[i][k2] * w[k2];
            w[i] = v;
        }
#pragma unroll
        for (int i = 4; i >= 0; --i) {
            float v = w[i] / D[i];
#pragma unroll
            for (int k2 = i + 1; k2 < 5; ++k2) v -= L[k2][i] * y[k2];
            y[i] = v;
        }
        float sum = y[0] + y[1] + y[2] + y[3] + y[4];
        float inv = 1.f / sum;
#pragma unroll
        for (int j = 0; j < 5; ++j) alf[j] = (j < n) ? y[j] * inv : 0.f;
    }
    __syncthreads();
    float a0 = alf[0], a1 = alf[1], a2 = alf[2], a3 = alf[3], a4 = alf[4];

    size_t elem = (size_t)b * DDs + (size_t)c * HWc + (size_t)hg * 8 * WWc;
    int off4 = (int)(elem >> 2);
    const int sq4 = 1179648;  // SZ_T/4
    const float4* F4 = (const float4*)F;
    float4* xc4 = (float4*)xc;
    if (n == 5) {
        for (int i4 = threadIdx.x; i4 < 384; i4 += 192) {
            float4 f0 = F4[off4 + i4];
            float4 f1 = F4[sq4 + off4 + i4];
            float4 f2 = F4[2 * sq4 + off4 + i4];
            float4 f3 = F4[3 * sq4 + off4 + i4];
            float4 f4v = F4[4 * sq4 + off4 + i4];
            float4 v;
            v.x = a0 * f0.x + a1 * f1.x + a2 * f2.x + a3 * f3.x + a4 * f4v.x;
            v.y = a0 * f0.y + a1 * f1.y + a2 * f2.y + a3 * f3.y + a4 * f4v.y;
            v.z = a0 * f0.z + a1 * f1.z + a2 * f2.z + a3 * f3.z + a4 * f4v.z;
            v.w = a0 * f0.w + a1 * f1.w + a2 * f2.w + a3 * f3.w + a4 * f4v.w;
            xc4[off4 + i4] = v;
            int r = i4 / 48, col = (i4 % 48) * 4;
            *(float4*)&rows[r * 196 + col] = v;
        }
    } else {
        for (int i4 = threadIdx.x; i4 < 384; i4 += 192) {
            float4 f0 = F4[off4 + i4];
            float4 f1 = F4[sq4 + off4 + i4];
            float4 v;
            v.x = a0 * f0.x + a1 * f1.x;
            v.y = a0 * f0.y + a1 * f1.y;
            v.z = a0 * f0.z + a1 * f1.z;
            v.w = a0 * f0.w + a1 * f1.w;
            if (n >= 3) {
                float4 f2 = F4[2 * sq4 + off4 + i4];
                v.x += a2 * f2.x; v.y += a2 * f2.y; v.z += a2 * f2.z; v.w += a2 * f2.w;
            }
            if (n >= 4) {
                float4 f3 = F4[3 * sq4 + off4 + i4];
                v.x += a3 * f3.x; v.y += a3 * f3.y; v.z += a3 * f3.z; v.w += a3 * f3.w;
            }
            xc4[off4 + i4] = v;
            int r = i4 / 48, col = (i4 % 48) * 4;
            *(float4*)&rows[r * 196 + col] = v;
        }
    }
    __syncthreads();
    int t = threadIdx.x;
    int r = t / 24, q = t % 24, ky = q >> 1, isim = q & 1;
    const float* tbp = tb + (isim ? (12 + ky) * 196 : ky * 196);
    const float* rowp = rows + r * 196;
    float a0s = 0.f, a1s = 0.f, a2s = 0.f, a3s = 0.f;
#pragma unroll
    for (int w2 = 0; w2 < WWc; w2 += 4) {
        a0s += rowp[w2] * tbp[w2];
        a1s += rowp[w2 + 1] * tbp[w2 + 1];
        a2s += rowp[w2 + 2] * tbp[w2 + 2];
        a3s += rowp[w2 + 3] * tbp[w2 + 3];
    }
    float acc = (a0s + a1s) + (a2s + a3s);
    if (isim) acc = -acc;
    int h = hg * 8 + r;
    Zc[(((size_t)ky * 128 + bc) * HHc + h) * 2 + isim] = acc;
}

// k_specA: H-DFT. grid 256 blocks, 192 threads, ~30KB LDS.
__global__ __launch_bounds__(192) void k_specA(const float* __restrict__ ZC,
                                               const float* __restrict__ tab,
                                               float* __restrict__ ZF) {
    int kyh = blockIdx.x & 1;
    int c = (blockIdx.x >> 1) & 31;
    int b = blockIdx.x >> 6;
    int bc = b * 32 + c;
    int ky0 = kyh * 6;
    __shared__ float zc[6 * 388];
    __shared__ float tcs[13 * 196];
    __shared__ float tsn[13 * 196];
    int t = threadIdx.x;
    for (int i4 = t; i4 < 576; i4 += 192) {
        int kyl = i4 / 96, r4 = (i4 % 96) * 4;
        *(float4*)&zc[kyl * 388 + r4] =
            *(const float4*)(ZC + (size_t)((ky0 + kyl) * 128 + bc) * 384 + r4);
    }
    for (int i4 = t; i4 < 1248; i4 += 192) {
        int half = i4 / 624, k = (i4 % 624) / 48, col = (i4 % 48) * 4;
        const float* src = tab + half * 2496 + k * 192 + col;
        float* dst = (half ? tsn : tcs) + k * 196 + col;
        *(float4*)dst = *(const float4*)src;
    }
    __syncthreads();
    if (t < 144) {
        int kyl = t / 24, j = t % 24;
        int k = (j < 12) ? j : 24 - j;
        float sgn = (j < 12) ? 1.f : -1.f;
        const float* zp = zc + kyl * 388;
        const float* cp = tcs + k * 196;
        const float* sp = tsn + k * 196;
        float re0 = 0.f, im0 = 0.f, re1 = 0.f, im1 = 0.f;
        for (int h = 0; h < 192; h += 2) {
            float zr = zp[h * 2], zi = zp[h * 2 + 1];
            float cv = cp[h], sv = sgn * sp[h];
            re0 += zr * cv + zi * sv;
            im0 += zi * cv - zr * sv;
            float zr1 = zp[h * 2 + 2], zi1 = zp[h * 2 + 3];
            float cv1 = cp[h + 1], sv1 = sgn * sp[h + 1];
            re1 += zr1 * cv1 + zi1 * sv1;
            im1 += zi1 * cv1 - zr1 * sv1;
        }
        size_t o = (((size_t)(b * 12 + ky0 + kyl) * 24 + j) * 32 + c) * 2;
        ZF[o] = re0 + re1;
        ZF[o + 1] = im0 + im1;
    }
}

// k_specB: mode-mix + iDFT-H. grid 192 blocks, 256 threads, ~17.5KB LDS.
__global__ __launch_bounds__(256) void k_specB(const float* __restrict__ ZF,
                                               const float* __restrict__ wt,
                                               const float* __restrict__ tab,
                                               float* __restrict__ Tm) {
    int hq = blockIdx.x & 3;
    int ky = (blockIdx.x >> 2) % 12;
    int b = blockIdx.x / 48;
    __shared__ float zf[24 * 64];
    __shared__ float mo[32 * 50];
    __shared__ float tcs[13 * 48];
    __shared__ float tsn[13 * 48];
    int t = threadIdx.x;
    const float4* zsrc = (const float4*)(ZF + (size_t)(b * 12 + ky) * 1536);
    for (int i4 = t; i4 < 384; i4 += 256)
        *(float4*)&zf[i4 * 4] = zsrc[i4];
    for (int i4 = t; i4 < 312; i4 += 256) {
        int half = i4 / 156, idx = i4 % 156;
        int k = idx / 12, col = (idx % 12) * 4;
        const float* src = tab + half * 2496 + k * 192 + hq * 48 + col;
        float* dst = (half ? tsn : tcs) + k * 48 + col;
        *(float4*)dst = *(const float4*)src;
    }
    __syncthreads();
    const float* wky = wt + (size_t)ky * 24 * 2048;
    for (int p = t; p < 768; p += 256) {
        int j = p / 32, o = p % 32;
        const float* wp = wky + (size_t)j * 2048 + o * 2;
        const float* zj = zf + j * 64;
        float re = 0.f, im = 0.f;
#pragma unroll 8
        for (int i = 0; i < 32; ++i) {
            float ar = zj[i * 2], ai = zj[i * 2 + 1];
            float wr = wp[i * 64], wi = wp[i * 64 + 1];
            re += ar * wr - ai * wi;
            im += ar * wi + ai * wr;
        }
        mo[o * 50 + j * 2] = re;
        mo[o * 50 + j * 2 + 1] = im;
    }
    __syncthreads();
    const float scale = 1.f / 192.f;
    for (int p = t; p < 1536; p += 256) {
        int o = p / 48, hl = p % 48;
        int h = hq * 48 + hl;
        const float* mp = mo + o * 50;
        float re = 0.f, im = 0.f;
#pragma unroll
        for (int j = 0; j < 24; ++j) {
            int k = (j < 12) ? j : 24 - j;
            float sgn = (j < 12) ? 1.f : -1.f;
            float mr = mp[j * 2], mi = mp[j * 2 + 1];
            float cv = tcs[k * 48 + hl], sv = sgn * tsn[k * 48 + hl];
            re += mr * cv - mi * sv;
            im += mr * sv + mi * cv;
        }
        float* dst = Tm + ((size_t)(b * 32 + o) * HHc + h) * 24 + ky * 2;
        dst[0] = re * scale;
        dst[1] = im * scale;
    }
}

// iDFT-W + y2(1x1 conv) + exact gelu + xi add -> sbuf; gn1 stats (sliced).
__global__ __launch_bounds__(384) void k_f5(const float* __restrict__ z0,
                                            const float* __restrict__ Tm,
                                            const float* __restrict__ xi,
                                            const float* __restrict__ w0w,
                                            const float* __restrict__ w0b,
                                            const float* __restrict__ tab,
                                            float* __restrict__ sbuf,
                                            float* __restrict__ stats_e,
                                            int use_y1) {
    int h = blockIdx.x % HHc;
    int b = blockIdx.x / HHc;
    __shared__ float zl[32 * 192];
    __shared__ float w0s[32 * 36];
    __shared__ float tms[32 * 28];
    __shared__ float redc[6][2];
    int tid = threadIdx.x;
    int oq = tid & 3;
    int wq = (tid >> 2) % 48;
    int oh = tid / 192;
    int w4 = wq * 4;
    int ob = oh * 16 + oq;

    if (z0) {
        const float* zp = z0 + (size_t)b * DDs + (size_t)h * WWc;
        for (int i4 = tid; i4 < 32 * 48; i4 += 384) {
            int c = i4 / 48, q = (i4 % 48) * 4;
            float4 v = *(const float4*)(zp + (size_t)c * HWc + q);
            *(float4*)&zl[c * 192 + q] = v;
        }
        if (tid < 256) {
            int oo = tid >> 3, q = (tid & 7) * 4;
            *(float4*)&w0s[oo * 36 + q] = *(const float4*)(w0w + oo * 32 + q);
        }
    }
    if (use_y1) {
        if (tid < 192) {
            int oo = tid / 6, q = (tid % 6) * 4;
            *(float4*)&tms[oo * 28 + q] =
                *(const float4*)(Tm + (((size_t)b * 32 + oo) * HHc + h) * 24 + q);
        }
    }
    float4 c1r = *(const float4*)(tab + 192 + w4);
    float4 s1r = *(const float4*)(tab + 2496 + 192 + w4);
    __syncthreads();

    const float Winv = 1.f / 192.f;
    float acc[4][4];
#pragma unroll
    for (int oo = 0; oo < 4; ++oo) {
        float bbv = w0b[ob + oo * 4];
#pragma unroll
        for (int k = 0; k < 4; ++k) acc[oo][k] = bbv;
    }
    if (use_y1) {
#pragma unroll
        for (int oo = 0; oo < 4; ++oo) {
            float t0 = tms[(ob + oo * 4) * 28];
#pragma unroll
            for (int k = 0; k < 4; ++k) acc[oo][k] += t0 * Winv;
        }
        float4 ck = c1r, sk = s1r;
        const float sc = 2.f * Winv;
#pragma unroll
        for (int ky = 1; ky <= 11; ++ky) {
#pragma unroll
            for (int oo = 0; oo < 4; ++oo) {
                int o = ob + oo * 4;
                float tre = tms[o * 28 + 2 * ky] * sc;
                float tim = tms[o * 28 + 2 * ky + 1] * sc;
                acc[oo][0] += tre * ck.x - tim * sk.x;
                acc[oo][1] += tre * ck.y - tim * sk.y;
                acc[oo][2] += tre * ck.z - tim * sk.z;
                acc[oo][3] += tre * ck.w - tim * sk.w;
            }
            if (ky < 11) {
                float4 cn, sn;
                cn.x = ck.x * c1r.x - sk.x * s1r.x;
                sn.x = sk.x * c1r.x + ck.x * s1r.x;
                cn.y = ck.y * c1r.y - sk.y * s1r.y;
                sn.y = sk.y * c1r.y + ck.y * s1r.y;
                cn.z = ck.z * c1r.z - sk.z * s1r.z;
                sn.z = sk.z * c1r.z + ck.z * s1r.z;
                cn.w = ck.w * c1r.w - sk.w * s1r.w;
                sn.w = sk.w * c1r.w + ck.w * s1r.w;
                ck = cn; sk = sn;
            }
        }
    }
    if (z0) {
#pragma unroll 2
        for (int c = 0; c < 32; c += 4) {
            float4 wv[4];
#pragma unroll
            for (int oo = 0; oo < 4; ++oo)
                wv[oo] = *(const float4*)&w0s[(ob + oo * 4) * 36 + c];
#pragma unroll
            for (int k = 0; k < 4; ++k) {
                float4 z4 = *(const float4*)&zl[(c + k) * 192 + w4];
#pragma unroll
                for (int oo = 0; oo < 4; ++oo) {
                    float wvk = ((const float*)&wv[oo])[k];
                    acc[oo][0] += z4.x * wvk;
                    acc[oo][1] += z4.y * wvk;
                    acc[oo][2] += z4.z * wvk;
                    acc[oo][3] += z4.w * wvk;
                }
            }
        }
    }
    float4 xv[4];
#pragma unroll
    for (int oo = 0; oo < 4; ++oo) {
        int o = ob + oo * 4;
        xv[oo] = *(const float4*)(xi + (size_t)b * DDs + (size_t)o * HWc +
                                  (size_t)h * WWc + w4);
    }
    float s = 0.f, q = 0.f;
#pragma unroll
    for (int oo = 0; oo < 4; ++oo) {
        int o = ob + oo * 4;
        size_t gi = (size_t)b * DDs + (size_t)o * HWc + (size_t)h * WWc + w4;
        float4 out4;
        float* op = (float*)&out4;
        const float* xp = (const float*)&xv[oo];
#pragma unroll
        for (int k = 0; k < 4; ++k) {
            float v = acc[oo][k];
            float u = 0.5f * v * (1.f + erff(v * 0.70710678118654752f));
            float sv = xp[k] + u;
            op[k] = sv;
            s += sv;
            q += sv * sv;
        }
        *(float4*)(sbuf + gi) = out4;
    }
    for (int o2 = 32; o2; o2 >>= 1) {
        s += __shfl_down(s, o2);
        q += __shfl_down(q, o2);
    }
    int wid = tid >> 6, lane = tid & 63;
    if (lane == 0) { redc[wid][0] = s; redc[wid][1] = q; }
    __syncthreads();
    if (tid == 0) {
        float s0 = redc[0][0] + redc[1][0] + redc[2][0];
        float q0 = redc[0][1] + redc[1][1] + redc[2][1];
        float s1 = redc[3][0] + redc[4][0] + redc[5][0];
        float q1 = redc[3][1] + redc[4][1] + redc[5][1];
        int slice = blockIdx.x & (NSLICE - 1);
        float* st = stats_e + slice * 32;
        atomicAdd(&st[b * 4 + 0], s0);
        atomicAdd(&st[b * 4 + 1], q0);
        atomicAdd(&st[b * 4 + 2], s1);
        atomicAdd(&st[b * 4 + 3], q1);
    }
}

// buf = relu(z + GN1(buf)) IN PLACE; gn2 stats (sliced); zero gram slot slices.
// (round-9 structure: writes buf — the materialized intermediate is L3-cheap,
//  recomputing it in f7g was net-worse; see round-10 note.)
__global__ __launch_bounds__(256) void k_f6(const float* __restrict__ z0,
                                            float* buf,
                                            float* __restrict__ stats_e,
                                            const float* __restrict__ n1w,
                                            const float* __restrict__ n1b,
                                            float* __restrict__ gram,
                                            int slot) {
    {
        int gid = blockIdx.x * 256 + threadIdx.x;
        if (gid < NGSLICE * 20) {
            int s2 = gid / 20, r = gid % 20;
            int j = r % 5, b2 = r / 5;
            int ii = slot > j ? slot : j, jj = slot > j ? j : slot;
            gram[s2 * 60 + b2 * 15 + ii * (ii + 1) / 2 + jj] = 0.f;
        }
    }
    const int binq = 147456;
    const int BPB = 144;
    int bin = blockIdx.x / BPB, sub = blockIdx.x % BPB;
    float Nv = 16.f * HWc;
    float su = 0.f, sq = 0.f;
    for (int s2 = 0; s2 < NSLICE; ++s2) {
        su += stats_e[s2 * 32 + bin * 2];
        sq += stats_e[s2 * 32 + bin * 2 + 1];
    }
    float mu = su / Nv;
    float var = sq / Nv - mu * mu;
    float inv = rsqrtf(var + EPSc);
    const float4* z4 = (const float4*)z0;
    float4* b4 = (float4*)buf;
    float s = 0.f, q = 0.f;
    for (int i4 = sub * 256 + threadIdx.x; i4 < binq; i4 += BPB * 256) {
        int e4 = bin * binq + i4;
        int c = (bin & 1) * 16 + i4 / 9216;
        float w1 = inv * n1w[c];
        float b1 = n1b[c] - mu * w1;
        float4 sv = b4[e4];
        float4 zv = make_float4(0.f, 0.f, 0.f, 0.f);
        if (z0) zv = z4[e4];
        float4 r;
        r.x = zv.x + sv.x * w1 + b1; r.x = r.x > 0.f ? r.x : 0.f;
        r.y = zv.y + sv.y * w1 + b1; r.y = r.y > 0.f ? r.y : 0.f;
        r.z = zv.z + sv.z * w1 + b1; r.z = r.z > 0.f ? r.z : 0.f;
        r.w = zv.w + sv.w * w1 + b1; r.w = r.w > 0.f ? r.w : 0.f;
        b4[e4] = r;
        s += r.x + r.y + r.z + r.w;
        q += r.x * r.x + r.y * r.y + r.z * r.z + r.w * r.w;
    }
    for (int o = 32; o; o >>= 1) { s += __shfl_down(s, o); q += __shfl_down(q, o); }
    __shared__ float rs[4], rq[4];
    int wid = threadIdx.x >> 6, lane = threadIdx.x & 63;
    if (lane == 0) { rs[wid] = s; rq[wid] = q; }
    __syncthreads();
    if (threadIdx.x == 0) {
        int slice = blockIdx.x & (NSLICE - 1);
        atomicAdd(&stats_e[slice * 32 + 16 + bin * 2], rs[0] + rs[1] + rs[2] + rs[3]);
        atomicAdd(&stats_e[slice * 32 + 16 + bin * 2 + 1], rq[0] + rq[1] + rq[2] + rq[3]);
    }
}

// buf = GN2(buf) IN PLACE; G[slot] = bf16(buf - z); sliced Gram.
// nvalid = number of valid G slots (skip uninitialized bf16 history in early
// evals — their products only fed gram entries that get zeroed before read).
// nvalid == 0 => no gram work at all (final eval).
__global__ __launch_bounds__(256) void k_f7g(float* buf,
                                             const float* __restrict__ z,
                                             const float* __restrict__ stats_e,
                                             const float* __restrict__ n2w,
                                             const float* __restrict__ n2b,
                                             unsigned short* __restrict__ G,
                                             float* __restrict__ gram,
                                             int slot, int nvalid) {
    int b = blockIdx.x / 288, sub = blockIdx.x % 288;
    const float Ninv = 1.f / (16.f * HWc);
    float su0 = 0.f, sq0 = 0.f, su1 = 0.f, sq1 = 0.f;
    for (int s2 = 0; s2 < NSLICE; ++s2) {
        const float* st = stats_e + s2 * 32 + 16 + b * 4;
        su0 += st[0]; sq0 += st[1]; su1 += st[2]; sq1 += st[3];
    }
    float mu0 = su0 * Ninv, inv0 = rsqrtf(sq0 * Ninv - mu0 * mu0 + EPSc);
    float mu1 = su1 * Ninv, inv1 = rsqrtf(sq1 * Ninv - mu1 * mu1 + EPSc);
    const int bq = 294912;
    const int sq4 = 1179648;
    float4* b4 = (float4*)buf;
    const float4* z4 = (const float4*)z;
    ushort4* GU = (ushort4*)G;
    float p0 = 0, p1 = 0, p2 = 0, p3 = 0, p4 = 0;
    for (int loc4 = sub * 256 + threadIdx.x; loc4 < bq; loc4 += 73728) {
        int e4 = b * bq + loc4;
        int c = loc4 / 9216;
        float mu = (c < 16) ? mu0 : mu1;
        float inv = (c < 16) ? inv0 : inv1;
        float wv = inv * n2w[c];
        float bv = n2b[c] - mu * wv;
        float4 r = b4[e4];
        float4 fn;
        fn.x = r.x * wv + bv;
        fn.y = r.y * wv + bv;
        fn.z = r.z * wv + bv;
        fn.w = r.w * wv + bv;
        b4[e4] = fn;
        if (nvalid) {
            float4 zv = make_float4(0.f, 0.f, 0.f, 0.f);
            if (z) zv = z4[e4];
            float4 g;
            g.x = fn.x - zv.x; g.y = fn.y - zv.y; g.z = fn.z - zv.z; g.w = fn.w - zv.w;
            ushort4 gw;
            gw.x = f2bf(g.x); gw.y = f2bf(g.y); gw.z = f2bf(g.z); gw.w = f2bf(g.w);
            GU[(size_t)slot * sq4 + e4] = gw;
            float4 gj[5];
#pragma unroll
            for (int j = 0; j < 5; ++j) {
                if (j >= nvalid) { gj[j] = make_float4(0.f, 0.f, 0.f, 0.f); }
                else if (j == slot) { gj[j] = g; }
                else {
                    ushort4 u = GU[(size_t)j * sq4 + e4];
                    gj[j].x = bf2f(u.x); gj[j].y = bf2f(u.y);
                    gj[j].z = bf2f(u.z); gj[j].w = bf2f(u.w);
                }
            }
            p0 += g.x * gj[0].x + g.y * gj[0].y + g.z * gj[0].z + g.w * gj[0].w;
            p1 += g.x * gj[1].x + g.y * gj[1].y + g.z * gj[1].z + g.w * gj[1].w;
            p2 += g.x * gj[2].x + g.y * gj[2].y + g.z * gj[2].z + g.w * gj[2].w;
            p3 += g.x * gj[3].x + g.y * gj[3].y + g.z * gj[3].z + g.w * gj[3].w;
            p4 += g.x * gj[4].x + g.y * gj[4].y + g.z * gj[4].z + g.w * gj[4].w;
        }
    }
    if (!nvalid) return;
    float p[5] = {p0, p1, p2, p3, p4};
    __shared__ float red[4][5];
    int wid = threadIdx.x >> 6, lane = threadIdx.x & 63;
#pragma unroll
    for (int j = 0; j < 5; ++j) {
        float v = p[j];
        for (int o = 32; o; o >>= 1) v += __shfl_down(v, o);
        if (lane == 0) red[wid][j] = v;
    }
    __syncthreads();
    if (threadIdx.x == 0) {
        int gsl = (blockIdx.x & (NGSLICE - 1)) * 60;
#pragma unroll
        for (int j = 0; j < 5; ++j) {
            if (j >= nvalid) continue;
            int ii = slot > j ? slot : j, jj = slot > j ? j : slot;
            atomicAdd(&gram[gsl + b * 15 + ii * (ii + 1) / 2 + jj],
                      red[0][j] + red[1][j] + red[2][j] + red[3][j]);
        }
    }
}

// ---------------- final: BN stats + BN + fc1(gelu) + fc2 ----------------
__global__ __launch_bounds__(256) void k_bnstats(const float* __restrict__ z,
                                                 float* __restrict__ bstats) {
    const int BPB = 18;
    int c = blockIdx.x / BPB, sub = blockIdx.x % BPB;
    float s = 0.f, q = 0.f;
    for (int i = sub * 256 + threadIdx.x; i < BBc * HWc; i += BPB * 256) {
        int b = i / HWc, hw = i % HWc;
        float v = z[(size_t)b * DDs + (size_t)c * HWc + hw];
        s += v;
        q += v * v;
    }
    for (int o = 32; o; o >>= 1) { s += __shfl_down(s, o); q += __shfl_down(q, o); }
    __shared__ float rs[4], rq[4];
    int wid = threadIdx.x >> 6, lane = threadIdx.x & 63;
    if (lane == 0) { rs[wid] = s; rq[wid] = q; }
    __syncthreads();
    if (threadIdx.x == 0) {
        atomicAdd(&bstats[c * 2], rs[0] + rs[1] + rs[2] + rs[3]);
        atomicAdd(&bstats[c * 2 + 1], rq[0] + rq[1] + rq[2] + rq[3]);
    }
}

__global__ __launch_bounds__(192) void k_final(const float* __restrict__ z,
                                               const float* __restrict__ bstats,
                                               const float* __restrict__ bnw,
                                               const float* __restrict__ bnb,
                                               const float* __restrict__ fc1w,
                                               const float* __restrict__ fc1b,
                                               const float* __restrict__ fc2w,
                                               const float* __restrict__ fc2b,
                                               float* __restrict__ out) {
    int b = blockIdx.x / HHc, h = blockIdx.x % HHc;
    int w = threadIdx.x;
    const float Ninv = 1.f / ((float)BBc * HWc);
    float zv[32];
#pragma unroll
    for (int c = 0; c < 32; ++c) {
        float su = bstats[c * 2], sq = bstats[c * 2 + 1];
        float mu = su * Ninv;
        float var = sq * Ninv - mu * mu;
        float inv = rsqrtf(var + EPSc);
        float v = z[(size_t)b * DDs + (size_t)c * HWc + (size_t)h * WWc + w];
        zv[c] = (v - mu) * inv * bnw[c] + bnb[c];
    }
    float acc2 = fc2b[0];
#pragma unroll
    for (int o = 0; o < 32; ++o) {
        float a = fc1b[o];
        const float* row = fc1w + o * 32;
#pragma unroll
        for (int c = 0; c < 32; ++c) a += zv[c] * row[c];
        float g = 0.5f * a * (1.f + erff(a * 0.70710678118654752f));
        acc2 += fc2w[o] * g;
    }
    out[(size_t)b * HWc + (size_t)h * WWc + w] = acc2;
}

// ---------------- host ----------------
extern "C" void kernel_launch(void* const* d_in, const int* in_sizes, int n_in,
                              void* d_out, int out_size, void* d_ws, size_t ws_size,
                              hipStream_t stream) {
    (void)in_sizes; (void)n_in; (void)out_size; (void)ws_size;
    const float* x    = (const float*)d_in[0];
    const float* fc0w = (const float*)d_in[1];
    const float* fc0b = (const float*)d_in[2];
    const float* convw = (const float*)d_in[3];
    const float* gnw  = (const float*)d_in[4];
    const float* gnb  = (const float*)d_in[5];
    const float* qw   = (const float*)d_in[6];
    const float* qb   = (const float*)d_in[7];
    const float* sw1r = (const float*)d_in[8];
    const float* sw1i = (const float*)d_in[9];
    const float* sw2r = (const float*)d_in[10];
    const float* sw2i = (const float*)d_in[11];
    const float* w0w  = (const float*)d_in[12];
    const float* w0b  = (const float*)d_in[13];
    const float* n1w  = (const float*)d_in[14];
    const float* n1b  = (const float*)d_in[15];
    const float* n2w  = (const float*)d_in[16];
    const float* n2b  = (const float*)d_in[17];
    const float* bnw  = (const float*)d_in[18];
    const float* bnb  = (const float*)d_in[19];
    const float* fc1w = (const float*)d_in[20];
    const float* fc1b = (const float*)d_in[21];
    const float* fc2w = (const float*)d_in[22];
    const float* fc2b = (const float*)d_in[23];
    float* out = (float*)d_out;

    float* ws = (float*)d_ws;
    float* XC  = ws + OFF_XC;
    float* XIp = ws + OFF_XI;
    float* Fb  = ws + OFF_F;
    unsigned short* Gb16 = (unsigned short*)(ws + OFF_G);
    float* ZC  = ws + OFF_ZC;
    float* ZFp = ws + OFF_ZF;
    float* MOp = ws + OFF_MO;
    float* TM  = ws + OFF_TM;
    float* WT  = ws + OFF_WT;
    float* TAB = ws + OFF_TAB;
    float* ST  = ws + OFF_STAT;
    float* XI0 = ws + A_XI0;   // setup alias (inside G region)
    float* EWB = MOp;          // setup alias

    auto runtail = [&](const float* zin, int outslot, int use_y1, int evalIdx,
                       int nvalid) {
        float* dst = Fb + (size_t)outslot * SZ_T;
        if (use_y1) {
            k_specA<<<256, 192, 0, stream>>>(ZC, TAB, ZFp);
            k_specB<<<BBc * 12 * 4, 256, 0, stream>>>(ZFp, WT, TAB, TM);
        }
        float* stats_e = ST + (size_t)evalIdx * ST_EV;
        k_f5<<<BBc * HHc, 384, 0, stream>>>(zin, TM, XIp, w0w, w0b, TAB, dst,
                                            stats_e, use_y1);
        k_f6<<<8 * 144, 256, 0, stream>>>(zin, dst, stats_e, n1w, n1b,
                                          ST + ST_GRAM, outslot);
        k_f7g<<<4 * 288, 256, 0, stream>>>(dst, zin, stats_e, n2w, n2b, Gb16,
                                           ST + ST_GRAM, outslot, nvalid);
    };

    // setup
    k_tables<<<10, 256, 0, stream>>>(TAB);
    k_wt<<<(24 * 12 * 1024 + 255) / 256, 256, 0, stream>>>(sw1r, sw1i, sw2r, sw2i, WT);
    k_zero<<<(ST_TOTAL + 255) / 256, 256, 0, stream>>>(ST, ST_TOTAL);
    k_ew<<<1, 192, 0, stream>>>(convw, fc0w, fc0b, EWB);
    k_conv2<<<BBc * HHc, 192, 0, stream>>>(x, EWB, XI0);
    k_binstats<<<8 * 36, 256, 0, stream>>>(XI0, ST + ST_INJ, 8 * HWc, 36);
    k_xi<<<BBc * HHc, 192, 0, stream>>>(XI0, ST + ST_INJ, gnw, gnb, qw, qb, XIp);

    // f0 = f(0) -> F0, G0, Gram(0,0): only slot 0 valid
    runtail(nullptr, 0, 0, 0, 1);
    // f1 = f(F0): plain dftw on F0; slots 0,1 valid
    k_dftw<<<BBc * CCc * 24, 192, 0, stream>>>(Fb, TAB, ZC);
    runtail(Fb, 1, 1, 1, 2);

    // Anderson iterations k = 2..15: fused solve+xnew+dftw -> rest
    for (int k = 2; k < 16; ++k) {
        int n = k < 5 ? k : 5;
        int slot = k % 5;
        int nv = (k < 15) ? ((k + 1 < 5) ? (k + 1) : 5) : 0;
        k_dftwx<<<BBc * CCc * 24, 192, 0, stream>>>(Fb, ST + ST_GRAM, TAB, XC, ZC, n);
        runtail(XC, slot, 1, k, nv);
    }

    // final z = F slot 0; BatchNorm + fc1(gelu) + fc2
    k_bnstats<<<32 * 18, 256, 0, stream>>>(Fb, ST + ST_BN);
    k_final<<<BBc * HHc, 192, 0, stream>>>(Fb, ST + ST_BN, bnw, bnb, fc1w, fc1b,
                                           fc2w, fc2b, out);
}

// Round 13
// 1744.941 us; speedup vs baseline: 1.0213x; 1.0056x over previous
//
#include <hip/hip_runtime.h>
#include <math.h>

#ifndef M_PI
#define M_PI 3.14159265358979323846
#endif

#define BBc 4
#define CCc 32
#define NRk 16
#define HHc 192
#define WWc 192
#define HWc 36864
#define DDi 1179648
#define M1c 12
#define EPSc 1e-5f

static const size_t DDs = (size_t)DDi;

// ---------------- workspace layout (floats) ----------------
#define SZ_T   ((size_t)4718592)       // B*C*HW  (= B*D)
#define SZ_ZC  ((size_t)589824)        // 12ky*4b*32c*192h*2  (ky-major)
#define SZ_ZF  ((size_t)73728)         // 4b*12ky*24j*32c*2 (specA->specB)
#define SZ_WT  ((size_t)589824)        // ky-major
#define SZ_TAB ((size_t)4992)          // 13*192*2

#define OFF_XC   ((size_t)0)
#define OFF_XI   (OFF_XC + SZ_T)
#define OFF_F    (OFF_XI + SZ_T)
#define OFF_G    (OFF_F + 5 * SZ_T)
#define OFF_ZC   (OFF_G + 5 * SZ_T)
#define OFF_ZF   (OFF_ZC + SZ_ZC)
#define OFF_MO   (OFF_ZF + SZ_ZF)             // setup alias only
#define OFF_TM   (OFF_MO + SZ_ZF)
#define OFF_WT   (OFF_TM + SZ_ZC)
#define OFF_TAB  (OFF_WT + SZ_WT)
#define OFF_STAT (OFF_TAB + SZ_TAB)
#define A_XI0  OFF_G                   // setup alias (dead before first G write)

// ---- stats sublayout: sliced accumulators (round 4, confirmed -34%) ----
// NOTE (rounds 7-8): cooperative-kernel fusion FAILS in this harness
// (hipLaunchCooperativeKernel incompatible with hipGraph capture; silently
// never executes). Do NOT retry cooperative launches.
// NOTE (round 10): stats-only f6 + GN1-recompute in f7g was NET-WORSE
// (+18us): the removed 19MB write was L3-absorbed; recompute wasn't free.
// NOTE (round 12): bf16 F-history FAILS numerics (absmax 0.78 vs 0.22):
// Anderson alpha are extrapolation coeffs (sum|a| ~ 3-5) -> bf16 error
// amplified each iteration. Keep F history f32.
#define NSLICE  32
#define NGSLICE 16
#define ST_EV   1024
#define ST_INJ   (16 * ST_EV)
#define ST_BN    (ST_INJ + 16)
#define ST_GRAM  (ST_BN + 64)
#define ST_ALPHA (ST_GRAM + NGSLICE * 60)
#define ST_TOTAL (ST_ALPHA + 20)

// bf16 helpers (RNE)
__device__ __forceinline__ float bf2f(unsigned short u) {
    return __uint_as_float(((unsigned int)u) << 16);
}
__device__ __forceinline__ unsigned short f2bf(float f) {
    unsigned int u = __float_as_uint(f);
    unsigned int r = (u + 0x7FFFu + ((u >> 16) & 1u)) >> 16;
    return (unsigned short)r;
}

// ---------------- small utility kernels ----------------
__global__ void k_zero(float* p, int n) {
    int i = blockIdx.x * blockDim.x + threadIdx.x;
    if (i < n) p[i] = 0.f;
}

__global__ void k_tables(float* tab) {
    int i = blockIdx.x * blockDim.x + threadIdx.x;  // 13*192
    if (i < 13 * 192) {
        int k = i / 192, x = i % 192;
        double th = 2.0 * M_PI * (double)(k * x) / 192.0;
        tab[i] = (float)cos(th);
        tab[13 * 192 + i] = (float)sin(th);
    }
}

// transpose spectral weights to wt[ky][j][i][o][2]
__global__ void k_wt(const float* __restrict__ w1r, const float* __restrict__ w1i,
                     const float* __restrict__ w2r, const float* __restrict__ w2i,
                     float* __restrict__ wt) {
    int idx = blockIdx.x * 256 + threadIdx.x;  // 24*12*32*32
    if (idx >= 24 * 12 * 1024) return;
    int o = idx & 31;
    int i = (idx >> 5) & 31;
    int ky = (idx >> 10) % 12;
    int j = idx / (12 * 1024);
    const float* wr;
    const float* wi;
    int x;
    if (j < 12) { wr = w1r; wi = w1i; x = j; }
    else        { wr = w2r; wi = w2i; x = j - 12; }
    int src = ((i * 32 + o) * 12 + x) * 12 + ky;
    size_t dst = (((size_t)ky * 24 + j) * 1024 + i * 32 + o) * 2;
    wt[dst] = wr[src];
    wt[dst + 1] = wi[src];
}

// effective single-channel conv weights
__global__ void k_ew(const float* __restrict__ cw, const float* __restrict__ fc0w,
                     const float* __restrict__ fc0b, float* __restrict__ ewb) {
    int i = threadIdx.x;  // 144 = 16 n x 9 taps
    if (i >= 144) return;
    int n = i / 9, t = i % 9;
    float ew = 0.f, eb = 0.f;
    for (int c = 0; c < 32; ++c) {
        float k = cw[(size_t)(n * CCc + c) * 9 + t];
        ew += k * fc0w[c];
        eb += k * fc0b[c];
    }
    ewb[i] = ew;
    ewb[144 + i] = eb;
}

// conv3x3 SAME on rank-1 input via effective kernels
__global__ __launch_bounds__(192) void k_conv2(const float* __restrict__ x,
                                               const float* __restrict__ ewb,
                                               float* __restrict__ xi0) {
    int b = blockIdx.x / HHc, h = blockIdx.x % HHc;
    __shared__ float sm[3 * 194];
    __shared__ float ews[144], ebs[144];
    int w = threadIdx.x;
    for (int i = threadIdx.x; i < 3 * 194; i += 192) {
        int r = i / 194, col = (i % 194) - 1;
        int hr = h + r - 1;
        float v = 0.f;
        if (hr >= 0 && hr < HHc && col >= 0 && col < WWc)
            v = x[(size_t)b * HWc + (size_t)hr * WWc + col];
        sm[i] = v;
    }
    if (threadIdx.x < 144) {
        ews[threadIdx.x] = ewb[threadIdx.x];
        ebs[threadIdx.x] = ewb[144 + threadIdx.x];
    }
    __syncthreads();
    float xv[9], mk[9];
#pragma unroll
    for (int r = 0; r < 3; ++r) {
        int hr = h + r - 1;
        bool rok = (hr >= 0 && hr < HHc);
#pragma unroll
        for (int dx = 0; dx < 3; ++dx) {
            int wx = w + dx - 1;
            bool ok = rok && (wx >= 0) && (wx < WWc);
            xv[r * 3 + dx] = sm[r * 194 + (w + dx)];
            mk[r * 3 + dx] = ok ? 1.f : 0.f;
        }
    }
#pragma unroll
    for (int n = 0; n < 16; ++n) {
        float acc = 0.f;
#pragma unroll
        for (int t = 0; t < 9; ++t)
            acc += ews[n * 9 + t] * xv[t] + mk[t] * ebs[n * 9 + t];
        xi0[((size_t)b * NRk + n) * HWc + (size_t)h * WWc + w] = acc;
    }
}

// generic contiguous-bin sum/sumsq with atomics (setup only)
__global__ void k_binstats(const float* __restrict__ src, float* __restrict__ stats,
                           int binsize, int blocksPerBin) {
    int bin = blockIdx.x / blocksPerBin, sub = blockIdx.x % blocksPerBin;
    const float* p = src + (size_t)bin * binsize;
    float s = 0.f, q = 0.f;
    for (int i = sub * blockDim.x + threadIdx.x; i < binsize; i += blocksPerBin * blockDim.x) {
        float v = p[i];
        s += v;
        q += v * v;
    }
    for (int o = 32; o; o >>= 1) { s += __shfl_down(s, o); q += __shfl_down(q, o); }
    __shared__ float rs[4], rq[4];
    int wid = threadIdx.x >> 6, lane = threadIdx.x & 63;
    if (lane == 0) { rs[wid] = s; rq[wid] = q; }
    __syncthreads();
    if (threadIdx.x == 0) {
        int nw = blockDim.x >> 6;
        float ts = 0.f, tq = 0.f;
        for (int i = 0; i < nw; ++i) { ts += rs[i]; tq += rq[i]; }
        atomicAdd(&stats[bin * 2], ts);
        atomicAdd(&stats[bin * 2 + 1], tq);
    }
}

// xi = sigmoid(q_w * GN(xi0) + q_b)
__global__ __launch_bounds__(192) void k_xi(const float* __restrict__ xi0,
                                            const float* __restrict__ stats,
                                            const float* __restrict__ gnw, const float* __restrict__ gnb,
                                            const float* __restrict__ qw, const float* __restrict__ qb,
                                            float* __restrict__ xi) {
    int b = blockIdx.x / HHc, h = blockIdx.x % HHc;
    int w = threadIdx.x;
    const float Ninv = 1.f / (8.f * HWc);
    float tn[16];
#pragma unroll
    for (int n = 0; n < 16; ++n) {
        int g = n >> 3;
        float su = stats[(b * 2 + g) * 2], sq = stats[(b * 2 + g) * 2 + 1];
        float mu = su * Ninv;
        float var = sq * Ninv - mu * mu;
        float inv = rsqrtf(var + EPSc);
        float v = xi0[((size_t)b * NRk + n) * HWc + (size_t)h * WWc + w];
        tn[n] = (v - mu) * inv * gnw[n] + gnb[n];
    }
#pragma unroll
    for (int d = 0; d < 32; ++d) {
        float acc = qb[d];
        const float* row = qw + d * 16;
#pragma unroll
        for (int n = 0; n < 16; ++n) acc += tn[n] * row[n];
        xi[((size_t)b * CCc + d) * HWc + (size_t)h * WWc + w] = 1.f / (1.f + expf(-acc));
    }
}

// ---------------- DFT chain ----------------
// ZC layout: [ky][b][c][h][2]; write: ZC[((ky*128 + bc)*192 + h)*2 + isim]

// plain forward DFT along W (eval 1, z = F0)
__global__ __launch_bounds__(192) void k_dftw(const float* __restrict__ z0,
                                              const float* __restrict__ tab,
                                              float* __restrict__ Zc) {
    int bc = blockIdx.x / 24;
    int hg = blockIdx.x % 24;
    int b = bc >> 5, c = bc & 31;
    const float* zp = z0 + (size_t)b * DDs + (size_t)c * HWc + (size_t)hg * 8 * WWc;
    __shared__ float rows[8 * 196];
    __shared__ float tb[24 * 196];
    const float4* zq = (const float4*)zp;
    for (int i4 = threadIdx.x; i4 < 384; i4 += 192) {
        float4 v = zq[i4];
        int r = i4 / 48, col = (i4 % 48) * 4;
        *(float4*)&rows[r * 196 + col] = v;
    }
    for (int i4 = threadIdx.x; i4 < 1152; i4 += 192) {
        int rr = i4 / 48, col = (i4 % 48) * 4;
        const float* src = (rr < 12) ? &tab[rr * 192 + col] : &tab[2496 + (rr - 12) * 192 + col];
        *(float4*)&tb[rr * 196 + col] = *(const float4*)src;
    }
    __syncthreads();
    int t = threadIdx.x;
    int r = t / 24, q = t % 24, ky = q >> 1, isim = q & 1;
    const float* tbp = tb + (isim ? (12 + ky) * 196 : ky * 196);
    const float* rowp = rows + r * 196;
    float a0 = 0.f, a1 = 0.f, a2 = 0.f, a3 = 0.f;
#pragma unroll
    for (int w2 = 0; w2 < WWc; w2 += 4) {
        a0 += rowp[w2] * tbp[w2];
        a1 += rowp[w2 + 1] * tbp[w2 + 1];
        a2 += rowp[w2 + 2] * tbp[w2 + 2];
        a3 += rowp[w2 + 3] * tbp[w2 + 3];
    }
    float acc = (a0 + a1) + (a2 + a3);
    if (isim) acc = -acc;
    int h = hg * 8 + r;
    Zc[(((size_t)ky * 128 + bc) * HHc + h) * 2 + isim] = acc;
}

// FUSED alpha-solve + xnew + forward W-DFT; skips F slots with alpha==0.
__global__ __launch_bounds__(192) void k_dftwx(const float* __restrict__ F,
                                               const float* __restrict__ gram,
                                               const float* __restrict__ tab,
                                               float* __restrict__ xc,
                                               float* __restrict__ Zc,
                                               int n) {
    int bc = blockIdx.x / 24;
    int hg = blockIdx.x % 24;
    int b = bc >> 5, c = bc & 31;
    __shared__ float rows[8 * 196];
    __shared__ float tb[24 * 196];
    __shared__ float gs[15];
    __shared__ float alf[5];
    for (int i4 = threadIdx.x; i4 < 1152; i4 += 192) {
        int rr = i4 / 48, col = (i4 % 48) * 4;
        const float* src = (rr < 12) ? &tab[rr * 192 + col] : &tab[2496 + (rr - 12) * 192 + col];
        *(float4*)&tb[rr * 196 + col] = *(const float4*)src;
    }
    if (threadIdx.x < 15) {
        float v = 0.f;
        for (int s2 = 0; s2 < NGSLICE; ++s2) v += gram[s2 * 60 + b * 15 + threadIdx.x];
        gs[threadIdx.x] = v;
    }
    __syncthreads();
    if (threadIdx.x == 0) {
        float H[5][5];
#pragma unroll
        for (int i = 0; i < 5; ++i)
#pragma unroll
            for (int j = 0; j <= i; ++j) {
                float v;
                if (i < n && j < n) v = gs[i * (i + 1) / 2 + j] + ((i == j) ? 1e-4f : 0.f);
                else                v = (i == j) ? 1.f : 0.f;
                H[i][j] = v;
                H[j][i] = v;
            }
        float L[5][5], D[5], w[5], y[5];
#pragma unroll
        for (int j = 0; j < 5; ++j) {
            float d = H[j][j];
#pragma unroll
            for (int k2 = 0; k2 < j; ++k2) d -= L[j][k2] * L[j][k2] * D[k2];
            D[j] = d;
#pragma unroll
            for (int i = j + 1; i < 5; ++i) {
                float v = H[i][j];
#pragma unroll
                for (int k2 = 0; k2 < j; ++k2) v -= L[i][k2] * L[j][k2] * D[k2];
                L[i][j] = v / d;
            }
        }
#pragma unroll
        for (int i = 0; i < 5; ++i) {
            float v = (i < n) ? 1.f : 0.f;
#pragma unroll
            for (int k2 = 0; k2 < i; ++k2) v -= L[i][k2] * w[k2];
            w[i] = v;
        }
#pragma unroll
        for (int i = 4; i >= 0; --i) {
            float v = w[i] / D[i];
#pragma unroll
            for (int k2 = i + 1; k2 < 5; ++k2) v -= L[k2][i] * y[k2];
            y[i] = v;
        }
        float sum = y[0] + y[1] + y[2] + y[3] + y[4];
        float inv = 1.f / sum;
#pragma unroll
        for (int j = 0; j < 5; ++j) alf[j] = (j < n) ? y[j] * inv : 0.f;
    }
    __syncthreads();
    float a0 = alf[0], a1 = alf[1], a2 = alf[2], a3 = alf[3], a4 = alf[4];

    size_t elem = (size_t)b * DDs + (size_t)c * HWc + (size_t)hg * 8 * WWc;
    int off4 = (int)(elem >> 2);
    const int sq4 = 1179648;  // SZ_T/4
    const float4* F4 = (const float4*)F;
    float4* xc4 = (float4*)xc;
    if (n == 5) {
        for (int i4 = threadIdx.x; i4 < 384; i4 += 192) {
            float4 f0 = F4[off4 + i4];
            float4 f1 = F4[sq4 + off4 + i4];
            float4 f2 = F4[2 * sq4 + off4 + i4];
            float4 f3 = F4[3 * sq4 + off4 + i4];
            float4 f4v = F4[4 * sq4 + off4 + i4];
            float4 v;
            v.x = a0 * f0.x + a1 * f1.x + a2 * f2.x + a3 * f3.x + a4 * f4v.x;
            v.y = a0 * f0.y + a1 * f1.y + a2 * f2.y + a3 * f3.y + a4 * f4v.y;
            v.z = a0 * f0.z + a1 * f1.z + a2 * f2.z + a3 * f3.z + a4 * f4v.z;
            v.w = a0 * f0.w + a1 * f1.w + a2 * f2.w + a3 * f3.w + a4 * f4v.w;
            xc4[off4 + i4] = v;
            int r = i4 / 48, col = (i4 % 48) * 4;
            *(float4*)&rows[r * 196 + col] = v;
        }
    } else {
        for (int i4 = threadIdx.x; i4 < 384; i4 += 192) {
            float4 f0 = F4[off4 + i4];
            float4 f1 = F4[sq4 + off4 + i4];
            float4 v;
            v.x = a0 * f0.x + a1 * f1.x;
            v.y = a0 * f0.y + a1 * f1.y;
            v.z = a0 * f0.z + a1 * f1.z;
            v.w = a0 * f0.w + a1 * f1.w;
            if (n >= 3) {
                float4 f2 = F4[2 * sq4 + off4 + i4];
                v.x += a2 * f2.x; v.y += a2 * f2.y; v.z += a2 * f2.z; v.w += a2 * f2.w;
            }
            if (n >= 4) {
                float4 f3 = F4[3 * sq4 + off4 + i4];
                v.x += a3 * f3.x; v.y += a3 * f3.y; v.z += a3 * f3.z; v.w += a3 * f3.w;
            }
            xc4[off4 + i4] = v;
            int r = i4 / 48, col = (i4 % 48) * 4;
            *(float4*)&rows[r * 196 + col] = v;
        }
    }
    __syncthreads();
    int t = threadIdx.x;
    int r = t / 24, q = t % 24, ky = q >> 1, isim = q & 1;
    const float* tbp = tb + (isim ? (12 + ky) * 196 : ky * 196);
    const float* rowp = rows + r * 196;
    float a0s = 0.f, a1s = 0.f, a2s = 0.f, a3s = 0.f;
#pragma unroll
    for (int w2 = 0; w2 < WWc; w2 += 4) {
        a0s += rowp[w2] * tbp[w2];
        a1s += rowp[w2 + 1] * tbp[w2 + 1];
        a2s += rowp[w2 + 2] * tbp[w2 + 2];
        a3s += rowp[w2 + 3] * tbp[w2 + 3];
    }
    float acc = (a0s + a1s) + (a2s + a3s);
    if (isim) acc = -acc;
    int h = hg * 8 + r;
    Zc[(((size_t)ky * 128 + bc) * HHc + h) * 2 + isim] = acc;
}

// k_specA: H-DFT. grid 256 blocks, 192 threads, ~30KB LDS.
__global__ __launch_bounds__(192) void k_specA(const float* __restrict__ ZC,
                                               const float* __restrict__ tab,
                                               float* __restrict__ ZF) {
    int kyh = blockIdx.x & 1;
    int c = (blockIdx.x >> 1) & 31;
    int b = blockIdx.x >> 6;
    int bc = b * 32 + c;
    int ky0 = kyh * 6;
    __shared__ float zc[6 * 388];
    __shared__ float tcs[13 * 196];
    __shared__ float tsn[13 * 196];
    int t = threadIdx.x;
    for (int i4 = t; i4 < 576; i4 += 192) {
        int kyl = i4 / 96, r4 = (i4 % 96) * 4;
        *(float4*)&zc[kyl * 388 + r4] =
            *(const float4*)(ZC + (size_t)((ky0 + kyl) * 128 + bc) * 384 + r4);
    }
    for (int i4 = t; i4 < 1248; i4 += 192) {
        int half = i4 / 624, k = (i4 % 624) / 48, col = (i4 % 48) * 4;
        const float* src = tab + half * 2496 + k * 192 + col;
        float* dst = (half ? tsn : tcs) + k * 196 + col;
        *(float4*)dst = *(const float4*)src;
    }
    __syncthreads();
    if (t < 144) {
        int kyl = t / 24, j = t % 24;
        int k = (j < 12) ? j : 24 - j;
        float sgn = (j < 12) ? 1.f : -1.f;
        const float* zp = zc + kyl * 388;
        const float* cp = tcs + k * 196;
        const float* sp = tsn + k * 196;
        float re0 = 0.f, im0 = 0.f, re1 = 0.f, im1 = 0.f;
        for (int h = 0; h < 192; h += 2) {
            float zr = zp[h * 2], zi = zp[h * 2 + 1];
            float cv = cp[h], sv = sgn * sp[h];
            re0 += zr * cv + zi * sv;
            im0 += zi * cv - zr * sv;
            float zr1 = zp[h * 2 + 2], zi1 = zp[h * 2 + 3];
            float cv1 = cp[h + 1], sv1 = sgn * sp[h + 1];
            re1 += zr1 * cv1 + zi1 * sv1;
            im1 += zi1 * cv1 - zr1 * sv1;
        }
        size_t o = (((size_t)(b * 12 + ky0 + kyl) * 24 + j) * 32 + c) * 2;
        ZF[o] = re0 + re1;
        ZF[o + 1] = im0 + im1;
    }
}

// k_specB: mode-mix + iDFT-H. grid 192 blocks, 256 threads, ~17.5KB LDS.
__global__ __launch_bounds__(256) void k_specB(const float* __restrict__ ZF,
                                               const float* __restrict__ wt,
                                               const float* __restrict__ tab,
                                               float* __restrict__ Tm) {
    int hq = blockIdx.x & 3;
    int ky = (blockIdx.x >> 2) % 12;
    int b = blockIdx.x / 48;
    __shared__ float zf[24 * 64];
    __shared__ float mo[32 * 50];
    __shared__ float tcs[13 * 48];
    __shared__ float tsn[13 * 48];
    int t = threadIdx.x;
    const float4* zsrc = (const float4*)(ZF + (size_t)(b * 12 + ky) * 1536);
    for (int i4 = t; i4 < 384; i4 += 256)
        *(float4*)&zf[i4 * 4] = zsrc[i4];
    for (int i4 = t; i4 < 312; i4 += 256) {
        int half = i4 / 156, idx = i4 % 156;
        int k = idx / 12, col = (idx % 12) * 4;
        const float* src = tab + half * 2496 + k * 192 + hq * 48 + col;
        float* dst = (half ? tsn : tcs) + k * 48 + col;
        *(float4*)dst = *(const float4*)src;
    }
    __syncthreads();
    const float* wky = wt + (size_t)ky * 24 * 2048;
    for (int p = t; p < 768; p += 256) {
        int j = p / 32, o = p % 32;
        const float* wp = wky + (size_t)j * 2048 + o * 2;
        const float* zj = zf + j * 64;
        float re = 0.f, im = 0.f;
#pragma unroll 8
        for (int i = 0; i < 32; ++i) {
            float ar = zj[i * 2], ai = zj[i * 2 + 1];
            float wr = wp[i * 64], wi = wp[i * 64 + 1];
            re += ar * wr - ai * wi;
            im += ar * wi + ai * wr;
        }
        mo[o * 50 + j * 2] = re;
        mo[o * 50 + j * 2 + 1] = im;
    }
    __syncthreads();
    const float scale = 1.f / 192.f;
    for (int p = t; p < 1536; p += 256) {
        int o = p / 48, hl = p % 48;
        int h = hq * 48 + hl;
        const float* mp = mo + o * 50;
        float re = 0.f, im = 0.f;
#pragma unroll
        for (int j = 0; j < 24; ++j) {
            int k = (j < 12) ? j : 24 - j;
            float sgn = (j < 12) ? 1.f : -1.f;
            float mr = mp[j * 2], mi = mp[j * 2 + 1];
            float cv = tcs[k * 48 + hl], sv = sgn * tsn[k * 48 + hl];
            re += mr * cv - mi * sv;
            im += mr * sv + mi * cv;
        }
        float* dst = Tm + ((size_t)(b * 32 + o) * HHc + h) * 24 + ky * 2;
        dst[0] = re * scale;
        dst[1] = im * scale;
    }
}

// iDFT-W + y2(1x1 conv) + exact gelu + xi add -> sbuf; gn1 stats (sliced).
__global__ __launch_bounds__(384) void k_f5(const float* __restrict__ z0,
                                            const float* __restrict__ Tm,
                                            const float* __restrict__ xi,
                                            const float* __restrict__ w0w,
                                            const float* __restrict__ w0b,
                                            const float* __restrict__ tab,
                                            float* __restrict__ sbuf,
                                            float* __restrict__ stats_e,
                                            int use_y1) {
    int h = blockIdx.x % HHc;
    int b = blockIdx.x / HHc;
    __shared__ float zl[32 * 192];
    __shared__ float w0s[32 * 36];
    __shared__ float tms[32 * 28];
    __shared__ float redc[6][2];
    int tid = threadIdx.x;
    int oq = tid & 3;
    int wq = (tid >> 2) % 48;
    int oh = tid / 192;
    int w4 = wq * 4;
    int ob = oh * 16 + oq;

    if (z0) {
        const float* zp = z0 + (size_t)b * DDs + (size_t)h * WWc;
        for (int i4 = tid; i4 < 32 * 48; i4 += 384) {
            int c = i4 / 48, q = (i4 % 48) * 4;
            float4 v = *(const float4*)(zp + (size_t)c * HWc + q);
            *(float4*)&zl[c * 192 + q] = v;
        }
        if (tid < 256) {
            int oo = tid >> 3, q = (tid & 7) * 4;
            *(float4*)&w0s[oo * 36 + q] = *(const float4*)(w0w + oo * 32 + q);
        }
    }
    if (use_y1) {
        if (tid < 192) {
            int oo = tid / 6, q = (tid % 6) * 4;
            *(float4*)&tms[oo * 28 + q] =
                *(const float4*)(Tm + (((size_t)b * 32 + oo) * HHc + h) * 24 + q);
        }
    }
    float4 c1r = *(const float4*)(tab + 192 + w4);
    float4 s1r = *(const float4*)(tab + 2496 + 192 + w4);
    __syncthreads();

    const float Winv = 1.f / 192.f;
    float acc[4][4];
#pragma unroll
    for (int oo = 0; oo < 4; ++oo) {
        float bbv = w0b[ob + oo * 4];
#pragma unroll
        for (int k = 0; k < 4; ++k) acc[oo][k] = bbv;
    }
    if (use_y1) {
#pragma unroll
        for (int oo = 0; oo < 4; ++oo) {
            float t0 = tms[(ob + oo * 4) * 28];
#pragma unroll
            for (int k = 0; k < 4; ++k) acc[oo][k] += t0 * Winv;
        }
        float4 ck = c1r, sk = s1r;
        const float sc = 2.f * Winv;
#pragma unroll
        for (int ky = 1; ky <= 11; ++ky) {
#pragma unroll
            for (int oo = 0; oo < 4; ++oo) {
                int o = ob + oo * 4;
                float tre = tms[o * 28 + 2 * ky] * sc;
                float tim = tms[o * 28 + 2 * ky + 1] * sc;
                acc[oo][0] += tre * ck.x - tim * sk.x;
                acc[oo][1] += tre * ck.y - tim * sk.y;
                acc[oo][2] += tre * ck.z - tim * sk.z;
                acc[oo][3] += tre * ck.w - tim * sk.w;
            }
            if (ky < 11) {
                float4 cn, sn;
                cn.x = ck.x * c1r.x - sk.x * s1r.x;
                sn.x = sk.x * c1r.x + ck.x * s1r.x;
                cn.y = ck.y * c1r.y - sk.y * s1r.y;
                sn.y = sk.y * c1r.y + ck.y * s1r.y;
                cn.z = ck.z * c1r.z - sk.z * s1r.z;
                sn.z = sk.z * c1r.z + ck.z * s1r.z;
                cn.w = ck.w * c1r.w - sk.w * s1r.w;
                sn.w = sk.w * c1r.w + ck.w * s1r.w;
                ck = cn; sk = sn;
            }
        }
    }
    if (z0) {
#pragma unroll 2
        for (int c = 0; c < 32; c += 4) {
            float4 wv[4];
#pragma unroll
            for (int oo = 0; oo < 4; ++oo)
                wv[oo] = *(const float4*)&w0s[(ob + oo * 4) * 36 + c];
#pragma unroll
            for (int k = 0; k < 4; ++k) {
                float4 z4 = *(const float4*)&zl[(c + k) * 192 + w4];
#pragma unroll
                for (int oo = 0; oo < 4; ++oo) {
                    float wvk = ((const float*)&wv[oo])[k];
                    acc[oo][0] += z4.x * wvk;
                    acc[oo][1] += z4.y * wvk;
                    acc[oo][2] += z4.z * wvk;
                    acc[oo][3] += z4.w * wvk;
                }
            }
        }
    }
    float4 xv[4];
#pragma unroll
    for (int oo = 0; oo < 4; ++oo) {
        int o = ob + oo * 4;
        xv[oo] = *(const float4*)(xi + (size_t)b * DDs + (size_t)o * HWc +
                                  (size_t)h * WWc + w4);
    }
    float s = 0.f, q = 0.f;
#pragma unroll
    for (int oo = 0; oo < 4; ++oo) {
        int o = ob + oo * 4;
        size_t gi = (size_t)b * DDs + (size_t)o * HWc + (size_t)h * WWc + w4;
        float4 out4;
        float* op = (float*)&out4;
        const float* xp = (const float*)&xv[oo];
#pragma unroll
        for (int k = 0; k < 4; ++k) {
            float v = acc[oo][k];
            float u = 0.5f * v * (1.f + erff(v * 0.70710678118654752f));
            float sv = xp[k] + u;
            op[k] = sv;
            s += sv;
            q += sv * sv;
        }
        *(float4*)(sbuf + gi) = out4;
    }
    for (int o2 = 32; o2; o2 >>= 1) {
        s += __shfl_down(s, o2);
        q += __shfl_down(q, o2);
    }
    int wid = tid >> 6, lane = tid & 63;
    if (lane == 0) { redc[wid][0] = s; redc[wid][1] = q; }
    __syncthreads();
    if (tid == 0) {
        float s0 = redc[0][0] + redc[1][0] + redc[2][0];
        float q0 = redc[0][1] + redc[1][1] + redc[2][1];
        float s1 = redc[3][0] + redc[4][0] + redc[5][0];
        float q1 = redc[3][1] + redc[4][1] + redc[5][1];
        int slice = blockIdx.x & (NSLICE - 1);
        float* st = stats_e + slice * 32;
        atomicAdd(&st[b * 4 + 0], s0);
        atomicAdd(&st[b * 4 + 1], q0);
        atomicAdd(&st[b * 4 + 2], s1);
        atomicAdd(&st[b * 4 + 3], q1);
    }
}

// buf = relu(z + GN1(buf)) IN PLACE; gn2 stats (sliced); zero gram slot slices.
__global__ __launch_bounds__(256) void k_f6(const float* __restrict__ z0,
                                            float* buf,
                                            float* __restrict__ stats_e,
                                            const float* __restrict__ n1w,
                                            const float* __restrict__ n1b,
                                            float* __restrict__ gram,
                                            int slot) {
    {
        int gid = blockIdx.x * 256 + threadIdx.x;
        if (gid < NGSLICE * 20) {
            int s2 = gid / 20, r = gid % 20;
            int j = r % 5, b2 = r / 5;
            int ii = slot > j ? slot : j, jj = slot > j ? j : slot;
            gram[s2 * 60 + b2 * 15 + ii * (ii + 1) / 2 + jj] = 0.f;
        }
    }
    const int binq = 147456;
    const int BPB = 144;
    int bin = blockIdx.x / BPB, sub = blockIdx.x % BPB;
    float Nv = 16.f * HWc;
    float su = 0.f, sq = 0.f;
    for (int s2 = 0; s2 < NSLICE; ++s2) {
        su += stats_e[s2 * 32 + bin * 2];
        sq += stats_e[s2 * 32 + bin * 2 + 1];
    }
    float mu = su / Nv;
    float var = sq / Nv - mu * mu;
    float inv = rsqrtf(var + EPSc);
    const float4* z4 = (const float4*)z0;
    float4* b4 = (float4*)buf;
    float s = 0.f, q = 0.f;
    for (int i4 = sub * 256 + threadIdx.x; i4 < binq; i4 += BPB * 256) {
        int e4 = bin * binq + i4;
        int c = (bin & 1) * 16 + i4 / 9216;
        float w1 = inv * n1w[c];
        float b1 = n1b[c] - mu * w1;
        float4 sv = b4[e4];
        float4 zv = make_float4(0.f, 0.f, 0.f, 0.f);
        if (z0) zv = z4[e4];
        float4 r;
        r.x = zv.x + sv.x * w1 + b1; r.x = r.x > 0.f ? r.x : 0.f;
        r.y = zv.y + sv.y * w1 + b1; r.y = r.y > 0.f ? r.y : 0.f;
        r.z = zv.z + sv.z * w1 + b1; r.z = r.z > 0.f ? r.z : 0.f;
        r.w = zv.w + sv.w * w1 + b1; r.w = r.w > 0.f ? r.w : 0.f;
        b4[e4] = r;
        s += r.x + r.y + r.z + r.w;
        q += r.x * r.x + r.y * r.y + r.z * r.z + r.w * r.w;
    }
    for (int o = 32; o; o >>= 1) { s += __shfl_down(s, o); q += __shfl_down(q, o); }
    __shared__ float rs[4], rq[4];
    int wid = threadIdx.x >> 6, lane = threadIdx.x & 63;
    if (lane == 0) { rs[wid] = s; rq[wid] = q; }
    __syncthreads();
    if (threadIdx.x == 0) {
        int slice = blockIdx.x & (NSLICE - 1);
        atomicAdd(&stats_e[slice * 32 + 16 + bin * 2], rs[0] + rs[1] + rs[2] + rs[3]);
        atomicAdd(&stats_e[slice * 32 + 16 + bin * 2 + 1], rq[0] + rq[1] + rq[2] + rq[3]);
    }
}

// buf = GN2(buf) IN PLACE; G[slot] = bf16(buf - z); sliced Gram.
// nvalid = number of valid G slots (skip uninitialized bf16 history in early
// evals). nvalid == 0 => no gram work at all (final eval).
__global__ __launch_bounds__(256) void k_f7g(float* buf,
                                             const float* __restrict__ z,
                                             const float* __restrict__ stats_e,
                                             const float* __restrict__ n2w,
                                             const float* __restrict__ n2b,
                                             unsigned short* __restrict__ G,
                                             float* __restrict__ gram,
                                             int slot, int nvalid) {
    int b = blockIdx.x / 288, sub = blockIdx.x % 288;
    const float Ninv = 1.f / (16.f * HWc);
    float su0 = 0.f, sq0 = 0.f, su1 = 0.f, sq1 = 0.f;
    for (int s2 = 0; s2 < NSLICE; ++s2) {
        const float* st = stats_e + s2 * 32 + 16 + b * 4;
        su0 += st[0]; sq0 += st[1]; su1 += st[2]; sq1 += st[3];
    }
    float mu0 = su0 * Ninv, inv0 = rsqrtf(sq0 * Ninv - mu0 * mu0 + EPSc);
    float mu1 = su1 * Ninv, inv1 = rsqrtf(sq1 * Ninv - mu1 * mu1 + EPSc);
    const int bq = 294912;
    const int sq4 = 1179648;
    float4* b4 = (float4*)buf;
    const float4* z4 = (const float4*)z;
    ushort4* GU = (ushort4*)G;
    float p0 = 0, p1 = 0, p2 = 0, p3 = 0, p4 = 0;
    for (int loc4 = sub * 256 + threadIdx.x; loc4 < bq; loc4 += 73728) {
        int e4 = b * bq + loc4;
        int c = loc4 / 9216;
        float mu = (c < 16) ? mu0 : mu1;
        float inv = (c < 16) ? inv0 : inv1;
        float wv = inv * n2w[c];
        float bv = n2b[c] - mu * wv;
        float4 r = b4[e4];
        float4 fn;
        fn.x = r.x * wv + bv;
        fn.y = r.y * wv + bv;
        fn.z = r.z * wv + bv;
        fn.w = r.w * wv + bv;
        b4[e4] = fn;
        if (nvalid) {
            float4 zv = make_float4(0.f, 0.f, 0.f, 0.f);
            if (z) zv = z4[e4];
            float4 g;
            g.x = fn.x - zv.x; g.y = fn.y - zv.y; g.z = fn.z - zv.z; g.w = fn.w - zv.w;
            ushort4 gw;
            gw.x = f2bf(g.x); gw.y = f2bf(g.y); gw.z = f2bf(g.z); gw.w = f2bf(g.w);
            GU[(size_t)slot * sq4 + e4] = gw;
            float4 gj[5];
#pragma unroll
            for (int j = 0; j < 5; ++j) {
                if (j >= nvalid) { gj[j] = make_float4(0.f, 0.f, 0.f, 0.f); }
                else if (j == slot) { gj[j] = g; }
                else {
                    ushort4 u = GU[(size_t)j * sq4 + e4];
                    gj[j].x = bf2f(u.x); gj[j].y = bf2f(u.y);
                    gj[j].z = bf2f(u.z); gj[j].w = bf2f(u.w);
                }
            }
            p0 += g.x * gj[0].x + g.y * gj[0].y + g.z * gj[0].z + g.w * gj[0].w;
            p1 += g.x * gj[1].x + g.y * gj[1].y + g.z * gj[1].z + g.w * gj[1].w;
            p2 += g.x * gj[2].x + g.y * gj[2].y + g.z * gj[2].z + g.w * gj[2].w;
            p3 += g.x * gj[3].x + g.y * gj[3].y + g.z * gj[3].z + g.w * gj[3].w;
            p4 += g.x * gj[4].x + g.y * gj[4].y + g.z * gj[4].z + g.w * gj[4].w;
        }
    }
    if (!nvalid) return;
    float p[5] = {p0, p1, p2, p3, p4};
    __shared__ float red[4][5];
    int wid = threadIdx.x >> 6, lane = threadIdx.x & 63;
#pragma unroll
    for (int j = 0; j < 5; ++j) {
        float v = p[j];
        for (int o = 32; o; o >>= 1) v += __shfl_down(v, o);
        if (lane == 0) red[wid][j] = v;
    }
    __syncthreads();
    if (threadIdx.x == 0) {
        int gsl = (blockIdx.x & (NGSLICE - 1)) * 60;
#pragma unroll
        for (int j = 0; j < 5; ++j) {
            if (j >= nvalid) continue;
            int ii = slot > j ? slot : j, jj = slot > j ? j : slot;
            atomicAdd(&gram[gsl + b * 15 + ii * (ii + 1) / 2 + jj],
                      red[0][j] + red[1][j] + red[2][j] + red[3][j]);
        }
    }
}

// ---------------- final: BN stats + BN + fc1(gelu) + fc2 ----------------
__global__ __launch_bounds__(256) void k_bnstats(const float* __restrict__ z,
                                                 float* __restrict__ bstats) {
    const int BPB = 18;
    int c = blockIdx.x / BPB, sub = blockIdx.x % BPB;
    float s = 0.f, q = 0.f;
    for (int i = sub * 256 + threadIdx.x; i < BBc * HWc; i += BPB * 256) {
        int b = i / HWc, hw = i % HWc;
        float v = z[(size_t)b * DDs + (size_t)c * HWc + hw];
        s += v;
        q += v * v;
    }
    for (int o = 32; o; o >>= 1) { s += __shfl_down(s, o); q += __shfl_down(q, o); }
    __shared__ float rs[4], rq[4];
    int wid = threadIdx.x >> 6, lane = threadIdx.x & 63;
    if (lane == 0) { rs[wid] = s; rq[wid] = q; }
    __syncthreads();
    if (threadIdx.x == 0) {
        atomicAdd(&bstats[c * 2], rs[0] + rs[1] + rs[2] + rs[3]);
        atomicAdd(&bstats[c * 2 + 1], rq[0] + rq[1] + rq[2] + rq[3]);
    }
}

__global__ __launch_bounds__(192) void k_final(const float* __restrict__ z,
                                               const float* __restrict__ bstats,
                                               const float* __restrict__ bnw,
                                               const float* __restrict__ bnb,
                                               const float* __restrict__ fc1w,
                                               const float* __restrict__ fc1b,
                                               const float* __restrict__ fc2w,
                                               const float* __restrict__ fc2b,
                                               float* __restrict__ out) {
    int b = blockIdx.x / HHc, h = blockIdx.x % HHc;
    int w = threadIdx.x;
    const float Ninv = 1.f / ((float)BBc * HWc);
    float zv[32];
#pragma unroll
    for (int c = 0; c < 32; ++c) {
        float su = bstats[c * 2], sq = bstats[c * 2 + 1];
        float mu = su * Ninv;
        float var = sq * Ninv - mu * mu;
        float inv = rsqrtf(var + EPSc);
        float v = z[(size_t)b * DDs + (size_t)c * HWc + (size_t)h * WWc + w];
        zv[c] = (v - mu) * inv * bnw[c] + bnb[c];
    }
    float acc2 = fc2b[0];
#pragma unroll
    for (int o = 0; o < 32; ++o) {
        float a = fc1b[o];
        const float* row = fc1w + o * 32;
#pragma unroll
        for (int c = 0; c < 32; ++c) a += zv[c] * row[c];
        float g = 0.5f * a * (1.f + erff(a * 0.70710678118654752f));
        acc2 += fc2w[o] * g;
    }
    out[(size_t)b * HWc + (size_t)h * WWc + w] = acc2;
}

// ---------------- host ----------------
extern "C" void kernel_launch(void* const* d_in, const int* in_sizes, int n_in,
                              void* d_out, int out_size, void* d_ws, size_t ws_size,
                              hipStream_t stream) {
    (void)in_sizes; (void)n_in; (void)out_size; (void)ws_size;
    const float* x    = (const float*)d_in[0];
    const float* fc0w = (const float*)d_in[1];
    const float* fc0b = (const float*)d_in[2];
    const float* convw = (const float*)d_in[3];
    const float* gnw  = (const float*)d_in[4];
    const float* gnb  = (const float*)d_in[5];
    const float* qw   = (const float*)d_in[6];
    const float* qb   = (const float*)d_in[7];
    const float* sw1r = (const float*)d_in[8];
    const float* sw1i = (const float*)d_in[9];
    const float* sw2r = (const float*)d_in[10];
    const float* sw2i = (const float*)d_in[11];
    const float* w0w  = (const float*)d_in[12];
    const float* w0b  = (const float*)d_in[13];
    const float* n1w  = (const float*)d_in[14];
    const float* n1b  = (const float*)d_in[15];
    const float* n2w  = (const float*)d_in[16];
    const float* n2b  = (const float*)d_in[17];
    const float* bnw  = (const float*)d_in[18];
    const float* bnb  = (const float*)d_in[19];
    const float* fc1w = (const float*)d_in[20];
    const float* fc1b = (const float*)d_in[21];
    const float* fc2w = (const float*)d_in[22];
    const float* fc2b = (const float*)d_in[23];
    float* out = (float*)d_out;

    float* ws = (float*)d_ws;
    float* XC  = ws + OFF_XC;
    float* XIp = ws + OFF_XI;
    float* Fb  = ws + OFF_F;
    unsigned short* Gb16 = (unsigned short*)(ws + OFF_G);
    float* ZC  = ws + OFF_ZC;
    float* ZFp = ws + OFF_ZF;
    float* MOp = ws + OFF_MO;
    float* TM  = ws + OFF_TM;
    float* WT  = ws + OFF_WT;
    float* TAB = ws + OFF_TAB;
    float* ST  = ws + OFF_STAT;
    float* XI0 = ws + A_XI0;   // setup alias (inside G region)
    float* EWB = MOp;          // setup alias

    auto runtail = [&](const float* zin, int outslot, int use_y1, int evalIdx,
                       int nvalid) {
        float* dst = Fb + (size_t)outslot * SZ_T;
        if (use_y1) {
            k_specA<<<256, 192, 0, stream>>>(ZC, TAB, ZFp);
            k_specB<<<BBc * 12 * 4, 256, 0, stream>>>(ZFp, WT, TAB, TM);
        }
        float* stats_e = ST + (size_t)evalIdx * ST_EV;
        k_f5<<<BBc * HHc, 384, 0, stream>>>(zin, TM, XIp, w0w, w0b, TAB, dst,
                                            stats_e, use_y1);
        k_f6<<<8 * 144, 256, 0, stream>>>(zin, dst, stats_e, n1w, n1b,
                                          ST + ST_GRAM, outslot);
        k_f7g<<<4 * 288, 256, 0, stream>>>(dst, zin, stats_e, n2w, n2b, Gb16,
                                           ST + ST_GRAM, outslot, nvalid);
    };

    // setup
    k_tables<<<10, 256, 0, stream>>>(TAB);
    k_wt<<<(24 * 12 * 1024 + 255) / 256, 256, 0, stream>>>(sw1r, sw1i, sw2r, sw2i, WT);
    k_zero<<<(ST_TOTAL + 255) / 256, 256, 0, stream>>>(ST, ST_TOTAL);
    k_ew<<<1, 192, 0, stream>>>(convw, fc0w, fc0b, EWB);
    k_conv2<<<BBc * HHc, 192, 0, stream>>>(x, EWB, XI0);
    k_binstats<<<8 * 36, 256, 0, stream>>>(XI0, ST + ST_INJ, 8 * HWc, 36);
    k_xi<<<BBc * HHc, 192, 0, stream>>>(XI0, ST + ST_INJ, gnw, gnb, qw, qb, XIp);

    // f0 = f(0) -> F0, G0, Gram(0,0): only slot 0 valid
    runtail(nullptr, 0, 0, 0, 1);
    // f1 = f(F0): plain dftw on F0; slots 0,1 valid
    k_dftw<<<BBc * CCc * 24, 192, 0, stream>>>(Fb, TAB, ZC);
    runtail(Fb, 1, 1, 1, 2);

    // Anderson iterations k = 2..15: fused solve+xnew+dftw -> rest
    for (int k = 2; k < 16; ++k) {
        int n = k < 5 ? k : 5;
        int slot = k % 5;
        int nv = (k < 15) ? ((k + 1 < 5) ? (k + 1) : 5) : 0;
        k_dftwx<<<BBc * CCc * 24, 192, 0, stream>>>(Fb, ST + ST_GRAM, TAB, XC, ZC, n);
        runtail(XC, slot, 1, k, nv);
    }

    // final z = F slot 0; BatchNorm + fc1(gelu) + fc2
    k_bnstats<<<32 * 18, 256, 0, stream>>>(Fb, ST + ST_BN);
    k_final<<<BBc * HHc, 192, 0, stream>>>(Fb, ST + ST_BN, bnw, bnb, fc1w, fc1b,
                                           fc2w, fc2b, out);
}

// Round 14
// 1713.790 us; speedup vs baseline: 1.0399x; 1.0182x over previous
//
#include <hip/hip_runtime.h>
#include <hip/hip_fp16.h>
#include <math.h>

#ifndef M_PI
#define M_PI 3.14159265358979323846
#endif

#define BBc 4
#define CCc 32
#define NRk 16
#define HHc 192
#define WWc 192
#define HWc 36864
#define DDi 1179648
#define M1c 12
#define EPSc 1e-5f

static const size_t DDs = (size_t)DDi;

// ---------------- workspace layout (floats) ----------------
#define SZ_T   ((size_t)4718592)       // B*C*HW  (= B*D)
#define SZ_ZC  ((size_t)589824)        // 12ky*4b*32c*192h*2  (ky-major)
#define SZ_ZF  ((size_t)73728)         // 4b*12ky*24j*32c*2 (specA->specB)
#define SZ_WT  ((size_t)589824)        // ky-major
#define SZ_TAB ((size_t)4992)          // 13*192*2

#define OFF_XC   ((size_t)0)
#define OFF_XI   (OFF_XC + SZ_T)
#define OFF_F    (OFF_XI + SZ_T)              // f32 scratch: FS0, FS1
#define OFF_G    (OFF_F + 5 * SZ_T)           // [0,2.5T): G bf16; [2.5T,5T): FH fp16
#define OFF_ZC   (OFF_G + 5 * SZ_T)
#define OFF_ZF   (OFF_ZC + SZ_ZC)
#define OFF_MO   (OFF_ZF + SZ_ZF)             // setup alias only
#define OFF_TM   (OFF_MO + SZ_ZF)
#define OFF_WT   (OFF_TM + SZ_ZC)
#define OFF_TAB  (OFF_WT + SZ_WT)
#define OFF_STAT (OFF_TAB + SZ_TAB)
#define A_XI0  OFF_G                   // setup alias (dead before first G write)

// ---- stats sublayout: sliced accumulators (round 4, confirmed -34%) ----
// NOTE (rounds 7-8): cooperative-kernel fusion FAILS in this harness
// (hipLaunchCooperativeKernel incompatible with hipGraph capture). Do NOT retry.
// NOTE (round 10): stats-only f6 + GN1-recompute in f7g was NET-WORSE (+18us).
// NOTE (round 12): bf16 F-history FAILS numerics (absmax 0.78 = 3.6x thresh;
// Anderson alpha are extrapolation coeffs, sum|a|~3-5, error compounds).
// ROUND 14: fp16 F-history (eps 8x smaller than bf16) -> predicted added
// error ~0.10 < 0.2175 thresh. dftwx history reads halved; working set
// 220 -> 175 MB. Pre-commit: fail => r13 f32 version is final.
#define NSLICE  32
#define NGSLICE 16
#define ST_EV   1024
#define ST_INJ   (16 * ST_EV)
#define ST_BN    (ST_INJ + 16)
#define ST_GRAM  (ST_BN + 64)
#define ST_ALPHA (ST_GRAM + NGSLICE * 60)
#define ST_TOTAL (ST_ALPHA + 20)

// bf16 helpers (RNE) — used for G history (unchanged, proven)
__device__ __forceinline__ float bf2f(unsigned short u) {
    return __uint_as_float(((unsigned int)u) << 16);
}
__device__ __forceinline__ unsigned short f2bf(float f) {
    unsigned int u = __float_as_uint(f);
    unsigned int r = (u + 0x7FFFu + ((u >> 16) & 1u)) >> 16;
    return (unsigned short)r;
}
// fp16 helpers (RNE) — used for F history (round 14)
__device__ __forceinline__ unsigned short f2h(float f) {
    __half h = __float2half_rn(f);
    return *reinterpret_cast<unsigned short*>(&h);
}
__device__ __forceinline__ float h2f(unsigned short u) {
    __half h = *reinterpret_cast<__half*>(&u);
    return __half2float(h);
}

// ---------------- small utility kernels ----------------
__global__ void k_zero(float* p, int n) {
    int i = blockIdx.x * blockDim.x + threadIdx.x;
    if (i < n) p[i] = 0.f;
}

__global__ void k_tables(float* tab) {
    int i = blockIdx.x * blockDim.x + threadIdx.x;  // 13*192
    if (i < 13 * 192) {
        int k = i / 192, x = i % 192;
        double th = 2.0 * M_PI * (double)(k * x) / 192.0;
        tab[i] = (float)cos(th);
        tab[13 * 192 + i] = (float)sin(th);
    }
}

// transpose spectral weights to wt[ky][j][i][o][2]
__global__ void k_wt(const float* __restrict__ w1r, const float* __restrict__ w1i,
                     const float* __restrict__ w2r, const float* __restrict__ w2i,
                     float* __restrict__ wt) {
    int idx = blockIdx.x * 256 + threadIdx.x;  // 24*12*32*32
    if (idx >= 24 * 12 * 1024) return;
    int o = idx & 31;
    int i = (idx >> 5) & 31;
    int ky = (idx >> 10) % 12;
    int j = idx / (12 * 1024);
    const float* wr;
    const float* wi;
    int x;
    if (j < 12) { wr = w1r; wi = w1i; x = j; }
    else        { wr = w2r; wi = w2i; x = j - 12; }
    int src = ((i * 32 + o) * 12 + x) * 12 + ky;
    size_t dst = (((size_t)ky * 24 + j) * 1024 + i * 32 + o) * 2;
    wt[dst] = wr[src];
    wt[dst + 1] = wi[src];
}

// effective single-channel conv weights
__global__ void k_ew(const float* __restrict__ cw, const float* __restrict__ fc0w,
                     const float* __restrict__ fc0b, float* __restrict__ ewb) {
    int i = threadIdx.x;  // 144 = 16 n x 9 taps
    if (i >= 144) return;
    int n = i / 9, t = i % 9;
    float ew = 0.f, eb = 0.f;
    for (int c = 0; c < 32; ++c) {
        float k = cw[(size_t)(n * CCc + c) * 9 + t];
        ew += k * fc0w[c];
        eb += k * fc0b[c];
    }
    ewb[i] = ew;
    ewb[144 + i] = eb;
}

// conv3x3 SAME on rank-1 input via effective kernels
__global__ __launch_bounds__(192) void k_conv2(const float* __restrict__ x,
                                               const float* __restrict__ ewb,
                                               float* __restrict__ xi0) {
    int b = blockIdx.x / HHc, h = blockIdx.x % HHc;
    __shared__ float sm[3 * 194];
    __shared__ float ews[144], ebs[144];
    int w = threadIdx.x;
    for (int i = threadIdx.x; i < 3 * 194; i += 192) {
        int r = i / 194, col = (i % 194) - 1;
        int hr = h + r - 1;
        float v = 0.f;
        if (hr >= 0 && hr < HHc && col >= 0 && col < WWc)
            v = x[(size_t)b * HWc + (size_t)hr * WWc + col];
        sm[i] = v;
    }
    if (threadIdx.x < 144) {
        ews[threadIdx.x] = ewb[threadIdx.x];
        ebs[threadIdx.x] = ewb[144 + threadIdx.x];
    }
    __syncthreads();
    float xv[9], mk[9];
#pragma unroll
    for (int r = 0; r < 3; ++r) {
        int hr = h + r - 1;
        bool rok = (hr >= 0 && hr < HHc);
#pragma unroll
        for (int dx = 0; dx < 3; ++dx) {
            int wx = w + dx - 1;
            bool ok = rok && (wx >= 0) && (wx < WWc);
            xv[r * 3 + dx] = sm[r * 194 + (w + dx)];
            mk[r * 3 + dx] = ok ? 1.f : 0.f;
        }
    }
#pragma unroll
    for (int n = 0; n < 16; ++n) {
        float acc = 0.f;
#pragma unroll
        for (int t = 0; t < 9; ++t)
            acc += ews[n * 9 + t] * xv[t] + mk[t] * ebs[n * 9 + t];
        xi0[((size_t)b * NRk + n) * HWc + (size_t)h * WWc + w] = acc;
    }
}

// generic contiguous-bin sum/sumsq with atomics (setup only)
__global__ void k_binstats(const float* __restrict__ src, float* __restrict__ stats,
                           int binsize, int blocksPerBin) {
    int bin = blockIdx.x / blocksPerBin, sub = blockIdx.x % blocksPerBin;
    const float* p = src + (size_t)bin * binsize;
    float s = 0.f, q = 0.f;
    for (int i = sub * blockDim.x + threadIdx.x; i < binsize; i += blocksPerBin * blockDim.x) {
        float v = p[i];
        s += v;
        q += v * v;
    }
    for (int o = 32; o; o >>= 1) { s += __shfl_down(s, o); q += __shfl_down(q, o); }
    __shared__ float rs[4], rq[4];
    int wid = threadIdx.x >> 6, lane = threadIdx.x & 63;
    if (lane == 0) { rs[wid] = s; rq[wid] = q; }
    __syncthreads();
    if (threadIdx.x == 0) {
        int nw = blockDim.x >> 6;
        float ts = 0.f, tq = 0.f;
        for (int i = 0; i < nw; ++i) { ts += rs[i]; tq += rq[i]; }
        atomicAdd(&stats[bin * 2], ts);
        atomicAdd(&stats[bin * 2 + 1], tq);
    }
}

// xi = sigmoid(q_w * GN(xi0) + q_b)
__global__ __launch_bounds__(192) void k_xi(const float* __restrict__ xi0,
                                            const float* __restrict__ stats,
                                            const float* __restrict__ gnw, const float* __restrict__ gnb,
                                            const float* __restrict__ qw, const float* __restrict__ qb,
                                            float* __restrict__ xi) {
    int b = blockIdx.x / HHc, h = blockIdx.x % HHc;
    int w = threadIdx.x;
    const float Ninv = 1.f / (8.f * HWc);
    float tn[16];
#pragma unroll
    for (int n = 0; n < 16; ++n) {
        int g = n >> 3;
        float su = stats[(b * 2 + g) * 2], sq = stats[(b * 2 + g) * 2 + 1];
        float mu = su * Ninv;
        float var = sq * Ninv - mu * mu;
        float inv = rsqrtf(var + EPSc);
        float v = xi0[((size_t)b * NRk + n) * HWc + (size_t)h * WWc + w];
        tn[n] = (v - mu) * inv * gnw[n] + gnb[n];
    }
#pragma unroll
    for (int d = 0; d < 32; ++d) {
        float acc = qb[d];
        const float* row = qw + d * 16;
#pragma unroll
        for (int n = 0; n < 16; ++n) acc += tn[n] * row[n];
        xi[((size_t)b * CCc + d) * HWc + (size_t)h * WWc + w] = 1.f / (1.f + expf(-acc));
    }
}

// ---------------- DFT chain ----------------
// ZC layout: [ky][b][c][h][2]; write: ZC[((ky*128 + bc)*192 + h)*2 + isim]

// plain forward DFT along W (eval 1, z = FS0, f32)
__global__ __launch_bounds__(192) void k_dftw(const float* __restrict__ z0,
                                              const float* __restrict__ tab,
                                              float* __restrict__ Zc) {
    int bc = blockIdx.x / 24;
    int hg = blockIdx.x % 24;
    int b = bc >> 5, c = bc & 31;
    const float* zp = z0 + (size_t)b * DDs + (size_t)c * HWc + (size_t)hg * 8 * WWc;
    __shared__ float rows[8 * 196];
    __shared__ float tb[24 * 196];
    const float4* zq = (const float4*)zp;
    for (int i4 = threadIdx.x; i4 < 384; i4 += 192) {
        float4 v = zq[i4];
        int r = i4 / 48, col = (i4 % 48) * 4;
        *(float4*)&rows[r * 196 + col] = v;
    }
    for (int i4 = threadIdx.x; i4 < 1152; i4 += 192) {
        int rr = i4 / 48, col = (i4 % 48) * 4;
        const float* src = (rr < 12) ? &tab[rr * 192 + col] : &tab[2496 + (rr - 12) * 192 + col];
        *(float4*)&tb[rr * 196 + col] = *(const float4*)src;
    }
    __syncthreads();
    int t = threadIdx.x;
    int r = t / 24, q = t % 24, ky = q >> 1, isim = q & 1;
    const float* tbp = tb + (isim ? (12 + ky) * 196 : ky * 196);
    const float* rowp = rows + r * 196;
    float a0 = 0.f, a1 = 0.f, a2 = 0.f, a3 = 0.f;
#pragma unroll
    for (int w2 = 0; w2 < WWc; w2 += 4) {
        a0 += rowp[w2] * tbp[w2];
        a1 += rowp[w2 + 1] * tbp[w2 + 1];
        a2 += rowp[w2 + 2] * tbp[w2 + 2];
        a3 += rowp[w2 + 3] * tbp[w2 + 3];
    }
    float acc = (a0 + a1) + (a2 + a3);
    if (isim) acc = -acc;
    int h = hg * 8 + r;
    Zc[(((size_t)ky * 128 + bc) * HHc + h) * 2 + isim] = acc;
}

// FUSED alpha-solve + xnew + forward W-DFT.
// Round 14: F history read as fp16 (FH); skips slots with alpha==0.
__global__ __launch_bounds__(192) void k_dftwx(const unsigned short* __restrict__ FH,
                                               const float* __restrict__ gram,
                                               const float* __restrict__ tab,
                                               float* __restrict__ xc,
                                               float* __restrict__ Zc,
                                               int n) {
    int bc = blockIdx.x / 24;
    int hg = blockIdx.x % 24;
    int b = bc >> 5, c = bc & 31;
    __shared__ float rows[8 * 196];
    __shared__ float tb[24 * 196];
    __shared__ float gs[15];
    __shared__ float alf[5];
    for (int i4 = threadIdx.x; i4 < 1152; i4 += 192) {
        int rr = i4 / 48, col = (i4 % 48) * 4;
        const float* src = (rr < 12) ? &tab[rr * 192 + col] : &tab[2496 + (rr - 12) * 192 + col];
        *(float4*)&tb[rr * 196 + col] = *(const float4*)src;
    }
    if (threadIdx.x < 15) {
        float v = 0.f;
        for (int s2 = 0; s2 < NGSLICE; ++s2) v += gram[s2 * 60 + b * 15 + threadIdx.x];
        gs[threadIdx.x] = v;
    }
    __syncthreads();
    if (threadIdx.x == 0) {
        float H[5][5];
#pragma unroll
        for (int i = 0; i < 5; ++i)
#pragma unroll
            for (int j = 0; j <= i; ++j) {
                float v;
                if (i < n && j < n) v = gs[i * (i + 1) / 2 + j] + ((i == j) ? 1e-4f : 0.f);
                else                v = (i == j) ? 1.f : 0.f;
                H[i][j] = v;
                H[j][i] = v;
            }
        float L[5][5], D[5], w[5], y[5];
#pragma unroll
        for (int j = 0; j < 5; ++j) {
            float d = H[j][j];
#pragma unroll
            for (int k2 = 0; k2 < j; ++k2) d -= L[j][k2] * L[j][k2] * D[k2];
            D[j] = d;
#pragma unroll
            for (int i = j + 1; i < 5; ++i) {
                float v = H[i][j];
#pragma unroll
                for (int k2 = 0; k2 < j; ++k2) v -= L[i][k2] * L[j][k2] * D[k2];
                L[i][j] = v / d;
            }
        }
#pragma unroll
        for (int i = 0; i < 5; ++i) {
            float v = (i < n) ? 1.f : 0.f;
#pragma unroll
            for (int k2 = 0; k2 < i; ++k2) v -= L[i][k2] * w[k2];
            w[i] = v;
        }
#pragma unroll
        for (int i = 4; i >= 0; --i) {
            float v = w[i] / D[i];
#pragma unroll
            for (int k2 = i + 1; k2 < 5; ++k2) v -= L[k2][i] * y[k2];
            y[i] = v;
        }
        float sum = y[0] + y[1] + y[2] + y[3] + y[4];
        float inv = 1.f / sum;
#pragma unroll
        for (int j = 0; j < 5; ++j) alf[j] = (j < n) ? y[j] * inv : 0.f;
    }
    __syncthreads();
    float a0 = alf[0], a1 = alf[1], a2 = alf[2], a3 = alf[3], a4 = alf[4];

    size_t elem = (size_t)b * DDs + (size_t)c * HWc + (size_t)hg * 8 * WWc;
    int off4 = (int)(elem >> 2);
    const int sq4 = 1179648;  // ushort4s per FH slot (SZ_T/4)
    const ushort4* F4 = (const ushort4*)FH;
    float4* xc4 = (float4*)xc;
    if (n == 5) {
        for (int i4 = threadIdx.x; i4 < 384; i4 += 192) {
            ushort4 u0 = F4[off4 + i4];
            ushort4 u1 = F4[sq4 + off4 + i4];
            ushort4 u2 = F4[2 * sq4 + off4 + i4];
            ushort4 u3 = F4[3 * sq4 + off4 + i4];
            ushort4 u4 = F4[4 * sq4 + off4 + i4];
            float4 v;
            v.x = a0 * h2f(u0.x) + a1 * h2f(u1.x) + a2 * h2f(u2.x) + a3 * h2f(u3.x) + a4 * h2f(u4.x);
            v.y = a0 * h2f(u0.y) + a1 * h2f(u1.y) + a2 * h2f(u2.y) + a3 * h2f(u3.y) + a4 * h2f(u4.y);
            v.z = a0 * h2f(u0.z) + a1 * h2f(u1.z) + a2 * h2f(u2.z) + a3 * h2f(u3.z) + a4 * h2f(u4.z);
            v.w = a0 * h2f(u0.w) + a1 * h2f(u1.w) + a2 * h2f(u2.w) + a3 * h2f(u3.w) + a4 * h2f(u4.w);
            xc4[off4 + i4] = v;
            int r = i4 / 48, col = (i4 % 48) * 4;
            *(float4*)&rows[r * 196 + col] = v;
        }
    } else {
        for (int i4 = threadIdx.x; i4 < 384; i4 += 192) {
            ushort4 u0 = F4[off4 + i4];
            ushort4 u1 = F4[sq4 + off4 + i4];
            float4 v;
            v.x = a0 * h2f(u0.x) + a1 * h2f(u1.x);
            v.y = a0 * h2f(u0.y) + a1 * h2f(u1.y);
            v.z = a0 * h2f(u0.z) + a1 * h2f(u1.z);
            v.w = a0 * h2f(u0.w) + a1 * h2f(u1.w);
            if (n >= 3) {
                ushort4 u2 = F4[2 * sq4 + off4 + i4];
                v.x += a2 * h2f(u2.x); v.y += a2 * h2f(u2.y);
                v.z += a2 * h2f(u2.z); v.w += a2 * h2f(u2.w);
            }
            if (n >= 4) {
                ushort4 u3 = F4[3 * sq4 + off4 + i4];
                v.x += a3 * h2f(u3.x); v.y += a3 * h2f(u3.y);
                v.z += a3 * h2f(u3.z); v.w += a3 * h2f(u3.w);
            }
            xc4[off4 + i4] = v;
            int r = i4 / 48, col = (i4 % 48) * 4;
            *(float4*)&rows[r * 196 + col] = v;
        }
    }
    __syncthreads();
    int t = threadIdx.x;
    int r = t / 24, q = t % 24, ky = q >> 1, isim = q & 1;
    const float* tbp = tb + (isim ? (12 + ky) * 196 : ky * 196);
    const float* rowp = rows + r * 196;
    float a0s = 0.f, a1s = 0.f, a2s = 0.f, a3s = 0.f;
#pragma unroll
    for (int w2 = 0; w2 < WWc; w2 += 4) {
        a0s += rowp[w2] * tbp[w2];
        a1s += rowp[w2 + 1] * tbp[w2 + 1];
        a2s += rowp[w2 + 2] * tbp[w2 + 2];
        a3s += rowp[w2 + 3] * tbp[w2 + 3];
    }
    float acc = (a0s + a1s) + (a2s + a3s);
    if (isim) acc = -acc;
    int h = hg * 8 + r;
    Zc[(((size_t)ky * 128 + bc) * HHc + h) * 2 + isim] = acc;
}

// k_specA: H-DFT. grid 256 blocks, 192 threads, ~30KB LDS.
__global__ __launch_bounds__(192) void k_specA(const float* __restrict__ ZC,
                                               const float* __restrict__ tab,
                                               float* __restrict__ ZF) {
    int kyh = blockIdx.x & 1;
    int c = (blockIdx.x >> 1) & 31;
    int b = blockIdx.x >> 6;
    int bc = b * 32 + c;
    int ky0 = kyh * 6;
    __shared__ float zc[6 * 388];
    __shared__ float tcs[13 * 196];
    __shared__ float tsn[13 * 196];
    int t = threadIdx.x;
    for (int i4 = t; i4 < 576; i4 += 192) {
        int kyl = i4 / 96, r4 = (i4 % 96) * 4;
        *(float4*)&zc[kyl * 388 + r4] =
            *(const float4*)(ZC + (size_t)((ky0 + kyl) * 128 + bc) * 384 + r4);
    }
    for (int i4 = t; i4 < 1248; i4 += 192) {
        int half = i4 / 624, k = (i4 % 624) / 48, col = (i4 % 48) * 4;
        const float* src = tab + half * 2496 + k * 192 + col;
        float* dst = (half ? tsn : tcs) + k * 196 + col;
        *(float4*)dst = *(const float4*)src;
    }
    __syncthreads();
    if (t < 144) {
        int kyl = t / 24, j = t % 24;
        int k = (j < 12) ? j : 24 - j;
        float sgn = (j < 12) ? 1.f : -1.f;
        const float* zp = zc + kyl * 388;
        const float* cp = tcs + k * 196;
        const float* sp = tsn + k * 196;
        float re0 = 0.f, im0 = 0.f, re1 = 0.f, im1 = 0.f;
        for (int h = 0; h < 192; h += 2) {
            float zr = zp[h * 2], zi = zp[h * 2 + 1];
            float cv = cp[h], sv = sgn * sp[h];
            re0 += zr * cv + zi * sv;
            im0 += zi * cv - zr * sv;
            float zr1 = zp[h * 2 + 2], zi1 = zp[h * 2 + 3];
            float cv1 = cp[h + 1], sv1 = sgn * sp[h + 1];
            re1 += zr1 * cv1 + zi1 * sv1;
            im1 += zi1 * cv1 - zr1 * sv1;
        }
        size_t o = (((size_t)(b * 12 + ky0 + kyl) * 24 + j) * 32 + c) * 2;
        ZF[o] = re0 + re1;
        ZF[o + 1] = im0 + im1;
    }
}

// k_specB: mode-mix + iDFT-H. grid 192 blocks, 256 threads, ~17.5KB LDS.
__global__ __launch_bounds__(256) void k_specB(const float* __restrict__ ZF,
                                               const float* __restrict__ wt,
                                               const float* __restrict__ tab,
                                               float* __restrict__ Tm) {
    int hq = blockIdx.x & 3;
    int ky = (blockIdx.x >> 2) % 12;
    int b = blockIdx.x / 48;
    __shared__ float zf[24 * 64];
    __shared__ float mo[32 * 50];
    __shared__ float tcs[13 * 48];
    __shared__ float tsn[13 * 48];
    int t = threadIdx.x;
    const float4* zsrc = (const float4*)(ZF + (size_t)(b * 12 + ky) * 1536);
    for (int i4 = t; i4 < 384; i4 += 256)
        *(float4*)&zf[i4 * 4] = zsrc[i4];
    for (int i4 = t; i4 < 312; i4 += 256) {
        int half = i4 / 156, idx = i4 % 156;
        int k = idx / 12, col = (idx % 12) * 4;
        const float* src = tab + half * 2496 + k * 192 + hq * 48 + col;
        float* dst = (half ? tsn : tcs) + k * 48 + col;
        *(float4*)dst = *(const float4*)src;
    }
    __syncthreads();
    const float* wky = wt + (size_t)ky * 24 * 2048;
    for (int p = t; p < 768; p += 256) {
        int j = p / 32, o = p % 32;
        const float* wp = wky + (size_t)j * 2048 + o * 2;
        const float* zj = zf + j * 64;
        float re = 0.f, im = 0.f;
#pragma unroll 8
        for (int i = 0; i < 32; ++i) {
            float ar = zj[i * 2], ai = zj[i * 2 + 1];
            float wr = wp[i * 64], wi = wp[i * 64 + 1];
            re += ar * wr - ai * wi;
            im += ar * wi + ai * wr;
        }
        mo[o * 50 + j * 2] = re;
        mo[o * 50 + j * 2 + 1] = im;
    }
    __syncthreads();
    const float scale = 1.f / 192.f;
    for (int p = t; p < 1536; p += 256) {
        int o = p / 48, hl = p % 48;
        int h = hq * 48 + hl;
        const float* mp = mo + o * 50;
        float re = 0.f, im = 0.f;
#pragma unroll
        for (int j = 0; j < 24; ++j) {
            int k = (j < 12) ? j : 24 - j;
            float sgn = (j < 12) ? 1.f : -1.f;
            float mr = mp[j * 2], mi = mp[j * 2 + 1];
            float cv = tcs[k * 48 + hl], sv = sgn * tsn[k * 48 + hl];
            re += mr * cv - mi * sv;
            im += mr * sv + mi * cv;
        }
        float* dst = Tm + ((size_t)(b * 32 + o) * HHc + h) * 24 + ky * 2;
        dst[0] = re * scale;
        dst[1] = im * scale;
    }
}

// iDFT-W + y2(1x1 conv) + exact gelu + xi add -> sbuf; gn1 stats (sliced).
__global__ __launch_bounds__(384) void k_f5(const float* __restrict__ z0,
                                            const float* __restrict__ Tm,
                                            const float* __restrict__ xi,
                                            const float* __restrict__ w0w,
                                            const float* __restrict__ w0b,
                                            const float* __restrict__ tab,
                                            float* __restrict__ sbuf,
                                            float* __restrict__ stats_e,
                                            int use_y1) {
    int h = blockIdx.x % HHc;
    int b = blockIdx.x / HHc;
    __shared__ float zl[32 * 192];
    __shared__ float w0s[32 * 36];
    __shared__ float tms[32 * 28];
    __shared__ float redc[6][2];
    int tid = threadIdx.x;
    int oq = tid & 3;
    int wq = (tid >> 2) % 48;
    int oh = tid / 192;
    int w4 = wq * 4;
    int ob = oh * 16 + oq;

    if (z0) {
        const float* zp = z0 + (size_t)b * DDs + (size_t)h * WWc;
        for (int i4 = tid; i4 < 32 * 48; i4 += 384) {
            int c = i4 / 48, q = (i4 % 48) * 4;
            float4 v = *(const float4*)(zp + (size_t)c * HWc + q);
            *(float4*)&zl[c * 192 + q] = v;
        }
        if (tid < 256) {
            int oo = tid >> 3, q = (tid & 7) * 4;
            *(float4*)&w0s[oo * 36 + q] = *(const float4*)(w0w + oo * 32 + q);
        }
    }
    if (use_y1) {
        if (tid < 192) {
            int oo = tid / 6, q = (tid % 6) * 4;
            *(float4*)&tms[oo * 28 + q] =
                *(const float4*)(Tm + (((size_t)b * 32 + oo) * HHc + h) * 24 + q);
        }
    }
    float4 c1r = *(const float4*)(tab + 192 + w4);
    float4 s1r = *(const float4*)(tab + 2496 + 192 + w4);
    __syncthreads();

    const float Winv = 1.f / 192.f;
    float acc[4][4];
#pragma unroll
    for (int oo = 0; oo < 4; ++oo) {
        float bbv = w0b[ob + oo * 4];
#pragma unroll
        for (int k = 0; k < 4; ++k) acc[oo][k] = bbv;
    }
    if (use_y1) {
#pragma unroll
        for (int oo = 0; oo < 4; ++oo) {
            float t0 = tms[(ob + oo * 4) * 28];
#pragma unroll
            for (int k = 0; k < 4; ++k) acc[oo][k] += t0 * Winv;
        }
        float4 ck = c1r, sk = s1r;
        const float sc = 2.f * Winv;
#pragma unroll
        for (int ky = 1; ky <= 11; ++ky) {
#pragma unroll
            for (int oo = 0; oo < 4; ++oo) {
                int o = ob + oo * 4;
                float tre = tms[o * 28 + 2 * ky] * sc;
                float tim = tms[o * 28 + 2 * ky + 1] * sc;
                acc[oo][0] += tre * ck.x - tim * sk.x;
                acc[oo][1] += tre * ck.y - tim * sk.y;
                acc[oo][2] += tre * ck.z - tim * sk.z;
                acc[oo][3] += tre * ck.w - tim * sk.w;
            }
            if (ky < 11) {
                float4 cn, sn;
                cn.x = ck.x * c1r.x - sk.x * s1r.x;
                sn.x = sk.x * c1r.x + ck.x * s1r.x;
                cn.y = ck.y * c1r.y - sk.y * s1r.y;
                sn.y = sk.y * c1r.y + ck.y * s1r.y;
                cn.z = ck.z * c1r.z - sk.z * s1r.z;
                sn.z = sk.z * c1r.z + ck.z * s1r.z;
                cn.w = ck.w * c1r.w - sk.w * s1r.w;
                sn.w = sk.w * c1r.w + ck.w * s1r.w;
                ck = cn; sk = sn;
            }
        }
    }
    if (z0) {
#pragma unroll 2
        for (int c = 0; c < 32; c += 4) {
            float4 wv[4];
#pragma unroll
            for (int oo = 0; oo < 4; ++oo)
                wv[oo] = *(const float4*)&w0s[(ob + oo * 4) * 36 + c];
#pragma unroll
            for (int k = 0; k < 4; ++k) {
                float4 z4 = *(const float4*)&zl[(c + k) * 192 + w4];
#pragma unroll
                for (int oo = 0; oo < 4; ++oo) {
                    float wvk = ((const float*)&wv[oo])[k];
                    acc[oo][0] += z4.x * wvk;
                    acc[oo][1] += z4.y * wvk;
                    acc[oo][2] += z4.z * wvk;
                    acc[oo][3] += z4.w * wvk;
                }
            }
        }
    }
    float4 xv[4];
#pragma unroll
    for (int oo = 0; oo < 4; ++oo) {
        int o = ob + oo * 4;
        xv[oo] = *(const float4*)(xi + (size_t)b * DDs + (size_t)o * HWc +
                                  (size_t)h * WWc + w4);
    }
    float s = 0.f, q = 0.f;
#pragma unroll
    for (int oo = 0; oo < 4; ++oo) {
        int o = ob + oo * 4;
        size_t gi = (size_t)b * DDs + (size_t)o * HWc + (size_t)h * WWc + w4;
        float4 out4;
        float* op = (float*)&out4;
        const float* xp = (const float*)&xv[oo];
#pragma unroll
        for (int k = 0; k < 4; ++k) {
            float v = acc[oo][k];
            float u = 0.5f * v * (1.f + erff(v * 0.70710678118654752f));
            float sv = xp[k] + u;
            op[k] = sv;
            s += sv;
            q += sv * sv;
        }
        *(float4*)(sbuf + gi) = out4;
    }
    for (int o2 = 32; o2; o2 >>= 1) {
        s += __shfl_down(s, o2);
        q += __shfl_down(q, o2);
    }
    int wid = tid >> 6, lane = tid & 63;
    if (lane == 0) { redc[wid][0] = s; redc[wid][1] = q; }
    __syncthreads();
    if (tid == 0) {
        float s0 = redc[0][0] + redc[1][0] + redc[2][0];
        float q0 = redc[0][1] + redc[1][1] + redc[2][1];
        float s1 = redc[3][0] + redc[4][0] + redc[5][0];
        float q1 = redc[3][1] + redc[4][1] + redc[5][1];
        int slice = blockIdx.x & (NSLICE - 1);
        float* st = stats_e + slice * 32;
        atomicAdd(&st[b * 4 + 0], s0);
        atomicAdd(&st[b * 4 + 1], q0);
        atomicAdd(&st[b * 4 + 2], s1);
        atomicAdd(&st[b * 4 + 3], q1);
    }
}

// buf = relu(z + GN1(buf)) IN PLACE; gn2 stats (sliced); zero gram slot slices.
__global__ __launch_bounds__(256) void k_f6(const float* __restrict__ z0,
                                            float* buf,
                                            float* __restrict__ stats_e,
                                            const float* __restrict__ n1w,
                                            const float* __restrict__ n1b,
                                            float* __restrict__ gram,
                                            int slot) {
    {
        int gid = blockIdx.x * 256 + threadIdx.x;
        if (gid < NGSLICE * 20) {
            int s2 = gid / 20, r = gid % 20;
            int j = r % 5, b2 = r / 5;
            int ii = slot > j ? slot : j, jj = slot > j ? j : slot;
            gram[s2 * 60 + b2 * 15 + ii * (ii + 1) / 2 + jj] = 0.f;
        }
    }
    const int binq = 147456;
    const int BPB = 144;
    int bin = blockIdx.x / BPB, sub = blockIdx.x % BPB;
    float Nv = 16.f * HWc;
    float su = 0.f, sq = 0.f;
    for (int s2 = 0; s2 < NSLICE; ++s2) {
        su += stats_e[s2 * 32 + bin * 2];
        sq += stats_e[s2 * 32 + bin * 2 + 1];
    }
    float mu = su / Nv;
    float var = sq / Nv - mu * mu;
    float inv = rsqrtf(var + EPSc);
    const float4* z4 = (const float4*)z0;
    float4* b4 = (float4*)buf;
    float s = 0.f, q = 0.f;
    for (int i4 = sub * 256 + threadIdx.x; i4 < binq; i4 += BPB * 256) {
        int e4 = bin * binq + i4;
        int c = (bin & 1) * 16 + i4 / 9216;
        float w1 = inv * n1w[c];
        float b1 = n1b[c] - mu * w1;
        float4 sv = b4[e4];
        float4 zv = make_float4(0.f, 0.f, 0.f, 0.f);
        if (z0) zv = z4[e4];
        float4 r;
        r.x = zv.x + sv.x * w1 + b1; r.x = r.x > 0.f ? r.x : 0.f;
        r.y = zv.y + sv.y * w1 + b1; r.y = r.y > 0.f ? r.y : 0.f;
        r.z = zv.z + sv.z * w1 + b1; r.z = r.z > 0.f ? r.z : 0.f;
        r.w = zv.w + sv.w * w1 + b1; r.w = r.w > 0.f ? r.w : 0.f;
        b4[e4] = r;
        s += r.x + r.y + r.z + r.w;
        q += r.x * r.x + r.y * r.y + r.z * r.z + r.w * r.w;
    }
    for (int o = 32; o; o >>= 1) { s += __shfl_down(s, o); q += __shfl_down(q, o); }
    __shared__ float rs[4], rq[4];
    int wid = threadIdx.x >> 6, lane = threadIdx.x & 63;
    if (lane == 0) { rs[wid] = s; rq[wid] = q; }
    __syncthreads();
    if (threadIdx.x == 0) {
        int slice = blockIdx.x & (NSLICE - 1);
        atomicAdd(&stats_e[slice * 32 + 16 + bin * 2], rs[0] + rs[1] + rs[2] + rs[3]);
        atomicAdd(&stats_e[slice * 32 + 16 + bin * 2 + 1], rq[0] + rq[1] + rq[2] + rq[3]);
    }
}

// buf = GN2(buf) IN PLACE; FH[slot] = fp16(buf); G[slot] = bf16(buf - z);
// sliced Gram. nvalid = valid G slots (0 => last eval: no history writes).
__global__ __launch_bounds__(256) void k_f7g(float* buf,
                                             const float* __restrict__ z,
                                             const float* __restrict__ stats_e,
                                             const float* __restrict__ n2w,
                                             const float* __restrict__ n2b,
                                             unsigned short* __restrict__ G,
                                             unsigned short* __restrict__ FH,
                                             float* __restrict__ gram,
                                             int slot, int nvalid) {
    int b = blockIdx.x / 288, sub = blockIdx.x % 288;
    const float Ninv = 1.f / (16.f * HWc);
    float su0 = 0.f, sq0 = 0.f, su1 = 0.f, sq1 = 0.f;
    for (int s2 = 0; s2 < NSLICE; ++s2) {
        const float* st = stats_e + s2 * 32 + 16 + b * 4;
        su0 += st[0]; sq0 += st[1]; su1 += st[2]; sq1 += st[3];
    }
    float mu0 = su0 * Ninv, inv0 = rsqrtf(sq0 * Ninv - mu0 * mu0 + EPSc);
    float mu1 = su1 * Ninv, inv1 = rsqrtf(sq1 * Ninv - mu1 * mu1 + EPSc);
    const int bq = 294912;
    const int sq4 = 1179648;
    float4* b4 = (float4*)buf;
    const float4* z4 = (const float4*)z;
    ushort4* GU = (ushort4*)G;
    ushort4* FU = (ushort4*)FH;
    float p0 = 0, p1 = 0, p2 = 0, p3 = 0, p4 = 0;
    for (int loc4 = sub * 256 + threadIdx.x; loc4 < bq; loc4 += 73728) {
        int e4 = b * bq + loc4;
        int c = loc4 / 9216;
        float mu = (c < 16) ? mu0 : mu1;
        float inv = (c < 16) ? inv0 : inv1;
        float wv = inv * n2w[c];
        float bv = n2b[c] - mu * wv;
        float4 r = b4[e4];
        float4 fn;
        fn.x = r.x * wv + bv;
        fn.y = r.y * wv + bv;
        fn.z = r.z * wv + bv;
        fn.w = r.w * wv + bv;
        b4[e4] = fn;
        if (nvalid) {
            ushort4 fw;
            fw.x = f2h(fn.x); fw.y = f2h(fn.y); fw.z = f2h(fn.z); fw.w = f2h(fn.w);
            FU[(size_t)slot * sq4 + e4] = fw;
            float4 zv = make_float4(0.f, 0.f, 0.f, 0.f);
            if (z) zv = z4[e4];
            float4 g;
            g.x = fn.x - zv.x; g.y = fn.y - zv.y; g.z = fn.z - zv.z; g.w = fn.w - zv.w;
            ushort4 gw;
            gw.x = f2bf(g.x); gw.y = f2bf(g.y); gw.z = f2bf(g.z); gw.w = f2bf(g.w);
            GU[(size_t)slot * sq4 + e4] = gw;
            float4 gj[5];
#pragma unroll
            for (int j = 0; j < 5; ++j) {
                if (j >= nvalid) { gj[j] = make_float4(0.f, 0.f, 0.f, 0.f); }
                else if (j == slot) { gj[j] = g; }
                else {
                    ushort4 u = GU[(size_t)j * sq4 + e4];
                    gj[j].x = bf2f(u.x); gj[j].y = bf2f(u.y);
                    gj[j].z = bf2f(u.z); gj[j].w = bf2f(u.w);
                }
            }
            p0 += g.x * gj[0].x + g.y * gj[0].y + g.z * gj[0].z + g.w * gj[0].w;
            p1 += g.x * gj[1].x + g.y * gj[1].y + g.z * gj[1].z + g.w * gj[1].w;
            p2 += g.x * gj[2].x + g.y * gj[2].y + g.z * gj[2].z + g.w * gj[2].w;
            p3 += g.x * gj[3].x + g.y * gj[3].y + g.z * gj[3].z + g.w * gj[3].w;
            p4 += g.x * gj[4].x + g.y * gj[4].y + g.z * gj[4].z + g.w * gj[4].w;
        }
    }
    if (!nvalid) return;
    float p[5] = {p0, p1, p2, p3, p4};
    __shared__ float red[4][5];
    int wid = threadIdx.x >> 6, lane = threadIdx.x & 63;
#pragma unroll
    for (int j = 0; j < 5; ++j) {
        float v = p[j];
        for (int o = 32; o; o >>= 1) v += __shfl_down(v, o);
        if (lane == 0) red[wid][j] = v;
    }
    __syncthreads();
    if (threadIdx.x == 0) {
        int gsl = (blockIdx.x & (NGSLICE - 1)) * 60;
#pragma unroll
        for (int j = 0; j < 5; ++j) {
            if (j >= nvalid) continue;
            int ii = slot > j ? slot : j, jj = slot > j ? j : slot;
            atomicAdd(&gram[gsl + b * 15 + ii * (ii + 1) / 2 + jj],
                      red[0][j] + red[1][j] + red[2][j] + red[3][j]);
        }
    }
}

// ---------------- final: BN stats + BN + fc1(gelu) + fc2 ----------------
__global__ __launch_bounds__(256) void k_bnstats(const float* __restrict__ z,
                                                 float* __restrict__ bstats) {
    const int BPB = 18;
    int c = blockIdx.x / BPB, sub = blockIdx.x % BPB;
    float s = 0.f, q = 0.f;
    for (int i = sub * 256 + threadIdx.x; i < BBc * HWc; i += BPB * 256) {
        int b = i / HWc, hw = i % HWc;
        float v = z[(size_t)b * DDs + (size_t)c * HWc + hw];
        s += v;
        q += v * v;
    }
    for (int o = 32; o; o >>= 1) { s += __shfl_down(s, o); q += __shfl_down(q, o); }
    __shared__ float rs[4], rq[4];
    int wid = threadIdx.x >> 6, lane = threadIdx.x & 63;
    if (lane == 0) { rs[wid] = s; rq[wid] = q; }
    __syncthreads();
    if (threadIdx.x == 0) {
        atomicAdd(&bstats[c * 2], rs[0] + rs[1] + rs[2] + rs[3]);
        atomicAdd(&bstats[c * 2 + 1], rq[0] + rq[1] + rq[2] + rq[3]);
    }
}

__global__ __launch_bounds__(192) void k_final(const float* __restrict__ z,
                                               const float* __restrict__ bstats,
                                               const float* __restrict__ bnw,
                                               const float* __restrict__ bnb,
                                               const float* __restrict__ fc1w,
                                               const float* __restrict__ fc1b,
                                               const float* __restrict__ fc2w,
                                               const float* __restrict__ fc2b,
                                               float* __restrict__ out) {
    int b = blockIdx.x / HHc, h = blockIdx.x % HHc;
    int w = threadIdx.x;
    const float Ninv = 1.f / ((float)BBc * HWc);
    float zv[32];
#pragma unroll
    for (int c = 0; c < 32; ++c) {
        float su = bstats[c * 2], sq = bstats[c * 2 + 1];
        float mu = su * Ninv;
        float var = sq * Ninv - mu * mu;
        float inv = rsqrtf(var + EPSc);
        float v = z[(size_t)b * DDs + (size_t)c * HWc + (size_t)h * WWc + w];
        zv[c] = (v - mu) * inv * bnw[c] + bnb[c];
    }
    float acc2 = fc2b[0];
#pragma unroll
    for (int o = 0; o < 32; ++o) {
        float a = fc1b[o];
        const float* row = fc1w + o * 32;
#pragma unroll
        for (int c = 0; c < 32; ++c) a += zv[c] * row[c];
        float g = 0.5f * a * (1.f + erff(a * 0.70710678118654752f));
        acc2 += fc2w[o] * g;
    }
    out[(size_t)b * HWc + (size_t)h * WWc + w] = acc2;
}

// ---------------- host ----------------
extern "C" void kernel_launch(void* const* d_in, const int* in_sizes, int n_in,
                              void* d_out, int out_size, void* d_ws, size_t ws_size,
                              hipStream_t stream) {
    (void)in_sizes; (void)n_in; (void)out_size; (void)ws_size;
    const float* x    = (const float*)d_in[0];
    const float* fc0w = (const float*)d_in[1];
    const float* fc0b = (const float*)d_in[2];
    const float* convw = (const float*)d_in[3];
    const float* gnw  = (const float*)d_in[4];
    const float* gnb  = (const float*)d_in[5];
    const float* qw   = (const float*)d_in[6];
    const float* qb   = (const float*)d_in[7];
    const float* sw1r = (const float*)d_in[8];
    const float* sw1i = (const float*)d_in[9];
    const float* sw2r = (const float*)d_in[10];
    const float* sw2i = (const float*)d_in[11];
    const float* w0w  = (const float*)d_in[12];
    const float* w0b  = (const float*)d_in[13];
    const float* n1w  = (const float*)d_in[14];
    const float* n1b  = (const float*)d_in[15];
    const float* n2w  = (const float*)d_in[16];
    const float* n2b  = (const float*)d_in[17];
    const float* bnw  = (const float*)d_in[18];
    const float* bnb  = (const float*)d_in[19];
    const float* fc1w = (const float*)d_in[20];
    const float* fc1b = (const float*)d_in[21];
    const float* fc2w = (const float*)d_in[22];
    const float* fc2b = (const float*)d_in[23];
    float* out = (float*)d_out;

    float* ws = (float*)d_ws;
    float* XC  = ws + OFF_XC;
    float* XIp = ws + OFF_XI;
    float* FS0 = ws + OFF_F;                 // f32 scratch slot 0
    float* FS1 = ws + OFF_F + SZ_T;          // f32 scratch slot 1 (eval 1 only)
    unsigned short* Gb16 = (unsigned short*)(ws + OFF_G);
    unsigned short* FH16 = (unsigned short*)(ws + OFF_G + 5 * (SZ_T / 2)); // fp16 F history
    float* ZC  = ws + OFF_ZC;
    float* ZFp = ws + OFF_ZF;
    float* MOp = ws + OFF_MO;
    float* TM  = ws + OFF_TM;
    float* WT  = ws + OFF_WT;
    float* TAB = ws + OFF_TAB;
    float* ST  = ws + OFF_STAT;
    float* XI0 = ws + A_XI0;   // setup alias (inside G region)
    float* EWB = MOp;          // setup alias

    auto runtail = [&](const float* zin, float* dst, int use_y1, int evalIdx,
                       int slot, int nvalid) {
        if (use_y1) {
            k_specA<<<256, 192, 0, stream>>>(ZC, TAB, ZFp);
            k_specB<<<BBc * 12 * 4, 256, 0, stream>>>(ZFp, WT, TAB, TM);
        }
        float* stats_e = ST + (size_t)evalIdx * ST_EV;
        k_f5<<<BBc * HHc, 384, 0, stream>>>(zin, TM, XIp, w0w, w0b, TAB, dst,
                                            stats_e, use_y1);
        k_f6<<<8 * 144, 256, 0, stream>>>(zin, dst, stats_e, n1w, n1b,
                                          ST + ST_GRAM, slot);
        k_f7g<<<4 * 288, 256, 0, stream>>>(dst, zin, stats_e, n2w, n2b, Gb16,
                                           FH16, ST + ST_GRAM, slot, nvalid);
    };

    // setup
    k_tables<<<10, 256, 0, stream>>>(TAB);
    k_wt<<<(24 * 12 * 1024 + 255) / 256, 256, 0, stream>>>(sw1r, sw1i, sw2r, sw2i, WT);
    k_zero<<<(ST_TOTAL + 255) / 256, 256, 0, stream>>>(ST, ST_TOTAL);
    k_ew<<<1, 192, 0, stream>>>(convw, fc0w, fc0b, EWB);
    k_conv2<<<BBc * HHc, 192, 0, stream>>>(x, EWB, XI0);
    k_binstats<<<8 * 36, 256, 0, stream>>>(XI0, ST + ST_INJ, 8 * HWc, 36);
    k_xi<<<BBc * HHc, 192, 0, stream>>>(XI0, ST + ST_INJ, gnw, gnb, qw, qb, XIp);

    // f0 = f(0) -> FS0 (+ FH[0] fp16); only slot 0 valid
    runtail(nullptr, FS0, 0, 0, 0, 1);
    // f1 = f(F0): dftw on FS0 (f32); z = FS0, dst = FS1; slots 0,1 valid
    k_dftw<<<BBc * CCc * 24, 192, 0, stream>>>(FS0, TAB, ZC);
    runtail(FS0, FS1, 1, 1, 1, 2);

    // Anderson iterations k = 2..15: fused solve+xnew(fp16 FH)+dftw -> rest
    // dst = FS0 (reused f32 scratch; FH holds history). Eval 15 -> FS0 = final z.
    for (int k = 2; k < 16; ++k) {
        int n = k < 5 ? k : 5;
        int slot = k % 5;
        int nv = (k < 15) ? ((k + 1 < 5) ? (k + 1) : 5) : 0;
        k_dftwx<<<BBc * CCc * 24, 192, 0, stream>>>(FH16, ST + ST_GRAM, TAB, XC, ZC, n);
        runtail(XC, FS0, 1, k, slot, nv);
    }

    // final z = FS0; BatchNorm + fc1(gelu) + fc2
    k_bnstats<<<32 * 18, 256, 0, stream>>>(FS0, ST + ST_BN);
    k_final<<<BBc * HHc, 192, 0, stream>>>(FS0, ST + ST_BN, bnw, bnb, fc1w, fc1b,
                                           fc2w, fc2b, out);
}

// Round 16
// 1710.737 us; speedup vs baseline: 1.0417x; 1.0018x over previous
//
#include <hip/hip_runtime.h>
#include <hip/hip_fp16.h>
#include <math.h>

#ifndef M_PI
#define M_PI 3.14159265358979323846
#endif

#define BBc 4
#define CCc 32
#define NRk 16
#define HHc 192
#define WWc 192
#define HWc 36864
#define DDi 1179648
#define M1c 12
#define EPSc 1e-5f

static const size_t DDs = (size_t)DDi;

// ---------------- workspace layout (floats) ----------------
#define SZ_T   ((size_t)4718592)       // B*C*HW  (= B*D)
#define SZ_ZC  ((size_t)589824)        // 12ky*4b*32c*192h*2  (ky-major)
#define SZ_ZF  ((size_t)73728)         // 4b*12ky*24j*32c*2 (specA->specB)
#define SZ_WT  ((size_t)589824)        // ky-major
#define SZ_TAB ((size_t)4992)          // 13*192*2

#define OFF_XC   ((size_t)0)
#define OFF_XI   (OFF_XC + SZ_T)
#define OFF_F    (OFF_XI + SZ_T)              // f32 scratch: FS0, FS1
#define OFF_G    (OFF_F + 5 * SZ_T)           // [0,2.5T): G bf16; [2.5T,5T): FH fp16
#define OFF_ZC   (OFF_G + 5 * SZ_T)
#define OFF_ZF   (OFF_ZC + SZ_ZC)
#define OFF_MO   (OFF_ZF + SZ_ZF)             // setup alias only
#define OFF_TM   (OFF_MO + SZ_ZF)
#define OFF_WT   (OFF_TM + SZ_ZC)
#define OFF_TAB  (OFF_WT + SZ_WT)
#define OFF_STAT (OFF_TAB + SZ_TAB)
#define A_XI0  OFF_G                   // setup alias (dead before first G write)

// ---- stats sublayout: sliced accumulators (round 4, confirmed -34%) ----
// NOTE (rounds 7-8): cooperative-kernel fusion FAILS in this harness
// (hipLaunchCooperativeKernel incompatible with hipGraph capture). Do NOT retry.
// NOTE (round 10): stats-only f6 + GN1-recompute in f7g was NET-WORSE (+18us).
// NOTE (round 12): bf16 F-history FAILS numerics (0.78 vs 0.22 thresh).
// ROUND 14 (FINAL, passed, absmax 0.135, 1713.8us): fp16 F-history — error
// scaled linearly with storage eps as predicted.
// NOTE (round 15): fp16 xi FAILS numerics (0.96): any perturbation injected
// inside the fixed-point loop is amplified ~3000x ((I-J)^-1 ill-conditioned).
// NO further precision reductions are viable.
#define NSLICE  32
#define NGSLICE 16
#define ST_EV   1024
#define ST_INJ   (16 * ST_EV)
#define ST_BN    (ST_INJ + 16)
#define ST_GRAM  (ST_BN + 64)
#define ST_ALPHA (ST_GRAM + NGSLICE * 60)
#define ST_TOTAL (ST_ALPHA + 20)

// bf16 helpers (RNE) — used for G history
__device__ __forceinline__ float bf2f(unsigned short u) {
    return __uint_as_float(((unsigned int)u) << 16);
}
__device__ __forceinline__ unsigned short f2bf(float f) {
    unsigned int u = __float_as_uint(f);
    unsigned int r = (u + 0x7FFFu + ((u >> 16) & 1u)) >> 16;
    return (unsigned short)r;
}
// fp16 helpers (RNE) — used for F history
__device__ __forceinline__ unsigned short f2h(float f) {
    __half h = __float2half_rn(f);
    return *reinterpret_cast<unsigned short*>(&h);
}
__device__ __forceinline__ float h2f(unsigned short u) {
    __half h = *reinterpret_cast<__half*>(&u);
    return __half2float(h);
}

// ---------------- small utility kernels ----------------
__global__ void k_zero(float* p, int n) {
    int i = blockIdx.x * blockDim.x + threadIdx.x;
    if (i < n) p[i] = 0.f;
}

__global__ void k_tables(float* tab) {
    int i = blockIdx.x * blockDim.x + threadIdx.x;  // 13*192
    if (i < 13 * 192) {
        int k = i / 192, x = i % 192;
        double th = 2.0 * M_PI * (double)(k * x) / 192.0;
        tab[i] = (float)cos(th);
        tab[13 * 192 + i] = (float)sin(th);
    }
}

// transpose spectral weights to wt[ky][j][i][o][2]
__global__ void k_wt(const float* __restrict__ w1r, const float* __restrict__ w1i,
                     const float* __restrict__ w2r, const float* __restrict__ w2i,
                     float* __restrict__ wt) {
    int idx = blockIdx.x * 256 + threadIdx.x;  // 24*12*32*32
    if (idx >= 24 * 12 * 1024) return;
    int o = idx & 31;
    int i = (idx >> 5) & 31;
    int ky = (idx >> 10) % 12;
    int j = idx / (12 * 1024);
    const float* wr;
    const float* wi;
    int x;
    if (j < 12) { wr = w1r; wi = w1i; x = j; }
    else        { wr = w2r; wi = w2i; x = j - 12; }
    int src = ((i * 32 + o) * 12 + x) * 12 + ky;
    size_t dst = (((size_t)ky * 24 + j) * 1024 + i * 32 + o) * 2;
    wt[dst] = wr[src];
    wt[dst + 1] = wi[src];
}

// effective single-channel conv weights
__global__ void k_ew(const float* __restrict__ cw, const float* __restrict__ fc0w,
                     const float* __restrict__ fc0b, float* __restrict__ ewb) {
    int i = threadIdx.x;  // 144 = 16 n x 9 taps
    if (i >= 144) return;
    int n = i / 9, t = i % 9;
    float ew = 0.f, eb = 0.f;
    for (int c = 0; c < 32; ++c) {
        float k = cw[(size_t)(n * CCc + c) * 9 + t];
        ew += k * fc0w[c];
        eb += k * fc0b[c];
    }
    ewb[i] = ew;
    ewb[144 + i] = eb;
}

// conv3x3 SAME on rank-1 input via effective kernels
__global__ __launch_bounds__(192) void k_conv2(const float* __restrict__ x,
                                               const float* __restrict__ ewb,
                                               float* __restrict__ xi0) {
    int b = blockIdx.x / HHc, h = blockIdx.x % HHc;
    __shared__ float sm[3 * 194];
    __shared__ float ews[144], ebs[144];
    int w = threadIdx.x;
    for (int i = threadIdx.x; i < 3 * 194; i += 192) {
        int r = i / 194, col = (i % 194) - 1;
        int hr = h + r - 1;
        float v = 0.f;
        if (hr >= 0 && hr < HHc && col >= 0 && col < WWc)
            v = x[(size_t)b * HWc + (size_t)hr * WWc + col];
        sm[i] = v;
    }
    if (threadIdx.x < 144) {
        ews[threadIdx.x] = ewb[threadIdx.x];
        ebs[threadIdx.x] = ewb[144 + threadIdx.x];
    }
    __syncthreads();
    float xv[9], mk[9];
#pragma unroll
    for (int r = 0; r < 3; ++r) {
        int hr = h + r - 1;
        bool rok = (hr >= 0 && hr < HHc);
#pragma unroll
        for (int dx = 0; dx < 3; ++dx) {
            int wx = w + dx - 1;
            bool ok = rok && (wx >= 0) && (wx < WWc);
            xv[r * 3 + dx] = sm[r * 194 + (w + dx)];
            mk[r * 3 + dx] = ok ? 1.f : 0.f;
        }
    }
#pragma unroll
    for (int n = 0; n < 16; ++n) {
        float acc = 0.f;
#pragma unroll
        for (int t = 0; t < 9; ++t)
            acc += ews[n * 9 + t] * xv[t] + mk[t] * ebs[n * 9 + t];
        xi0[((size_t)b * NRk + n) * HWc + (size_t)h * WWc + w] = acc;
    }
}

// generic contiguous-bin sum/sumsq with atomics (setup only)
__global__ void k_binstats(const float* __restrict__ src, float* __restrict__ stats,
                           int binsize, int blocksPerBin) {
    int bin = blockIdx.x / blocksPerBin, sub = blockIdx.x % blocksPerBin;
    const float* p = src + (size_t)bin * binsize;
    float s = 0.f, q = 0.f;
    for (int i = sub * blockDim.x + threadIdx.x; i < binsize; i += blocksPerBin * blockDim.x) {
        float v = p[i];
        s += v;
        q += v * v;
    }
    for (int o = 32; o; o >>= 1) { s += __shfl_down(s, o); q += __shfl_down(q, o); }
    __shared__ float rs[4], rq[4];
    int wid = threadIdx.x >> 6, lane = threadIdx.x & 63;
    if (lane == 0) { rs[wid] = s; rq[wid] = q; }
    __syncthreads();
    if (threadIdx.x == 0) {
        int nw = blockDim.x >> 6;
        float ts = 0.f, tq = 0.f;
        for (int i = 0; i < nw; ++i) { ts += rs[i]; tq += rq[i]; }
        atomicAdd(&stats[bin * 2], ts);
        atomicAdd(&stats[bin * 2 + 1], tq);
    }
}

// xi = sigmoid(q_w * GN(xi0) + q_b)
__global__ __launch_bounds__(192) void k_xi(const float* __restrict__ xi0,
                                            const float* __restrict__ stats,
                                            const float* __restrict__ gnw, const float* __restrict__ gnb,
                                            const float* __restrict__ qw, const float* __restrict__ qb,
                                            float* __restrict__ xi) {
    int b = blockIdx.x / HHc, h = blockIdx.x % HHc;
    int w = threadIdx.x;
    const float Ninv = 1.f / (8.f * HWc);
    float tn[16];
#pragma unroll
    for (int n = 0; n < 16; ++n) {
        int g = n >> 3;
        float su = stats[(b * 2 + g) * 2], sq = stats[(b * 2 + g) * 2 + 1];
        float mu = su * Ninv;
        float var = sq * Ninv - mu * mu;
        float inv = rsqrtf(var + EPSc);
        float v = xi0[((size_t)b * NRk + n) * HWc + (size_t)h * WWc + w];
        tn[n] = (v - mu) * inv * gnw[n] + gnb[n];
    }
#pragma unroll
    for (int d = 0; d < 32; ++d) {
        float acc = qb[d];
        const float* row = qw + d * 16;
#pragma unroll
        for (int n = 0; n < 16; ++n) acc += tn[n] * row[n];
        xi[((size_t)b * CCc + d) * HWc + (size_t)h * WWc + w] = 1.f / (1.f + expf(-acc));
    }
}

// ---------------- DFT chain ----------------
// ZC layout: [ky][b][c][h][2]; write: ZC[((ky*128 + bc)*192 + h)*2 + isim]

// plain forward DFT along W (eval 1, z = FS0, f32)
__global__ __launch_bounds__(192) void k_dftw(const float* __restrict__ z0,
                                              const float* __restrict__ tab,
                                              float* __restrict__ Zc) {
    int bc = blockIdx.x / 24;
    int hg = blockIdx.x % 24;
    int b = bc >> 5, c = bc & 31;
    const float* zp = z0 + (size_t)b * DDs + (size_t)c * HWc + (size_t)hg * 8 * WWc;
    __shared__ float rows[8 * 196];
    __shared__ float tb[24 * 196];
    const float4* zq = (const float4*)zp;
    for (int i4 = threadIdx.x; i4 < 384; i4 += 192) {
        float4 v = zq[i4];
        int r = i4 / 48, col = (i4 % 48) * 4;
        *(float4*)&rows[r * 196 + col] = v;
    }
    for (int i4 = threadIdx.x; i4 < 1152; i4 += 192) {
        int rr = i4 / 48, col = (i4 % 48) * 4;
        const float* src = (rr < 12) ? &tab[rr * 192 + col] : &tab[2496 + (rr - 12) * 192 + col];
        *(float4*)&tb[rr * 196 + col] = *(const float4*)src;
    }
    __syncthreads();
    int t = threadIdx.x;
    int r = t / 24, q = t % 24, ky = q >> 1, isim = q & 1;
    const float* tbp = tb + (isim ? (12 + ky) * 196 : ky * 196);
    const float* rowp = rows + r * 196;
    float a0 = 0.f, a1 = 0.f, a2 = 0.f, a3 = 0.f;
#pragma unroll
    for (int w2 = 0; w2 < WWc; w2 += 4) {
        a0 += rowp[w2] * tbp[w2];
        a1 += rowp[w2 + 1] * tbp[w2 + 1];
        a2 += rowp[w2 + 2] * tbp[w2 + 2];
        a3 += rowp[w2 + 3] * tbp[w2 + 3];
    }
    float acc = (a0 + a1) + (a2 + a3);
    if (isim) acc = -acc;
    int h = hg * 8 + r;
    Zc[(((size_t)ky * 128 + bc) * HHc + h) * 2 + isim] = acc;
}

// FUSED alpha-solve + xnew + forward W-DFT. F history read as fp16 (FH).
__global__ __launch_bounds__(192) void k_dftwx(const unsigned short* __restrict__ FH,
                                               const float* __restrict__ gram,
                                               const float* __restrict__ tab,
                                               float* __restrict__ xc,
                                               float* __restrict__ Zc,
                                               int n) {
    int bc = blockIdx.x / 24;
    int hg = blockIdx.x % 24;
    int b = bc >> 5, c = bc & 31;
    __shared__ float rows[8 * 196];
    __shared__ float tb[24 * 196];
    __shared__ float gs[15];
    __shared__ float alf[5];
    for (int i4 = threadIdx.x; i4 < 1152; i4 += 192) {
        int rr = i4 / 48, col = (i4 % 48) * 4;
        const float* src = (rr < 12) ? &tab[rr * 192 + col] : &tab[2496 + (rr - 12) * 192 + col];
        *(float4*)&tb[rr * 196 + col] = *(const float4*)src;
    }
    if (threadIdx.x < 15) {
        float v = 0.f;
        for (int s2 = 0; s2 < NGSLICE; ++s2) v += gram[s2 * 60 + b * 15 + threadIdx.x];
        gs[threadIdx.x] = v;
    }
    __syncthreads();
    if (threadIdx.x == 0) {
        float H[5][5];
#pragma unroll
        for (int i = 0; i < 5; ++i)
#pragma unroll
            for (int j = 0; j <= i; ++j) {
                float v;
                if (i < n && j < n) v = gs[i * (i + 1) / 2 + j] + ((i == j) ? 1e-4f : 0.f);
                else                v = (i == j) ? 1.f : 0.f;
                H[i][j] = v;
                H[j][i] = v;
            }
        float L[5][5], D[5], w[5], y[5];
#pragma unroll
        for (int j = 0; j < 5; ++j) {
            float d = H[j][j];
#pragma unroll
            for (int k2 = 0; k2 < j; ++k2) d -= L[j][k2] * L[j][k2] * D[k2];
            D[j] = d;
#pragma unroll
            for (int i = j + 1; i < 5; ++i) {
                float v = H[i][j];
#pragma unroll
                for (int k2 = 0; k2 < j; ++k2) v -= L[i][k2] * L[j][k2] * D[k2];
                L[i][j] = v / d;
            }
        }
#pragma unroll
        for (int i = 0; i < 5; ++i) {
            float v = (i < n) ? 1.f : 0.f;
#pragma unroll
            for (int k2 = 0; k2 < i; ++k2) v -= L[i][k2] * w[k2];
            w[i] = v;
        }
#pragma unroll
        for (int i = 4; i >= 0; --i) {
            float v = w[i] / D[i];
#pragma unroll
            for (int k2 = i + 1; k2 < 5; ++k2) v -= L[k2][i] * y[k2];
            y[i] = v;
        }
        float sum = y[0] + y[1] + y[2] + y[3] + y[4];
        float inv = 1.f / sum;
#pragma unroll
        for (int j = 0; j < 5; ++j) alf[j] = (j < n) ? y[j] * inv : 0.f;
    }
    __syncthreads();
    float a0 = alf[0], a1 = alf[1], a2 = alf[2], a3 = alf[3], a4 = alf[4];

    size_t elem = (size_t)b * DDs + (size_t)c * HWc + (size_t)hg * 8 * WWc;
    int off4 = (int)(elem >> 2);
    const int sq4 = 1179648;  // ushort4s per FH slot (SZ_T/4)
    const ushort4* F4 = (const ushort4*)FH;
    float4* xc4 = (float4*)xc;
    if (n == 5) {
        for (int i4 = threadIdx.x; i4 < 384; i4 += 192) {
            ushort4 u0 = F4[off4 + i4];
            ushort4 u1 = F4[sq4 + off4 + i4];
            ushort4 u2 = F4[2 * sq4 + off4 + i4];
            ushort4 u3 = F4[3 * sq4 + off4 + i4];
            ushort4 u4 = F4[4 * sq4 + off4 + i4];
            float4 v;
            v.x = a0 * h2f(u0.x) + a1 * h2f(u1.x) + a2 * h2f(u2.x) + a3 * h2f(u3.x) + a4 * h2f(u4.x);
            v.y = a0 * h2f(u0.y) + a1 * h2f(u1.y) + a2 * h2f(u2.y) + a3 * h2f(u3.y) + a4 * h2f(u4.y);
            v.z = a0 * h2f(u0.z) + a1 * h2f(u1.z) + a2 * h2f(u2.z) + a3 * h2f(u3.z) + a4 * h2f(u4.z);
            v.w = a0 * h2f(u0.w) + a1 * h2f(u1.w) + a2 * h2f(u2.w) + a3 * h2f(u3.w) + a4 * h2f(u4.w);
            xc4[off4 + i4] = v;
            int r = i4 / 48, col = (i4 % 48) * 4;
            *(float4*)&rows[r * 196 + col] = v;
        }
    } else {
        for (int i4 = threadIdx.x; i4 < 384; i4 += 192) {
            ushort4 u0 = F4[off4 + i4];
            ushort4 u1 = F4[sq4 + off4 + i4];
            float4 v;
            v.x = a0 * h2f(u0.x) + a1 * h2f(u1.x);
            v.y = a0 * h2f(u0.y) + a1 * h2f(u1.y);
            v.z = a0 * h2f(u0.z) + a1 * h2f(u1.z);
            v.w = a0 * h2f(u0.w) + a1 * h2f(u1.w);
            if (n >= 3) {
                ushort4 u2 = F4[2 * sq4 + off4 + i4];
                v.x += a2 * h2f(u2.x); v.y += a2 * h2f(u2.y);
                v.z += a2 * h2f(u2.z); v.w += a2 * h2f(u2.w);
            }
            if (n >= 4) {
                ushort4 u3 = F4[3 * sq4 + off4 + i4];
                v.x += a3 * h2f(u3.x); v.y += a3 * h2f(u3.y);
                v.z += a3 * h2f(u3.z); v.w += a3 * h2f(u3.w);
            }
            xc4[off4 + i4] = v;
            int r = i4 / 48, col = (i4 % 48) * 4;
            *(float4*)&rows[r * 196 + col] = v;
        }
    }
    __syncthreads();
    int t = threadIdx.x;
    int r = t / 24, q = t % 24, ky = q >> 1, isim = q & 1;
    const float* tbp = tb + (isim ? (12 + ky) * 196 : ky * 196);
    const float* rowp = rows + r * 196;
    float a0s = 0.f, a1s = 0.f, a2s = 0.f, a3s = 0.f;
#pragma unroll
    for (int w2 = 0; w2 < WWc; w2 += 4) {
        a0s += rowp[w2] * tbp[w2];
        a1s += rowp[w2 + 1] * tbp[w2 + 1];
        a2s += rowp[w2 + 2] * tbp[w2 + 2];
        a3s += rowp[w2 + 3] * tbp[w2 + 3];
    }
    float acc = (a0s + a1s) + (a2s + a3s);
    if (isim) acc = -acc;
    int h = hg * 8 + r;
    Zc[(((size_t)ky * 128 + bc) * HHc + h) * 2 + isim] = acc;
}

// k_specA: H-DFT. grid 256 blocks, 192 threads, ~30KB LDS.
__global__ __launch_bounds__(192) void k_specA(const float* __restrict__ ZC,
                                               const float* __restrict__ tab,
                                               float* __restrict__ ZF) {
    int kyh = blockIdx.x & 1;
    int c = (blockIdx.x >> 1) & 31;
    int b = blockIdx.x >> 6;
    int bc = b * 32 + c;
    int ky0 = kyh * 6;
    __shared__ float zc[6 * 388];
    __shared__ float tcs[13 * 196];
    __shared__ float tsn[13 * 196];
    int t = threadIdx.x;
    for (int i4 = t; i4 < 576; i4 += 192) {
        int kyl = i4 / 96, r4 = (i4 % 96) * 4;
        *(float4*)&zc[kyl * 388 + r4] =
            *(const float4*)(ZC + (size_t)((ky0 + kyl) * 128 + bc) * 384 + r4);
    }
    for (int i4 = t; i4 < 1248; i4 += 192) {
        int half = i4 / 624, k = (i4 % 624) / 48, col = (i4 % 48) * 4;
        const float* src = tab + half * 2496 + k * 192 + col;
        float* dst = (half ? tsn : tcs) + k * 196 + col;
        *(float4*)dst = *(const float4*)src;
    }
    __syncthreads();
    if (t < 144) {
        int kyl = t / 24, j = t % 24;
        int k = (j < 12) ? j : 24 - j;
        float sgn = (j < 12) ? 1.f : -1.f;
        const float* zp = zc + kyl * 388;
        const float* cp = tcs + k * 196;
        const float* sp = tsn + k * 196;
        float re0 = 0.f, im0 = 0.f, re1 = 0.f, im1 = 0.f;
        for (int h = 0; h < 192; h += 2) {
            float zr = zp[h * 2], zi = zp[h * 2 + 1];
            float cv = cp[h], sv = sgn * sp[h];
            re0 += zr * cv + zi * sv;
            im0 += zi * cv - zr * sv;
            float zr1 = zp[h * 2 + 2], zi1 = zp[h * 2 + 3];
            float cv1 = cp[h + 1], sv1 = sgn * sp[h + 1];
            re1 += zr1 * cv1 + zi1 * sv1;
            im1 += zi1 * cv1 - zr1 * sv1;
        }
        size_t o = (((size_t)(b * 12 + ky0 + kyl) * 24 + j) * 32 + c) * 2;
        ZF[o] = re0 + re1;
        ZF[o + 1] = im0 + im1;
    }
}

// k_specB: mode-mix + iDFT-H. grid 192 blocks, 256 threads, ~17.5KB LDS.
__global__ __launch_bounds__(256) void k_specB(const float* __restrict__ ZF,
                                               const float* __restrict__ wt,
                                               const float* __restrict__ tab,
                                               float* __restrict__ Tm) {
    int hq = blockIdx.x & 3;
    int ky = (blockIdx.x >> 2) % 12;
    int b = blockIdx.x / 48;
    __shared__ float zf[24 * 64];
    __shared__ float mo[32 * 50];
    __shared__ float tcs[13 * 48];
    __shared__ float tsn[13 * 48];
    int t = threadIdx.x;
    const float4* zsrc = (const float4*)(ZF + (size_t)(b * 12 + ky) * 1536);
    for (int i4 = t; i4 < 384; i4 += 256)
        *(float4*)&zf[i4 * 4] = zsrc[i4];
    for (int i4 = t; i4 < 312; i4 += 256) {
        int half = i4 / 156, idx = i4 % 156;
        int k = idx / 12, col = (idx % 12) * 4;
        const float* src = tab + half * 2496 + k * 192 + hq * 48 + col;
        float* dst = (half ? tsn : tcs) + k * 48 + col;
        *(float4*)dst = *(const float4*)src;
    }
    __syncthreads();
    const float* wky = wt + (size_t)ky * 24 * 2048;
    for (int p = t; p < 768; p += 256) {
        int j = p / 32, o = p % 32;
        const float* wp = wky + (size_t)j * 2048 + o * 2;
        const float* zj = zf + j * 64;
        float re = 0.f, im = 0.f;
#pragma unroll 8
        for (int i = 0; i < 32; ++i) {
            float ar = zj[i * 2], ai = zj[i * 2 + 1];
            float wr = wp[i * 64], wi = wp[i * 64 + 1];
            re += ar * wr - ai * wi;
            im += ar * wi + ai * wr;
        }
        mo[o * 50 + j * 2] = re;
        mo[o * 50 + j * 2 + 1] = im;
    }
    __syncthreads();
    const float scale = 1.f / 192.f;
    for (int p = t; p < 1536; p += 256) {
        int o = p / 48, hl = p % 48;
        int h = hq * 48 + hl;
        const float* mp = mo + o * 50;
        float re = 0.f, im = 0.f;
#pragma unroll
        for (int j = 0; j < 24; ++j) {
            int k = (j < 12) ? j : 24 - j;
            float sgn = (j < 12) ? 1.f : -1.f;
            float mr = mp[j * 2], mi = mp[j * 2 + 1];
            float cv = tcs[k * 48 + hl], sv = sgn * tsn[k * 48 + hl];
            re += mr * cv - mi * sv;
            im += mr * sv + mi * cv;
        }
        float* dst = Tm + ((size_t)(b * 32 + o) * HHc + h) * 24 + ky * 2;
        dst[0] = re * scale;
        dst[1] = im * scale;
    }
}

// iDFT-W + y2(1x1 conv) + exact gelu + xi add -> sbuf; gn1 stats (sliced).
__global__ __launch_bounds__(384) void k_f5(const float* __restrict__ z0,
                                            const float* __restrict__ Tm,
                                            const float* __restrict__ xi,
                                            const float* __restrict__ w0w,
                                            const float* __restrict__ w0b,
                                            const float* __restrict__ tab,
                                            float* __restrict__ sbuf,
                                            float* __restrict__ stats_e,
                                            int use_y1) {
    int h = blockIdx.x % HHc;
    int b = blockIdx.x / HHc;
    __shared__ float zl[32 * 192];
    __shared__ float w0s[32 * 36];
    __shared__ float tms[32 * 28];
    __shared__ float redc[6][2];
    int tid = threadIdx.x;
    int oq = tid & 3;
    int wq = (tid >> 2) % 48;
    int oh = tid / 192;
    int w4 = wq * 4;
    int ob = oh * 16 + oq;

    if (z0) {
        const float* zp = z0 + (size_t)b * DDs + (size_t)h * WWc;
        for (int i4 = tid; i4 < 32 * 48; i4 += 384) {
            int c = i4 / 48, q = (i4 % 48) * 4;
            float4 v = *(const float4*)(zp + (size_t)c * HWc + q);
            *(float4*)&zl[c * 192 + q] = v;
        }
        if (tid < 256) {
            int oo = tid >> 3, q = (tid & 7) * 4;
            *(float4*)&w0s[oo * 36 + q] = *(const float4*)(w0w + oo * 32 + q);
        }
    }
    if (use_y1) {
        if (tid < 192) {
            int oo = tid / 6, q = (tid % 6) * 4;
            *(float4*)&tms[oo * 28 + q] =
                *(const float4*)(Tm + (((size_t)b * 32 + oo) * HHc + h) * 24 + q);
        }
    }
    float4 c1r = *(const float4*)(tab + 192 + w4);
    float4 s1r = *(const float4*)(tab + 2496 + 192 + w4);
    __syncthreads();

    const float Winv = 1.f / 192.f;
    float acc[4][4];
#pragma unroll
    for (int oo = 0; oo < 4; ++oo) {
        float bbv = w0b[ob + oo * 4];
#pragma unroll
        for (int k = 0; k < 4; ++k) acc[oo][k] = bbv;
    }
    if (use_y1) {
#pragma unroll
        for (int oo = 0; oo < 4; ++oo) {
            float t0 = tms[(ob + oo * 4) * 28];
#pragma unroll
            for (int k = 0; k < 4; ++k) acc[oo][k] += t0 * Winv;
        }
        float4 ck = c1r, sk = s1r;
        const float sc = 2.f * Winv;
#pragma unroll
        for (int ky = 1; ky <= 11; ++ky) {
#pragma unroll
            for (int oo = 0; oo < 4; ++oo) {
                int o = ob + oo * 4;
                float tre = tms[o * 28 + 2 * ky] * sc;
                float tim = tms[o * 28 + 2 * ky + 1] * sc;
                acc[oo][0] += tre * ck.x - tim * sk.x;
                acc[oo][1] += tre * ck.y - tim * sk.y;
                acc[oo][2] += tre * ck.z - tim * sk.z;
                acc[oo][3] += tre * ck.w - tim * sk.w;
            }
            if (ky < 11) {
                float4 cn, sn;
                cn.x = ck.x * c1r.x - sk.x * s1r.x;
                sn.x = sk.x * c1r.x + ck.x * s1r.x;
                cn.y = ck.y * c1r.y - sk.y * s1r.y;
                sn.y = sk.y * c1r.y + ck.y * s1r.y;
                cn.z = ck.z * c1r.z - sk.z * s1r.z;
                sn.z = sk.z * c1r.z + ck.z * s1r.z;
                cn.w = ck.w * c1r.w - sk.w * s1r.w;
                sn.w = sk.w * c1r.w + ck.w * s1r.w;
                ck = cn; sk = sn;
            }
        }
    }
    if (z0) {
#pragma unroll 2
        for (int c = 0; c < 32; c += 4) {
            float4 wv[4];
#pragma unroll
            for (int oo = 0; oo < 4; ++oo)
                wv[oo] = *(const float4*)&w0s[(ob + oo * 4) * 36 + c];
#pragma unroll
            for (int k = 0; k < 4; ++k) {
                float4 z4 = *(const float4*)&zl[(c + k) * 192 + w4];
#pragma unroll
                for (int oo = 0; oo < 4; ++oo) {
                    float wvk = ((const float*)&wv[oo])[k];
                    acc[oo][0] += z4.x * wvk;
                    acc[oo][1] += z4.y * wvk;
                    acc[oo][2] += z4.z * wvk;
                    acc[oo][3] += z4.w * wvk;
                }
            }
        }
    }
    float4 xv[4];
#pragma unroll
    for (int oo = 0; oo < 4; ++oo) {
        int o = ob + oo * 4;
        xv[oo] = *(const float4*)(xi + (size_t)b * DDs + (size_t)o * HWc +
                                  (size_t)h * WWc + w4);
    }
    float s = 0.f, q = 0.f;
#pragma unroll
    for (int oo = 0; oo < 4; ++oo) {
        int o = ob + oo * 4;
        size_t gi = (size_t)b * DDs + (size_t)o * HWc + (size_t)h * WWc + w4;
        float4 out4;
        float* op = (float*)&out4;
        const float* xp = (const float*)&xv[oo];
#pragma unroll
        for (int k = 0; k < 4; ++k) {
            float v = acc[oo][k];
            float u = 0.5f * v * (1.f + erff(v * 0.70710678118654752f));
            float sv = xp[k] + u;
            op[k] = sv;
            s += sv;
            q += sv * sv;
        }
        *(float4*)(sbuf + gi) = out4;
    }
    for (int o2 = 32; o2; o2 >>= 1) {
        s += __shfl_down(s, o2);
        q += __shfl_down(q, o2);
    }
    int wid = tid >> 6, lane = tid & 63;
    if (lane == 0) { redc[wid][0] = s; redc[wid][1] = q; }
    __syncthreads();
    if (tid == 0) {
        float s0 = redc[0][0] + redc[1][0] + redc[2][0];
        float q0 = redc[0][1] + redc[1][1] + redc[2][1];
        float s1 = redc[3][0] + redc[4][0] + redc[5][0];
        float q1 = redc[3][1] + redc[4][1] + redc[5][1];
        int slice = blockIdx.x & (NSLICE - 1);
        float* st = stats_e + slice * 32;
        atomicAdd(&st[b * 4 + 0], s0);
        atomicAdd(&st[b * 4 + 1], q0);
        atomicAdd(&st[b * 4 + 2], s1);
        atomicAdd(&st[b * 4 + 3], q1);
    }
}

// buf = relu(z + GN1(buf)) IN PLACE; gn2 stats (sliced); zero gram slot slices.
__global__ __launch_bounds__(256) void k_f6(const float* __restrict__ z0,
                                            float* buf,
                                            float* __restrict__ stats_e,
                                            const float* __restrict__ n1w,
                                            const float* __restrict__ n1b,
                                            float* __restrict__ gram,
                                            int slot) {
    {
        int gid = blockIdx.x * 256 + threadIdx.x;
        if (gid < NGSLICE * 20) {
            int s2 = gid / 20, r = gid % 20;
            int j = r % 5, b2 = r / 5;
            int ii = slot > j ? slot : j, jj = slot > j ? j : slot;
            gram[s2 * 60 + b2 * 15 + ii * (ii + 1) / 2 + jj] = 0.f;
        }
    }
    const int binq = 147456;
    const int BPB = 144;
    int bin = blockIdx.x / BPB, sub = blockIdx.x % BPB;
    float Nv = 16.f * HWc;
    float su = 0.f, sq = 0.f;
    for (int s2 = 0; s2 < NSLICE; ++s2) {
        su += stats_e[s2 * 32 + bin * 2];
        sq += stats_e[s2 * 32 + bin * 2 + 1];
    }
    float mu = su / Nv;
    float var = sq / Nv - mu * mu;
    float inv = rsqrtf(var + EPSc);
    const float4* z4 = (const float4*)z0;
    float4* b4 = (float4*)buf;
    float s = 0.f, q = 0.f;
    for (int i4 = sub * 256 + threadIdx.x; i4 < binq; i4 += BPB * 256) {
        int e4 = bin * binq + i4;
        int c = (bin & 1) * 16 + i4 / 9216;
        float w1 = inv * n1w[c];
        float b1 = n1b[c] - mu * w1;
        float4 sv = b4[e4];
        float4 zv = make_float4(0.f, 0.f, 0.f, 0.f);
        if (z0) zv = z4[e4];
        float4 r;
        r.x = zv.x + sv.x * w1 + b1; r.x = r.x > 0.f ? r.x : 0.f;
        r.y = zv.y + sv.y * w1 + b1; r.y = r.y > 0.f ? r.y : 0.f;
        r.z = zv.z + sv.z * w1 + b1; r.z = r.z > 0.f ? r.z : 0.f;
        r.w = zv.w + sv.w * w1 + b1; r.w = r.w > 0.f ? r.w : 0.f;
        b4[e4] = r;
        s += r.x + r.y + r.z + r.w;
        q += r.x * r.x + r.y * r.y + r.z * r.z + r.w * r.w;
    }
    for (int o = 32; o; o >>= 1) { s += __shfl_down(s, o); q += __shfl_down(q, o); }
    __shared__ float rs[4], rq[4];
    int wid = threadIdx.x >> 6, lane = threadIdx.x & 63;
    if (lane == 0) { rs[wid] = s; rq[wid] = q; }
    __syncthreads();
    if (threadIdx.x == 0) {
        int slice = blockIdx.x & (NSLICE - 1);
        atomicAdd(&stats_e[slice * 32 + 16 + bin * 2], rs[0] + rs[1] + rs[2] + rs[3]);
        atomicAdd(&stats_e[slice * 32 + 16 + bin * 2 + 1], rq[0] + rq[1] + rq[2] + rq[3]);
    }
}

// buf = GN2(buf) IN PLACE; FH[slot] = fp16(buf); G[slot] = bf16(buf - z);
// sliced Gram. nvalid = valid G slots (0 => last eval: no history writes).
__global__ __launch_bounds__(256) void k_f7g(float* buf,
                                             const float* __restrict__ z,
                                             const float* __restrict__ stats_e,
                                             const float* __restrict__ n2w,
                                             const float* __restrict__ n2b,
                                             unsigned short* __restrict__ G,
                                             unsigned short* __restrict__ FH,
                                             float* __restrict__ gram,
                                             int slot, int nvalid) {
    int b = blockIdx.x / 288, sub = blockIdx.x % 288;
    const float Ninv = 1.f / (16.f * HWc);
    float su0 = 0.f, sq0 = 0.f, su1 = 0.f, sq1 = 0.f;
    for (int s2 = 0; s2 < NSLICE; ++s2) {
        const float* st = stats_e + s2 * 32 + 16 + b * 4;
        su0 += st[0]; sq0 += st[1]; su1 += st[2]; sq1 += st[3];
    }
    float mu0 = su0 * Ninv, inv0 = rsqrtf(sq0 * Ninv - mu0 * mu0 + EPSc);
    float mu1 = su1 * Ninv, inv1 = rsqrtf(sq1 * Ninv - mu1 * mu1 + EPSc);
    const int bq = 294912;
    const int sq4 = 1179648;
    float4* b4 = (float4*)buf;
    const float4* z4 = (const float4*)z;
    ushort4* GU = (ushort4*)G;
    ushort4* FU = (ushort4*)FH;
    float p0 = 0, p1 = 0, p2 = 0, p3 = 0, p4 = 0;
    for (int loc4 = sub * 256 + threadIdx.x; loc4 < bq; loc4 += 73728) {
        int e4 = b * bq + loc4;
        int c = loc4 / 9216;
        float mu = (c < 16) ? mu0 : mu1;
        float inv = (c < 16) ? inv0 : inv1;
        float wv = inv * n2w[c];
        float bv = n2b[c] - mu * wv;
        float4 r = b4[e4];
        float4 fn;
        fn.x = r.x * wv + bv;
        fn.y = r.y * wv + bv;
        fn.z = r.z * wv + bv;
        fn.w = r.w * wv + bv;
        b4[e4] = fn;
        if (nvalid) {
            ushort4 fw;
            fw.x = f2h(fn.x); fw.y = f2h(fn.y); fw.z = f2h(fn.z); fw.w = f2h(fn.w);
            FU[(size_t)slot * sq4 + e4] = fw;
            float4 zv = make_float4(0.f, 0.f, 0.f, 0.f);
            if (z) zv = z4[e4];
            float4 g;
            g.x = fn.x - zv.x; g.y = fn.y - zv.y; g.z = fn.z - zv.z; g.w = fn.w - zv.w;
            ushort4 gw;
            gw.x = f2bf(g.x); gw.y = f2bf(g.y); gw.z = f2bf(g.z); gw.w = f2bf(g.w);
            GU[(size_t)slot * sq4 + e4] = gw;
            float4 gj[5];
#pragma unroll
            for (int j = 0; j < 5; ++j) {
                if (j >= nvalid) { gj[j] = make_float4(0.f, 0.f, 0.f, 0.f); }
                else if (j == slot) { gj[j] = g; }
                else {
                    ushort4 u = GU[(size_t)j * sq4 + e4];
                    gj[j].x = bf2f(u.x); gj[j].y = bf2f(u.y);
                    gj[j].z = bf2f(u.z); gj[j].w = bf2f(u.w);
                }
            }
            p0 += g.x * gj[0].x + g.y * gj[0].y + g.z * gj[0].z + g.w * gj[0].w;
            p1 += g.x * gj[1].x + g.y * gj[1].y + g.z * gj[1].z + g.w * gj[1].w;
            p2 += g.x * gj[2].x + g.y * gj[2].y + g.z * gj[2].z + g.w * gj[2].w;
            p3 += g.x * gj[3].x + g.y * gj[3].y + g.z * gj[3].z + g.w * gj[3].w;
            p4 += g.x * gj[4].x + g.y * gj[4].y + g.z * gj[4].z + g.w * gj[4].w;
        }
    }
    if (!nvalid) return;
    float p[5] = {p0, p1, p2, p3, p4};
    __shared__ float red[4][5];
    int wid = threadIdx.x >> 6, lane = threadIdx.x & 63;
#pragma unroll
    for (int j = 0; j < 5; ++j) {
        float v = p[j];
        for (int o = 32; o; o >>= 1) v += __shfl_down(v, o);
        if (lane == 0) red[wid][j] = v;
    }
    __syncthreads();
    if (threadIdx.x == 0) {
        int gsl = (blockIdx.x & (NGSLICE - 1)) * 60;
#pragma unroll
        for (int j = 0; j < 5; ++j) {
            if (j >= nvalid) continue;
            int ii = slot > j ? slot : j, jj = slot > j ? j : slot;
            atomicAdd(&gram[gsl + b * 15 + ii * (ii + 1) / 2 + jj],
                      red[0][j] + red[1][j] + red[2][j] + red[3][j]);
        }
    }
}

// ---------------- final: BN stats + BN + fc1(gelu) + fc2 ----------------
__global__ __launch_bounds__(256) void k_bnstats(const float* __restrict__ z,
                                                 float* __restrict__ bstats) {
    const int BPB = 18;
    int c = blockIdx.x / BPB, sub = blockIdx.x % BPB;
    float s = 0.f, q = 0.f;
    for (int i = sub * 256 + threadIdx.x; i < BBc * HWc; i += BPB * 256) {
        int b = i / HWc, hw = i % HWc;
        float v = z[(size_t)b * DDs + (size_t)c * HWc + hw];
        s += v;
        q += v * v;
    }
    for (int o = 32; o; o >>= 1) { s += __shfl_down(s, o); q += __shfl_down(q, o); }
    __shared__ float rs[4], rq[4];
    int wid = threadIdx.x >> 6, lane = threadIdx.x & 63;
    if (lane == 0) { rs[wid] = s; rq[wid] = q; }
    __syncthreads();
    if (threadIdx.x == 0) {
        atomicAdd(&bstats[c * 2], rs[0] + rs[1] + rs[2] + rs[3]);
        atomicAdd(&bstats[c * 2 + 1], rq[0] + rq[1] + rq[2] + rq[3]);
    }
}

__global__ __launch_bounds__(192) void k_final(const float* __restrict__ z,
                                               const float* __restrict__ bstats,
                                               const float* __restrict__ bnw,
                                               const float* __restrict__ bnb,
                                               const float* __restrict__ fc1w,
                                               const float* __restrict__ fc1b,
                                               const float* __restrict__ fc2w,
                                               const float* __restrict__ fc2b,
                                               float* __restrict__ out) {
    int b = blockIdx.x / HHc, h = blockIdx.x % HHc;
    int w = threadIdx.x;
    const float Ninv = 1.f / ((float)BBc * HWc);
    float zv[32];
#pragma unroll
    for (int c = 0; c < 32; ++c) {
        float su = bstats[c * 2], sq = bstats[c * 2 + 1];
        float mu = su * Ninv;
        float var = sq * Ninv - mu * mu;
        float inv = rsqrtf(var + EPSc);
        float v = z[(size_t)b * DDs + (size_t)c * HWc + (size_t)h * WWc + w];
        zv[c] = (v - mu) * inv * bnw[c] + bnb[c];
    }
    float acc2 = fc2b[0];
#pragma unroll
    for (int o = 0; o < 32; ++o) {
        float a = fc1b[o];
        const float* row = fc1w + o * 32;
#pragma unroll
        for (int c = 0; c < 32; ++c) a += zv[c] * row[c];
        float g = 0.5f * a * (1.f + erff(a * 0.70710678118654752f));
        acc2 += fc2w[o] * g;
    }
    out[(size_t)b * HWc + (size_t)h * WWc + w] = acc2;
}

// ---------------- host ----------------
extern "C" void kernel_launch(void* const* d_in, const int* in_sizes, int n_in,
                              void* d_out, int out_size, void* d_ws, size_t ws_size,
                              hipStream_t stream) {
    (void)in_sizes; (void)n_in; (void)out_size; (void)ws_size;
    const float* x    = (const float*)d_in[0];
    const float* fc0w = (const float*)d_in[1];
    const float* fc0b = (const float*)d_in[2];
    const float* convw = (const float*)d_in[3];
    const float* gnw  = (const float*)d_in[4];
    const float* gnb  = (const float*)d_in[5];
    const float* qw   = (const float*)d_in[6];
    const float* qb   = (const float*)d_in[7];
    const float* sw1r = (const float*)d_in[8];
    const float* sw1i = (const float*)d_in[9];
    const float* sw2r = (const float*)d_in[10];
    const float* sw2i = (const float*)d_in[11];
    const float* w0w  = (const float*)d_in[12];
    const float* w0b  = (const float*)d_in[13];
    const float* n1w  = (const float*)d_in[14];
    const float* n1b  = (const float*)d_in[15];
    const float* n2w  = (const float*)d_in[16];
    const float* n2b  = (const float*)d_in[17];
    const float* bnw  = (const float*)d_in[18];
    const float* bnb  = (const float*)d_in[19];
    const float* fc1w = (const float*)d_in[20];
    const float* fc1b = (const float*)d_in[21];
    const float* fc2w = (const float*)d_in[22];
    const float* fc2b = (const float*)d_in[23];
    float* out = (float*)d_out;

    float* ws = (float*)d_ws;
    float* XC  = ws + OFF_XC;
    float* XIp = ws + OFF_XI;
    float* FS0 = ws + OFF_F;                 // f32 scratch slot 0
    float* FS1 = ws + OFF_F + SZ_T;          // f32 scratch slot 1 (eval 1 only)
    unsigned short* Gb16 = (unsigned short*)(ws + OFF_G);
    unsigned short* FH16 = (unsigned short*)(ws + OFF_G + 5 * (SZ_T / 2)); // fp16 F history
    float* ZC  = ws + OFF_ZC;
    float* ZFp = ws + OFF_ZF;
    float* MOp = ws + OFF_MO;
    float* TM  = ws + OFF_TM;
    float* WT  = ws + OFF_WT;
    float* TAB = ws + OFF_TAB;
    float* ST  = ws + OFF_STAT;
    float* XI0 = ws + A_XI0;   // setup alias (inside G region)
    float* EWB = MOp;          // setup alias

    auto runtail = [&](const float* zin, float* dst, int use_y1, int evalIdx,
                       int slot, int nvalid) {
        if (use_y1) {
            k_specA<<<256, 192, 0, stream>>>(ZC, TAB, ZFp);
            k_specB<<<BBc * 12 * 4, 256, 0, stream>>>(ZFp, WT, TAB, TM);
        }
        float* stats_e = ST + (size_t)evalIdx * ST_EV;
        k_f5<<<BBc * HHc, 384, 0, stream>>>(zin, TM, XIp, w0w, w0b, TAB, dst,
                                            stats_e, use_y1);
        k_f6<<<8 * 144, 256, 0, stream>>>(zin, dst, stats_e, n1w, n1b,
                                          ST + ST_GRAM, slot);
        k_f7g<<<4 * 288, 256, 0, stream>>>(dst, zin, stats_e, n2w, n2b, Gb16,
                                           FH16, ST + ST_GRAM, slot, nvalid);
    };

    // setup
    k_tables<<<10, 256, 0, stream>>>(TAB);
    k_wt<<<(24 * 12 * 1024 + 255) / 256, 256, 0, stream>>>(sw1r, sw1i, sw2r, sw2i, WT);
    k_zero<<<(ST_TOTAL + 255) / 256, 256, 0, stream>>>(ST, ST_TOTAL);
    k_ew<<<1, 192, 0, stream>>>(convw, fc0w, fc0b, EWB);
    k_conv2<<<BBc * HHc, 192, 0, stream>>>(x, EWB, XI0);
    k_binstats<<<8 * 36, 256, 0, stream>>>(XI0, ST + ST_INJ, 8 * HWc, 36);
    k_xi<<<BBc * HHc, 192, 0, stream>>>(XI0, ST + ST_INJ, gnw, gnb, qw, qb, XIp);

    // f0 = f(0) -> FS0 (+ FH[0] fp16); only slot 0 valid
    runtail(nullptr, FS0, 0, 0, 0, 1);
    // f1 = f(F0): dftw on FS0 (f32); z = FS0, dst = FS1; slots 0,1 valid
    k_dftw<<<BBc * CCc * 24, 192, 0, stream>>>(FS0, TAB, ZC);
    runtail(FS0, FS1, 1, 1, 1, 2);

    // Anderson iterations k = 2..15: fused solve+xnew(fp16 FH)+dftw -> rest
    // dst = FS0 (reused f32 scratch; FH holds history). Eval 15 -> FS0 = final z.
    for (int k = 2; k < 16; ++k) {
        int n = k < 5 ? k : 5;
        int slot = k % 5;
        int nv = (k < 15) ? ((k + 1 < 5) ? (k + 1) : 5) : 0;
        k_dftwx<<<BBc * CCc * 24, 192, 0, stream>>>(FH16, ST + ST_GRAM, TAB, XC, ZC, n);
        runtail(XC, FS0, 1, k, slot, nv);
    }

    // final z = FS0; BatchNorm + fc1(gelu) + fc2
    k_bnstats<<<32 * 18, 256, 0, stream>>>(FS0, ST + ST_BN);
    k_final<<<BBc * HHc, 192, 0, stream>>>(FS0, ST + ST_BN, bnw, bnb, fc1w, fc1b,
                                           fc2w, fc2b, out);
}